// Round 1
// baseline (261.222 us; speedup 1.0000x reference)
//
#include <hip/hip_runtime.h>
#include <math.h>

#define NN 8192
#define NFEAT 512
#define NHID 64
#define NHEADS 4
#define NCLASS 16
#define NEDGE 262144
#define LRELU_ALPHA 0.2f
#define MAXDEG 1024

// h1[h][n][d] = b1[h][d] + sum_k x[n][k] * W1[h][d][k]
__global__ void gemm1(const float* __restrict__ x, const float* __restrict__ W1,
                      const float* __restrict__ b1, float* __restrict__ h1) {
    __shared__ float xs[8][NFEAT];
    int b = blockIdx.x;          // group of 8 nodes
    int t = threadIdx.x;         // 256 threads; t = h*64+d = output feature
    int n0 = b * 8;
    const float4* xv = (const float4*)(x + (size_t)n0 * NFEAT);
    float4* xsv = (float4*)&xs[0][0];
#pragma unroll
    for (int i = 0; i < 4; i++) xsv[t + 256 * i] = xv[t + 256 * i];
    __syncthreads();
    int h = t >> 6, d = t & 63;
    const float* wrow = W1 + (size_t)t * NFEAT;
    float acc[8] = {0, 0, 0, 0, 0, 0, 0, 0};
    for (int k = 0; k < NFEAT; k++) {
        float wk = wrow[k];
#pragma unroll
        for (int j = 0; j < 8; j++) acc[j] += wk * xs[j][k];
    }
    float bias = b1[t];
#pragma unroll
    for (int j = 0; j < 8; j++)
        h1[((size_t)h * NN + (n0 + j)) * NHID + d] = acc[j] + bias;
}

// per-node scores: as1[h][n] = h1[h][n][:]·a1[h][:64], at1 with a1[h][64:]
__global__ void scores1(const float* __restrict__ h1, const float* __restrict__ a1,
                        float* __restrict__ as1, float* __restrict__ at1) {
    int n = blockIdx.x;
    int d = threadIdx.x;  // 64
    for (int h = 0; h < NHEADS; h++) {
        float v = h1[((size_t)h * NN + n) * NHID + d];
        float s1 = v * a1[h * 2 * NHID + d];
        float s2 = v * a1[h * 2 * NHID + NHID + d];
#pragma unroll
        for (int o = 32; o >= 1; o >>= 1) {
            s1 += __shfl_xor(s1, o);
            s2 += __shfl_xor(s2, o);
        }
        if (d == 0) { as1[h * NN + n] = s1; at1[h * NN + n] = s2; }
    }
}

__global__ void count_deg(const int* __restrict__ src, int* __restrict__ deg) {
    int k = blockIdx.x * blockDim.x + threadIdx.x;
    if (k < NEDGE) atomicAdd(&deg[src[k]], 1);
}

__global__ void scan8192(const int* __restrict__ deg, int* __restrict__ rowptr) {
    __shared__ int part[256];
    __shared__ int base[256];
    int t = threadIdx.x;
    int s = 0;
#pragma unroll
    for (int i = 0; i < 32; i++) s += deg[t * 32 + i];
    part[t] = s;
    __syncthreads();
    if (t == 0) {
        int r = 0;
        for (int j = 0; j < 256; j++) { base[j] = r; r += part[j]; }
        rowptr[NN] = r;
    }
    __syncthreads();
    int r = base[t];
    for (int i = 0; i < 32; i++) { rowptr[t * 32 + i] = r; r += deg[t * 32 + i]; }
}

__global__ void fill_csr(const int* __restrict__ src, const int* __restrict__ tgt,
                         int* __restrict__ cursor, int* __restrict__ csr) {
    int k = blockIdx.x * blockDim.x + threadIdx.x;
    if (k < NEDGE) {
        int s = src[k];
        int p = atomicAdd(&cursor[s], 1);
        csr[p] = tgt[k];
    }
}

// one wave per (row n, head h): sparse softmax (with exact duplicate-edge
// summing) + weighted aggregation + ELU; writes hcat[n][h*64+lane]
__global__ void agg1(const float* __restrict__ h1, const float* __restrict__ as1,
                     const float* __restrict__ at1, const int* __restrict__ rowptr,
                     const int* __restrict__ csr, float* __restrict__ hcat) {
    __shared__ int ts[MAXDEG];
    __shared__ float ss[MAXDEG];
    __shared__ float ps[MAXDEG];
    int n = blockIdx.x;
    int h = blockIdx.y;
    int lane = threadIdx.x;  // 64
    int r0 = rowptr[n];
    int deg = rowptr[n + 1] - r0;
    if (deg > MAXDEG) deg = MAXDEG;  // statistically impossible
    if (deg == 0) {                  // statistically impossible; avoid NaN
        hcat[(size_t)n * (NHID * NHEADS) + h * NHID + lane] = 0.f;
        return;
    }
    float asv = as1[h * NN + n];
    for (int j = lane; j < deg; j += 64) {
        int tj = csr[r0 + j];
        ts[j] = tj;
        float e = asv + at1[h * NN + tj];
        ss[j] = e > 0.f ? e : LRELU_ALPHA * e;
    }
    __syncthreads();
    // duplicate combine: first occurrence sums all dups, later ones -> -inf
    float lmax = -INFINITY;
    for (int j = lane; j < deg; j += 64) {
        int tj = ts[j];
        float s = ss[j];
        bool skip = false;
        for (int j2 = 0; j2 < deg; j2++) {
            if (j2 == j) continue;
            if (ts[j2] == tj) {
                if (j2 < j) { skip = true; break; }
                s += ss[j2];
            }
        }
        float v = skip ? -INFINITY : s;
        ps[j] = v;
        if (v > lmax) lmax = v;
    }
#pragma unroll
    for (int o = 32; o >= 1; o >>= 1) lmax = fmaxf(lmax, __shfl_xor(lmax, o));
    __syncthreads();
    float lsum = 0.f;
    for (int j = lane; j < deg; j += 64) {
        float p = expf(ps[j] - lmax);  // exp(-inf - m) = 0 for dups
        ps[j] = p;
        lsum += p;
    }
#pragma unroll
    for (int o = 32; o >= 1; o >>= 1) lsum += __shfl_xor(lsum, o);
    __syncthreads();
    // aggregation: lane = output feature d
    float acc = 0.f;
    const float* hb = h1 + (size_t)h * NN * NHID;
    for (int j = 0; j < deg; j++) acc += ps[j] * hb[(size_t)ts[j] * NHID + lane];
    float v = acc / lsum;
    v = v > 0.f ? v : (expf(v) - 1.f);  // ELU
    hcat[(size_t)n * (NHID * NHEADS) + h * NHID + lane] = v;
}

// h2[n][c] = b2[c] + sum_k hcat[n][k] * W2[c][k]; also as2/at2 scores
__global__ void gemm2(const float* __restrict__ hcat, const float* __restrict__ W2,
                      const float* __restrict__ b2, float* __restrict__ h2,
                      const float* __restrict__ a2, float* __restrict__ as2,
                      float* __restrict__ at2) {
    int n = blockIdx.x;
    int lane = threadIdx.x;  // 64
    int c = lane >> 2, g = lane & 3;
    const float* xr = hcat + (size_t)n * (NHID * NHEADS);
    const float* wr = W2 + (size_t)c * (NHID * NHEADS);
    float acc = 0.f;
    for (int k = g * 64; k < g * 64 + 64; k++) acc += xr[k] * wr[k];
    acc += __shfl_xor(acc, 1);
    acc += __shfl_xor(acc, 2);
    float v = acc + b2[c];
    if (g == 0) h2[(size_t)n * NCLASS + c] = v;
    float s1 = (g == 0) ? v * a2[c] : 0.f;
    float s2 = (g == 0) ? v * a2[NCLASS + c] : 0.f;
#pragma unroll
    for (int o = 32; o >= 1; o >>= 1) {
        s1 += __shfl_xor(s1, o);
        s2 += __shfl_xor(s2, o);
    }
    if (lane == 0) { as2[n] = s1; at2[n] = s2; }
}

// second GAT conv (16 classes) fused with log_softmax -> d_out
__global__ void agg2(const float* __restrict__ h2, const float* __restrict__ as2,
                     const float* __restrict__ at2, const int* __restrict__ rowptr,
                     const int* __restrict__ csr, float* __restrict__ out) {
    __shared__ int ts[MAXDEG];
    __shared__ float ss[MAXDEG];
    __shared__ float ps[MAXDEG];
    __shared__ float row[NCLASS];
    int n = blockIdx.x;
    int lane = threadIdx.x;  // 64
    int r0 = rowptr[n];
    int deg = rowptr[n + 1] - r0;
    if (deg > MAXDEG) deg = MAXDEG;
    if (deg == 0) {
        if (lane < NCLASS) out[(size_t)n * NCLASS + lane] = -logf((float)NCLASS);
        return;
    }
    float asv = as2[n];
    for (int j = lane; j < deg; j += 64) {
        int tj = csr[r0 + j];
        ts[j] = tj;
        float e = asv + at2[tj];
        ss[j] = e > 0.f ? e : LRELU_ALPHA * e;
    }
    __syncthreads();
    float lmax = -INFINITY;
    for (int j = lane; j < deg; j += 64) {
        int tj = ts[j];
        float s = ss[j];
        bool skip = false;
        for (int j2 = 0; j2 < deg; j2++) {
            if (j2 == j) continue;
            if (ts[j2] == tj) {
                if (j2 < j) { skip = true; break; }
                s += ss[j2];
            }
        }
        float v = skip ? -INFINITY : s;
        ps[j] = v;
        if (v > lmax) lmax = v;
    }
#pragma unroll
    for (int o = 32; o >= 1; o >>= 1) lmax = fmaxf(lmax, __shfl_xor(lmax, o));
    __syncthreads();
    float lsum = 0.f;
    for (int j = lane; j < deg; j += 64) {
        float p = expf(ps[j] - lmax);
        ps[j] = p;
        lsum += p;
    }
#pragma unroll
    for (int o = 32; o >= 1; o >>= 1) lsum += __shfl_xor(lsum, o);
    __syncthreads();
    if (lane < NCLASS) {
        float acc = 0.f;
        for (int j = 0; j < deg; j++) acc += ps[j] * h2[(size_t)ts[j] * NCLASS + lane];
        row[lane] = acc / lsum;
    }
    __syncthreads();
    float m = -INFINITY;
#pragma unroll
    for (int c = 0; c < NCLASS; c++) m = fmaxf(m, row[c]);
    float sum = 0.f;
#pragma unroll
    for (int c = 0; c < NCLASS; c++) sum += expf(row[c] - m);
    if (lane < NCLASS) out[(size_t)n * NCLASS + lane] = row[lane] - m - logf(sum);
}

extern "C" void kernel_launch(void* const* d_in, const int* in_sizes, int n_in,
                              void* d_out, int out_size, void* d_ws, size_t ws_size,
                              hipStream_t stream) {
    const float* x  = (const float*)d_in[0];
    const int* el   = (const int*)d_in[1];
    const float* W1 = (const float*)d_in[2];
    const float* b1 = (const float*)d_in[3];
    const float* a1 = (const float*)d_in[4];
    const float* W2 = (const float*)d_in[5];
    const float* b2 = (const float*)d_in[6];
    const float* a2 = (const float*)d_in[7];
    float* out = (float*)d_out;

    float* h1   = (float*)d_ws;               // 4*8192*64 = 2097152
    float* hcat = h1 + 2097152;               // 8192*256  = 2097152
    float* h2   = hcat + 2097152;             // 8192*16   = 131072
    float* as1  = h2 + 131072;                // 4*8192
    float* at1  = as1 + 32768;                // 4*8192
    float* as2  = at1 + 32768;                // 8192
    float* at2  = as2 + 8192;                 // 8192
    int* deg    = (int*)(at2 + 8192);         // 8192
    int* rowptr = deg + 8192;                 // 8193 (+pad)
    int* cursor = rowptr + 8200;              // 8192
    int* csr    = cursor + 8192;              // 262144

    const int* src = el;
    const int* tgt = el + NEDGE;

    hipMemsetAsync(deg, 0, NN * sizeof(int), stream);
    gemm1<<<NN / 8, 256, 0, stream>>>(x, W1, b1, h1);
    scores1<<<NN, 64, 0, stream>>>(h1, a1, as1, at1);
    count_deg<<<NEDGE / 256, 256, 0, stream>>>(src, deg);
    scan8192<<<1, 256, 0, stream>>>(deg, rowptr);
    hipMemcpyAsync(cursor, rowptr, NN * sizeof(int), hipMemcpyDeviceToDevice, stream);
    fill_csr<<<NEDGE / 256, 256, 0, stream>>>(src, tgt, cursor, csr);
    agg1<<<dim3(NN, NHEADS), 64, 0, stream>>>(h1, as1, at1, rowptr, csr, hcat);
    gemm2<<<NN, 64, 0, stream>>>(hcat, W2, b2, h2, a2, as2, at2);
    agg2<<<NN, 64, 0, stream>>>(h2, as2, at2, rowptr, csr, out);
}

// Round 2
// 227.927 us; speedup vs baseline: 1.1461x; 1.1461x over previous
//
#include <hip/hip_runtime.h>
#include <math.h>

#define NN 8192
#define NFEAT 512
#define NHID 64
#define NHEADS 4
#define NCLASS 16
#define NEDGE 262144
#define LRELU_ALPHA 0.2f
#define MAXDEG 192

// Wt4[k4*256 + t] = float4(W1[t][4k4 .. 4k4+3]), t = h*64+d in [0,256)
__global__ void transposeW1(const float* __restrict__ W1, float4* __restrict__ Wt4) {
    int i = blockIdx.x * 256 + threadIdx.x;  // 32768 total
    int k4 = i & 127, t = i >> 7;
    const float4* src = (const float4*)(W1 + (size_t)t * NFEAT);
    Wt4[(size_t)k4 * 256 + t] = src[k4];     // reads coalesced, writes scattered (512KB one-off)
}

// h1[h][n][d] = b1[h][d] + sum_k x[n][k] * W1[h][d][k]
__global__ void gemm1(const float* __restrict__ x, const float4* __restrict__ Wt4,
                      const float* __restrict__ b1, float* __restrict__ h1) {
    __shared__ float4 xs[8][NFEAT / 4];
    int b = blockIdx.x;          // group of 8 nodes
    int t = threadIdx.x;         // 256 threads; t = h*64+d = output feature
    int n0 = b * 8;
    const float4* xv = (const float4*)(x + (size_t)n0 * NFEAT);
    float4* xsv = &xs[0][0];
#pragma unroll
    for (int i = 0; i < 4; i++) xsv[t + 256 * i] = xv[t + 256 * i];
    __syncthreads();
    float acc[8] = {0, 0, 0, 0, 0, 0, 0, 0};
    for (int k4 = 0; k4 < NFEAT / 4; k4++) {
        float4 wv = Wt4[(size_t)k4 * 256 + t];   // coalesced, L2-resident
#pragma unroll
        for (int j = 0; j < 8; j++) {
            float4 xq = xs[j][k4];               // broadcast b128
            acc[j] += wv.x * xq.x + wv.y * xq.y + wv.z * xq.z + wv.w * xq.w;
        }
    }
    int h = t >> 6, d = t & 63;
    float bias = b1[t];
#pragma unroll
    for (int j = 0; j < 8; j++)
        h1[((size_t)h * NN + (n0 + j)) * NHID + d] = acc[j] + bias;
}

// per-node scores: as1[h][n] = h1[h][n][:]·a1[h][:64], at1 with a1[h][64:]
__global__ void scores1(const float* __restrict__ h1, const float* __restrict__ a1,
                        float* __restrict__ as1, float* __restrict__ at1) {
    int n = blockIdx.x * 4 + (threadIdx.x >> 6);
    int d = threadIdx.x & 63;
#pragma unroll
    for (int h = 0; h < NHEADS; h++) {
        float v = h1[((size_t)h * NN + n) * NHID + d];
        float s1 = v * a1[h * 2 * NHID + d];
        float s2 = v * a1[h * 2 * NHID + NHID + d];
#pragma unroll
        for (int o = 32; o >= 1; o >>= 1) {
            s1 += __shfl_xor(s1, o);
            s2 += __shfl_xor(s2, o);
        }
        if (d == 0) { as1[h * NN + n] = s1; at1[h * NN + n] = s2; }
    }
}

__global__ void count_deg(const int* __restrict__ src, int* __restrict__ deg) {
    int k = blockIdx.x * blockDim.x + threadIdx.x;
    if (k < NEDGE) atomicAdd(&deg[src[k]], 1);
}

__global__ void scan8192(const int* __restrict__ deg, int* __restrict__ rowptr) {
    __shared__ int part[256];
    __shared__ int base[256];
    int t = threadIdx.x;
    int s = 0;
#pragma unroll
    for (int i = 0; i < 32; i++) s += deg[t * 32 + i];
    part[t] = s;
    __syncthreads();
    if (t == 0) {
        int r = 0;
        for (int j = 0; j < 256; j++) { base[j] = r; r += part[j]; }
        rowptr[NN] = r;
    }
    __syncthreads();
    int r = base[t];
    for (int i = 0; i < 32; i++) { rowptr[t * 32 + i] = r; r += deg[t * 32 + i]; }
}

__global__ void fill_csr(const int* __restrict__ src, const int* __restrict__ tgt,
                         int* __restrict__ cursor, int* __restrict__ csr) {
    int k = blockIdx.x * blockDim.x + threadIdx.x;
    if (k < NEDGE) {
        int s = src[k];
        int p = atomicAdd(&cursor[s], 1);
        csr[p] = tgt[k];
    }
}

// one 256-thread block per row: 4 waves = 4 heads. Shared CSR + dup-combine,
// per-wave softmax + gather-aggregate + ELU. hcat[n][h*64+lane].
__global__ void agg1(const float* __restrict__ h1, const float* __restrict__ as1,
                     const float* __restrict__ at1, const int* __restrict__ rowptr,
                     const int* __restrict__ csr, float* __restrict__ hcat) {
    __shared__ int ts[MAXDEG];
    __shared__ float ss[NHEADS][MAXDEG];
    __shared__ float ps[NHEADS][MAXDEG];
    int n = blockIdx.x;
    int tid = threadIdx.x;
    int w = tid >> 6;        // wave = head
    int lane = tid & 63;
    int r0 = rowptr[n];
    int deg = rowptr[n + 1] - r0;
    if (deg > MAXDEG) deg = MAXDEG;  // statistically impossible
    if (deg == 0) {                  // statistically impossible; avoid NaN
        hcat[(size_t)n * (NHID * NHEADS) + tid] = 0.f;
        return;
    }
    float asv0 = as1[0 * NN + n], asv1 = as1[1 * NN + n];
    float asv2 = as1[2 * NN + n], asv3 = as1[3 * NN + n];
    for (int j = tid; j < deg; j += 256) {
        int tj = csr[r0 + j];
        ts[j] = tj;
        float e0 = asv0 + at1[0 * NN + tj];
        float e1 = asv1 + at1[1 * NN + tj];
        float e2 = asv2 + at1[2 * NN + tj];
        float e3 = asv3 + at1[3 * NN + tj];
        ss[0][j] = e0 > 0.f ? e0 : LRELU_ALPHA * e0;
        ss[1][j] = e1 > 0.f ? e1 : LRELU_ALPHA * e1;
        ss[2][j] = e2 > 0.f ? e2 : LRELU_ALPHA * e2;
        ss[3][j] = e3 > 0.f ? e3 : LRELU_ALPHA * e3;
    }
    __syncthreads();
    // duplicate combine (structure shared by heads): first occurrence sums dups
    for (int j = tid; j < deg; j += 256) {
        int tj = ts[j];
        float s0 = ss[0][j], s1 = ss[1][j], s2 = ss[2][j], s3 = ss[3][j];
        bool skip = false;
        for (int j2 = 0; j2 < deg; j2++) {
            if (j2 == j) continue;
            if (ts[j2] == tj) {
                if (j2 < j) { skip = true; break; }
                s0 += ss[0][j2]; s1 += ss[1][j2]; s2 += ss[2][j2]; s3 += ss[3][j2];
            }
        }
        ps[0][j] = skip ? -INFINITY : s0;
        ps[1][j] = skip ? -INFINITY : s1;
        ps[2][j] = skip ? -INFINITY : s2;
        ps[3][j] = skip ? -INFINITY : s3;
    }
    __syncthreads();
    // per-wave (per-head) softmax over its own row (wave-synchronous LDS)
    float m = -INFINITY;
    for (int j = lane; j < deg; j += 64) m = fmaxf(m, ps[w][j]);
#pragma unroll
    for (int o = 32; o >= 1; o >>= 1) m = fmaxf(m, __shfl_xor(m, o));
    float lsum = 0.f;
    for (int j = lane; j < deg; j += 64) {
        float p = expf(ps[w][j] - m);  // exp(-inf) = 0 for dup slots
        ps[w][j] = p;
        lsum += p;
    }
#pragma unroll
    for (int o = 32; o >= 1; o >>= 1) lsum += __shfl_xor(lsum, o);
    // gather-aggregate: lane = feature d, unrolled x2 for load ILP
    const float* hb = h1 + (size_t)w * NN * NHID;
    float acc0 = 0.f, acc1 = 0.f;
    int j = 0;
    for (; j + 2 <= deg; j += 2) {
        float p0 = ps[w][j], p1 = ps[w][j + 1];
        int t0 = ts[j], t1 = ts[j + 1];
        acc0 += p0 * hb[(size_t)t0 * NHID + lane];
        acc1 += p1 * hb[(size_t)t1 * NHID + lane];
    }
    if (j < deg) acc0 += ps[w][j] * hb[(size_t)ts[j] * NHID + lane];
    float v = (acc0 + acc1) / lsum;
    v = v > 0.f ? v : (expf(v) - 1.f);  // ELU
    hcat[(size_t)n * (NHID * NHEADS) + w * NHID + lane] = v;
}

// h2[n][c] = b2[c] + sum_k hcat[n][k] * W2[c][k]; also as2/at2 scores
__global__ void gemm2(const float* __restrict__ hcat, const float* __restrict__ W2,
                      const float* __restrict__ b2, float* __restrict__ h2,
                      const float* __restrict__ a2, float* __restrict__ as2,
                      float* __restrict__ at2) {
    int n = blockIdx.x;
    int lane = threadIdx.x;  // 64
    int c = lane >> 2, g = lane & 3;
    const float* xr = hcat + (size_t)n * (NHID * NHEADS);
    const float* wr = W2 + (size_t)c * (NHID * NHEADS);
    float acc = 0.f;
    for (int k = g * 64; k < g * 64 + 64; k++) acc += xr[k] * wr[k];
    acc += __shfl_xor(acc, 1);
    acc += __shfl_xor(acc, 2);
    float v = acc + b2[c];
    if (g == 0) h2[(size_t)n * NCLASS + c] = v;
    float s1 = (g == 0) ? v * a2[c] : 0.f;
    float s2 = (g == 0) ? v * a2[NCLASS + c] : 0.f;
#pragma unroll
    for (int o = 32; o >= 1; o >>= 1) {
        s1 += __shfl_xor(s1, o);
        s2 += __shfl_xor(s2, o);
    }
    if (lane == 0) { as2[n] = s1; at2[n] = s2; }
}

// second GAT conv (16 classes) fused with log_softmax -> d_out
// 256 threads/row; aggregation parallelized 16-way over edges.
__global__ void agg2(const float* __restrict__ h2, const float* __restrict__ as2,
                     const float* __restrict__ at2, const int* __restrict__ rowptr,
                     const int* __restrict__ csr, float* __restrict__ out) {
    __shared__ int ts[MAXDEG];
    __shared__ float ss[MAXDEG];
    __shared__ float ps[MAXDEG];
    __shared__ float red[8];
    __shared__ float partial[4][NCLASS];
    int n = blockIdx.x;
    int tid = threadIdx.x;
    int w = tid >> 6;
    int lane = tid & 63;
    int r0 = rowptr[n];
    int deg = rowptr[n + 1] - r0;
    if (deg > MAXDEG) deg = MAXDEG;
    if (deg == 0) {
        if (tid < NCLASS) out[(size_t)n * NCLASS + tid] = -logf((float)NCLASS);
        return;
    }
    float asv = as2[n];
    for (int j = tid; j < deg; j += 256) {
        int tj = csr[r0 + j];
        ts[j] = tj;
        float e = asv + at2[tj];
        ss[j] = e > 0.f ? e : LRELU_ALPHA * e;
    }
    __syncthreads();
    for (int j = tid; j < deg; j += 256) {
        int tj = ts[j];
        float s = ss[j];
        bool skip = false;
        for (int j2 = 0; j2 < deg; j2++) {
            if (j2 == j) continue;
            if (ts[j2] == tj) {
                if (j2 < j) { skip = true; break; }
                s += ss[j2];
            }
        }
        ps[j] = skip ? -INFINITY : s;
    }
    __syncthreads();
    // block max
    float m = -INFINITY;
    for (int j = tid; j < deg; j += 256) m = fmaxf(m, ps[j]);
#pragma unroll
    for (int o = 32; o >= 1; o >>= 1) m = fmaxf(m, __shfl_xor(m, o));
    if (lane == 0) red[w] = m;
    __syncthreads();
    m = fmaxf(fmaxf(red[0], red[1]), fmaxf(red[2], red[3]));
    // exp + block sum
    float s = 0.f;
    for (int j = tid; j < deg; j += 256) {
        float p = expf(ps[j] - m);
        ps[j] = p;
        s += p;
    }
#pragma unroll
    for (int o = 32; o >= 1; o >>= 1) s += __shfl_xor(s, o);
    if (lane == 0) red[4 + w] = s;
    __syncthreads();   // also publishes the ps[] writes
    float lsum = red[4] + red[5] + red[6] + red[7];
    // aggregation: 16 edges in flight; lane = (jg, c)
    int jg = lane >> 4, c = lane & 15;
    float acc = 0.f;
    for (int j = w * 4 + jg; j < deg; j += 16)
        acc += ps[j] * h2[(size_t)ts[j] * NCLASS + c];
    acc += __shfl_xor(acc, 16);
    acc += __shfl_xor(acc, 32);
    if (lane < NCLASS) partial[w][lane] = acc;
    __syncthreads();
    if (tid < NCLASS) {
        float v = (partial[0][tid] + partial[1][tid] + partial[2][tid] + partial[3][tid]) / lsum;
        float mm = v;
#pragma unroll
        for (int o = 8; o >= 1; o >>= 1) mm = fmaxf(mm, __shfl_xor(mm, o));
        float se = expf(v - mm);
#pragma unroll
        for (int o = 8; o >= 1; o >>= 1) se += __shfl_xor(se, o);
        out[(size_t)n * NCLASS + tid] = v - mm - logf(se);
    }
}

extern "C" void kernel_launch(void* const* d_in, const int* in_sizes, int n_in,
                              void* d_out, int out_size, void* d_ws, size_t ws_size,
                              hipStream_t stream) {
    const float* x  = (const float*)d_in[0];
    const int* el   = (const int*)d_in[1];
    const float* W1 = (const float*)d_in[2];
    const float* b1 = (const float*)d_in[3];
    const float* a1 = (const float*)d_in[4];
    const float* W2 = (const float*)d_in[5];
    const float* b2 = (const float*)d_in[6];
    const float* a2 = (const float*)d_in[7];
    float* out = (float*)d_out;

    float* h1   = (float*)d_ws;               // 4*8192*64 = 2097152
    float* hcat = h1 + 2097152;               // 8192*256  = 2097152
    float* h2   = hcat + 2097152;             // 8192*16   = 131072
    float* as1  = h2 + 131072;                // 4*8192
    float* at1  = as1 + 32768;                // 4*8192
    float* as2  = at1 + 32768;                // 8192
    float* at2  = as2 + 8192;                 // 8192
    int* deg    = (int*)(at2 + 8192);         // 8192
    int* rowptr = deg + 8192;                 // 8193 (+pad)
    int* cursor = rowptr + 8200;              // 8192
    int* csr    = cursor + 8192;              // 262144
    float4* Wt4 = (float4*)(csr + 262144);    // 32768 float4 = 512KB

    const int* src = el;
    const int* tgt = el + NEDGE;

    hipMemsetAsync(deg, 0, NN * sizeof(int), stream);
    transposeW1<<<128, 256, 0, stream>>>(W1, Wt4);
    gemm1<<<NN / 8, 256, 0, stream>>>(x, Wt4, b1, h1);
    scores1<<<NN / 4, 256, 0, stream>>>(h1, a1, as1, at1);
    count_deg<<<NEDGE / 256, 256, 0, stream>>>(src, deg);
    scan8192<<<1, 256, 0, stream>>>(deg, rowptr);
    hipMemcpyAsync(cursor, rowptr, NN * sizeof(int), hipMemcpyDeviceToDevice, stream);
    fill_csr<<<NEDGE / 256, 256, 0, stream>>>(src, tgt, cursor, csr);
    agg1<<<NN, 256, 0, stream>>>(h1, as1, at1, rowptr, csr, hcat);
    gemm2<<<NN, 64, 0, stream>>>(hcat, W2, b2, h2, a2, as2, at2);
    agg2<<<NN, 256, 0, stream>>>(h2, as2, at2, rowptr, csr, out);
}

// Round 3
// 204.562 us; speedup vs baseline: 1.2770x; 1.1142x over previous
//
#include <hip/hip_runtime.h>
#include <math.h>

#define NN 8192
#define NFEAT 512
#define NHID 64
#define NHEADS 4
#define NCLASS 16
#define NEDGE 262144
#define LRELU_ALPHA 0.2f
#define MAXDEG 192

// Wt4[k4*256 + t] = float4(W1[t][4k4 .. 4k4+3]), t = h*64+d in [0,256)
__global__ void transposeW1(const float* __restrict__ W1, float4* __restrict__ Wt4) {
    int i = blockIdx.x * 256 + threadIdx.x;  // 32768 total
    int k4 = i & 127, t = i >> 7;
    const float4* src = (const float4*)(W1 + (size_t)t * NFEAT);
    Wt4[(size_t)k4 * 256 + t] = src[k4];
}

// h1[h][n][d] = b1[h][d] + sum_k x[n][k] * W1[h][d][k]
// 16 nodes/block, 256 threads; per-thread tile 4 nodes x 4 output features.
// Fused: as1[h][n], at1[h][n] scores via 16-lane shuffle reduction.
__global__ void gemm1(const float* __restrict__ x, const float4* __restrict__ Wt4,
                      const float* __restrict__ b1, float* __restrict__ h1,
                      const float* __restrict__ a1, float* __restrict__ as1,
                      float* __restrict__ at1) {
    __shared__ float4 xs[16][NFEAT / 4];     // 32 KB
    int t = threadIdx.x;
    int n0 = blockIdx.x * 16;
    const float4* xv = (const float4*)(x + (size_t)n0 * NFEAT);
    float4* xsv = &xs[0][0];
#pragma unroll
    for (int i = 0; i < 8; i++) xsv[t + 256 * i] = xv[t + 256 * i];
    __syncthreads();
    int w = t >> 6, lane = t & 63;
    int o0 = lane * 4;                        // 4 consecutive output features
    float acc[4][4];
#pragma unroll
    for (int j = 0; j < 4; j++)
#pragma unroll
        for (int i = 0; i < 4; i++) acc[j][i] = 0.f;
    const float4* wbase = Wt4 + o0;
    for (int k4 = 0; k4 < NFEAT / 4; k4++) {
        float4 wv0 = wbase[(size_t)k4 * 256 + 0];
        float4 wv1 = wbase[(size_t)k4 * 256 + 1];
        float4 wv2 = wbase[(size_t)k4 * 256 + 2];
        float4 wv3 = wbase[(size_t)k4 * 256 + 3];
#pragma unroll
        for (int j = 0; j < 4; j++) {
            float4 xq = xs[w * 4 + j][k4];    // LDS broadcast
            acc[j][0] += wv0.x * xq.x + wv0.y * xq.y + wv0.z * xq.z + wv0.w * xq.w;
            acc[j][1] += wv1.x * xq.x + wv1.y * xq.y + wv1.z * xq.z + wv1.w * xq.w;
            acc[j][2] += wv2.x * xq.x + wv2.y * xq.y + wv2.z * xq.z + wv2.w * xq.w;
            acc[j][3] += wv3.x * xq.x + wv3.y * xq.y + wv3.z * xq.z + wv3.w * xq.w;
        }
    }
    int head = lane >> 4;                     // o0 >> 6
    float bias[4], a1s[4], a1t[4];
#pragma unroll
    for (int i = 0; i < 4; i++) {
        int d = (o0 + i) & 63;
        bias[i] = b1[o0 + i];
        a1s[i] = a1[head * 2 * NHID + d];
        a1t[i] = a1[head * 2 * NHID + NHID + d];
    }
#pragma unroll
    for (int j = 0; j < 4; j++) {
        int n = n0 + w * 4 + j;
        float p1 = 0.f, p2 = 0.f;
#pragma unroll
        for (int i = 0; i < 4; i++) {
            float v = acc[j][i] + bias[i];
            h1[((size_t)head * NN + n) * NHID + ((o0 + i) & 63)] = v;
            p1 += v * a1s[i];
            p2 += v * a1t[i];
        }
#pragma unroll
        for (int o = 8; o >= 1; o >>= 1) {
            p1 += __shfl_xor(p1, o);
            p2 += __shfl_xor(p2, o);
        }
        if ((lane & 15) == 0) { as1[head * NN + n] = p1; at1[head * NN + n] = p2; }
    }
}

__global__ void count_deg(const int* __restrict__ src, int* __restrict__ deg) {
    int k = blockIdx.x * blockDim.x + threadIdx.x;
    if (k < NEDGE) atomicAdd(&deg[src[k]], 1);
}

__global__ void scan8192(const int* __restrict__ deg, int* __restrict__ rowptr,
                         int* __restrict__ cursor) {
    __shared__ int part[256];
    __shared__ int base[256];
    int t = threadIdx.x;
    int s = 0;
#pragma unroll
    for (int i = 0; i < 32; i++) s += deg[t * 32 + i];
    part[t] = s;
    __syncthreads();
    if (t == 0) {
        int r = 0;
        for (int j = 0; j < 256; j++) { base[j] = r; r += part[j]; }
        rowptr[NN] = r;
    }
    __syncthreads();
    int r = base[t];
    for (int i = 0; i < 32; i++) {
        rowptr[t * 32 + i] = r;
        cursor[t * 32 + i] = r;
        r += deg[t * 32 + i];
    }
}

__global__ void fill_csr(const int* __restrict__ src, const int* __restrict__ tgt,
                         int* __restrict__ cursor, int* __restrict__ csr) {
    int k = blockIdx.x * blockDim.x + threadIdx.x;
    if (k < NEDGE) {
        int s = src[k];
        int p = atomicAdd(&cursor[s], 1);
        csr[p] = tgt[k];
    }
}

// one 256-thread block per row: 4 waves = 4 heads. Shared CSR + dup-combine,
// per-wave softmax + gather-aggregate + ELU. hcat[n][h*64+lane].
__global__ void agg1(const float* __restrict__ h1, const float* __restrict__ as1,
                     const float* __restrict__ at1, const int* __restrict__ rowptr,
                     const int* __restrict__ csr, float* __restrict__ hcat) {
    __shared__ int ts[MAXDEG];
    __shared__ float ss[NHEADS][MAXDEG];
    __shared__ float ps[NHEADS][MAXDEG];
    int n = blockIdx.x;
    int tid = threadIdx.x;
    int w = tid >> 6;        // wave = head
    int lane = tid & 63;
    int r0 = rowptr[n];
    int deg = rowptr[n + 1] - r0;
    if (deg > MAXDEG) deg = MAXDEG;  // statistically impossible
    if (deg == 0) {                  // statistically impossible; avoid NaN
        hcat[(size_t)n * (NHID * NHEADS) + tid] = 0.f;
        return;
    }
    float asv0 = as1[0 * NN + n], asv1 = as1[1 * NN + n];
    float asv2 = as1[2 * NN + n], asv3 = as1[3 * NN + n];
    for (int j = tid; j < deg; j += 256) {
        int tj = csr[r0 + j];
        ts[j] = tj;
        float e0 = asv0 + at1[0 * NN + tj];
        float e1 = asv1 + at1[1 * NN + tj];
        float e2 = asv2 + at1[2 * NN + tj];
        float e3 = asv3 + at1[3 * NN + tj];
        ss[0][j] = e0 > 0.f ? e0 : LRELU_ALPHA * e0;
        ss[1][j] = e1 > 0.f ? e1 : LRELU_ALPHA * e1;
        ss[2][j] = e2 > 0.f ? e2 : LRELU_ALPHA * e2;
        ss[3][j] = e3 > 0.f ? e3 : LRELU_ALPHA * e3;
    }
    __syncthreads();
    // duplicate combine (structure shared by heads): first occurrence sums dups
    for (int j = tid; j < deg; j += 256) {
        int tj = ts[j];
        float s0 = ss[0][j], s1 = ss[1][j], s2 = ss[2][j], s3 = ss[3][j];
        bool skip = false;
        for (int j2 = 0; j2 < deg; j2++) {
            if (j2 == j) continue;
            if (ts[j2] == tj) {
                if (j2 < j) { skip = true; break; }
                s0 += ss[0][j2]; s1 += ss[1][j2]; s2 += ss[2][j2]; s3 += ss[3][j2];
            }
        }
        ps[0][j] = skip ? -INFINITY : s0;
        ps[1][j] = skip ? -INFINITY : s1;
        ps[2][j] = skip ? -INFINITY : s2;
        ps[3][j] = skip ? -INFINITY : s3;
    }
    __syncthreads();
    // per-wave (per-head) softmax over its own row (wave-synchronous LDS)
    float m = -INFINITY;
    for (int j = lane; j < deg; j += 64) m = fmaxf(m, ps[w][j]);
#pragma unroll
    for (int o = 32; o >= 1; o >>= 1) m = fmaxf(m, __shfl_xor(m, o));
    float lsum = 0.f;
    for (int j = lane; j < deg; j += 64) {
        float p = expf(ps[w][j] - m);  // exp(-inf) = 0 for dup slots
        ps[w][j] = p;
        lsum += p;
    }
#pragma unroll
    for (int o = 32; o >= 1; o >>= 1) lsum += __shfl_xor(lsum, o);
    // gather-aggregate: lane = feature d, unrolled x2 for load ILP
    const float* hb = h1 + (size_t)w * NN * NHID;
    float acc0 = 0.f, acc1 = 0.f;
    int j = 0;
    for (; j + 2 <= deg; j += 2) {
        float p0 = ps[w][j], p1 = ps[w][j + 1];
        int t0 = ts[j], t1 = ts[j + 1];
        acc0 += p0 * hb[(size_t)t0 * NHID + lane];
        acc1 += p1 * hb[(size_t)t1 * NHID + lane];
    }
    if (j < deg) acc0 += ps[w][j] * hb[(size_t)ts[j] * NHID + lane];
    float v = (acc0 + acc1) / lsum;
    v = v > 0.f ? v : (expf(v) - 1.f);  // ELU
    hcat[(size_t)n * (NHID * NHEADS) + w * NHID + lane] = v;
}

// h2[n][c] = b2[c] + sum_k hcat[n][k] * W2[c][k]; fused as2/at2 scores.
// 16 nodes/block, 256 threads; hcat rows + W2 staged in LDS.
__global__ void gemm2(const float* __restrict__ hcat, const float* __restrict__ W2,
                      const float* __restrict__ b2, float* __restrict__ h2,
                      const float* __restrict__ a2, float* __restrict__ as2,
                      float* __restrict__ at2) {
    __shared__ float hs[16][260];
    __shared__ float ws[16][260];
    int t = threadIdx.x;
    int n0 = blockIdx.x * 16;
#pragma unroll
    for (int i = 0; i < 16; i++) {
        hs[i][t] = hcat[(size_t)(n0 + i) * 256 + t];
        ws[i][t] = W2[i * 256 + t];
    }
    __syncthreads();
    int nl = t >> 4, c = t & 15;
    const float4* hr = (const float4*)&hs[nl][0];   // 260*4B row => 16B aligned
    const float4* wr = (const float4*)&ws[c][0];
    float dot = 0.f;
#pragma unroll 4
    for (int k4 = 0; k4 < 64; k4++) {
        float4 a = hr[k4], b = wr[k4];
        dot += a.x * b.x + a.y * b.y + a.z * b.z + a.w * b.w;
    }
    float v = dot + b2[c];
    h2[(size_t)(n0 + nl) * NCLASS + c] = v;
    float s1 = v * a2[c], s2 = v * a2[NCLASS + c];
#pragma unroll
    for (int o = 8; o >= 1; o >>= 1) {
        s1 += __shfl_xor(s1, o);
        s2 += __shfl_xor(s2, o);
    }
    if (c == 0) { as2[n0 + nl] = s1; at2[n0 + nl] = s2; }
}

// second GAT conv (16 classes) fused with log_softmax -> d_out
// 256 threads/row; aggregation parallelized 16-way over edges.
__global__ void agg2(const float* __restrict__ h2, const float* __restrict__ as2,
                     const float* __restrict__ at2, const int* __restrict__ rowptr,
                     const int* __restrict__ csr, float* __restrict__ out) {
    __shared__ int ts[MAXDEG];
    __shared__ float ss[MAXDEG];
    __shared__ float ps[MAXDEG];
    __shared__ float red[8];
    __shared__ float partial[4][NCLASS];
    int n = blockIdx.x;
    int tid = threadIdx.x;
    int w = tid >> 6;
    int lane = tid & 63;
    int r0 = rowptr[n];
    int deg = rowptr[n + 1] - r0;
    if (deg > MAXDEG) deg = MAXDEG;
    if (deg == 0) {
        if (tid < NCLASS) out[(size_t)n * NCLASS + tid] = -logf((float)NCLASS);
        return;
    }
    float asv = as2[n];
    for (int j = tid; j < deg; j += 256) {
        int tj = csr[r0 + j];
        ts[j] = tj;
        float e = asv + at2[tj];
        ss[j] = e > 0.f ? e : LRELU_ALPHA * e;
    }
    __syncthreads();
    for (int j = tid; j < deg; j += 256) {
        int tj = ts[j];
        float s = ss[j];
        bool skip = false;
        for (int j2 = 0; j2 < deg; j2++) {
            if (j2 == j) continue;
            if (ts[j2] == tj) {
                if (j2 < j) { skip = true; break; }
                s += ss[j2];
            }
        }
        ps[j] = skip ? -INFINITY : s;
    }
    __syncthreads();
    float m = -INFINITY;
    for (int j = tid; j < deg; j += 256) m = fmaxf(m, ps[j]);
#pragma unroll
    for (int o = 32; o >= 1; o >>= 1) m = fmaxf(m, __shfl_xor(m, o));
    if (lane == 0) red[w] = m;
    __syncthreads();
    m = fmaxf(fmaxf(red[0], red[1]), fmaxf(red[2], red[3]));
    float s = 0.f;
    for (int j = tid; j < deg; j += 256) {
        float p = expf(ps[j] - m);
        ps[j] = p;
        s += p;
    }
#pragma unroll
    for (int o = 32; o >= 1; o >>= 1) s += __shfl_xor(s, o);
    if (lane == 0) red[4 + w] = s;
    __syncthreads();
    float lsum = red[4] + red[5] + red[6] + red[7];
    int jg = lane >> 4, c = lane & 15;
    float acc = 0.f;
    for (int j = w * 4 + jg; j < deg; j += 16)
        acc += ps[j] * h2[(size_t)ts[j] * NCLASS + c];
    acc += __shfl_xor(acc, 16);
    acc += __shfl_xor(acc, 32);
    if (lane < NCLASS) partial[w][lane] = acc;
    __syncthreads();
    if (tid < NCLASS) {
        float v = (partial[0][tid] + partial[1][tid] + partial[2][tid] + partial[3][tid]) / lsum;
        float mm = v;
#pragma unroll
        for (int o = 8; o >= 1; o >>= 1) mm = fmaxf(mm, __shfl_xor(mm, o));
        float se = expf(v - mm);
#pragma unroll
        for (int o = 8; o >= 1; o >>= 1) se += __shfl_xor(se, o);
        out[(size_t)n * NCLASS + tid] = v - mm - logf(se);
    }
}

extern "C" void kernel_launch(void* const* d_in, const int* in_sizes, int n_in,
                              void* d_out, int out_size, void* d_ws, size_t ws_size,
                              hipStream_t stream) {
    const float* x  = (const float*)d_in[0];
    const int* el   = (const int*)d_in[1];
    const float* W1 = (const float*)d_in[2];
    const float* b1 = (const float*)d_in[3];
    const float* a1 = (const float*)d_in[4];
    const float* W2 = (const float*)d_in[5];
    const float* b2 = (const float*)d_in[6];
    const float* a2 = (const float*)d_in[7];
    float* out = (float*)d_out;

    float* h1   = (float*)d_ws;               // 4*8192*64 = 2097152
    float* hcat = h1 + 2097152;               // 8192*256  = 2097152
    float* h2   = hcat + 2097152;             // 8192*16   = 131072
    float* as1  = h2 + 131072;                // 4*8192
    float* at1  = as1 + 32768;                // 4*8192
    float* as2  = at1 + 32768;                // 8192
    float* at2  = as2 + 8192;                 // 8192
    int* deg    = (int*)(at2 + 8192);         // 8192
    int* rowptr = deg + 8192;                 // 8193 (+pad)
    int* cursor = rowptr + 8200;              // 8192
    int* csr    = cursor + 8192;              // 262144
    float4* Wt4 = (float4*)(csr + 262144);    // 32768 float4 = 512KB

    const int* src = el;
    const int* tgt = el + NEDGE;

    hipMemsetAsync(deg, 0, NN * sizeof(int), stream);
    transposeW1<<<128, 256, 0, stream>>>(W1, Wt4);
    gemm1<<<NN / 16, 256, 0, stream>>>(x, Wt4, b1, h1, a1, as1, at1);
    count_deg<<<NEDGE / 256, 256, 0, stream>>>(src, deg);
    scan8192<<<1, 256, 0, stream>>>(deg, rowptr, cursor);
    fill_csr<<<NEDGE / 256, 256, 0, stream>>>(src, tgt, cursor, csr);
    agg1<<<NN, 256, 0, stream>>>(h1, as1, at1, rowptr, csr, hcat);
    gemm2<<<NN / 16, 256, 0, stream>>>(hcat, W2, b2, h2, a2, as2, at2);
    agg2<<<NN, 256, 0, stream>>>(h2, as2, at2, rowptr, csr, out);
}

// Round 4
// 152.750 us; speedup vs baseline: 1.7101x; 1.3392x over previous
//
#include <hip/hip_runtime.h>
#include <math.h>

#define NN 8192
#define NFEAT 512
#define NHID 64
#define NHEADS 4
#define NCLASS 16
#define NEDGE 262144
#define LRELU_ALPHA 0.2f
#define MAXDEG 192

typedef __attribute__((ext_vector_type(8))) short short8;
typedef __attribute__((ext_vector_type(8))) unsigned short ushort8;
typedef __attribute__((ext_vector_type(4))) float f32x4;

__device__ __forceinline__ unsigned short bfr(float f) {
    unsigned int u = __float_as_uint(f);
    u += 0x7fffu + ((u >> 16) & 1u);   // round-to-nearest-even
    return (unsigned short)(u >> 16);
}

// Wbf[((ks*16 + nt)*64 + lane)*8 + i] = bf16(W1[nt*16 + (lane&15)][ks*32 + (lane>>4)*8 + i])
// i.e. B-fragment-ordered for mfma_f32_16x16x32_bf16.
__global__ void buildWbf(const float* __restrict__ W1, unsigned short* __restrict__ Wbf) {
    int idx = blockIdx.x * 256 + threadIdx.x;   // 16384 total
    int lane = idx & 63, nt = (idx >> 6) & 15, ks = idx >> 10;
    int tfeat = nt * 16 + (lane & 15);
    int k0 = ks * 32 + (lane >> 4) * 8;
    const float* src = W1 + (size_t)tfeat * NFEAT + k0;
    float4 lo = *(const float4*)src;
    float4 hi = *(const float4*)(src + 4);
    ushort8 v;
    v[0] = bfr(lo.x); v[1] = bfr(lo.y); v[2] = bfr(lo.z); v[3] = bfr(lo.w);
    v[4] = bfr(hi.x); v[5] = bfr(hi.y); v[6] = bfr(hi.z); v[7] = bfr(hi.w);
    *(ushort8*)(Wbf + (size_t)idx * 8) = v;
}

// MFMA gemm1: h1[h][n][d] = b1 + x@W1^T, fused as1/at1 scores.
// 512 blocks x 16 nodes; wave w = head w (64 output features = 4 N-tiles).
__global__ void gemm1(const float* __restrict__ x, const unsigned short* __restrict__ Wbf,
                      const float* __restrict__ b1, float* __restrict__ h1,
                      const float* __restrict__ a1, float* __restrict__ as1,
                      float* __restrict__ at1) {
    __shared__ __align__(16) unsigned short xs[16 * 512];   // 16 KB, XOR-swizzled rows
    int t = threadIdx.x;
    int n0 = blockIdx.x * 16;
    // stage x tile -> bf16 LDS (coalesced fp32 reads)
    const float4* xv = (const float4*)(x + (size_t)n0 * NFEAT);
#pragma unroll
    for (int i = 0; i < 4; i++) {
        int g = i * 256 + t;          // 1024 groups of 8 bf16 (16 B)
        int row = g >> 6;
        int k0 = (g & 63) * 8;
        float4 lo = xv[g * 2];
        float4 hi = xv[g * 2 + 1];
        ushort8 v;
        v[0] = bfr(lo.x); v[1] = bfr(lo.y); v[2] = bfr(lo.z); v[3] = bfr(lo.w);
        v[4] = bfr(hi.x); v[5] = bfr(hi.y); v[6] = bfr(hi.z); v[7] = bfr(hi.w);
        int byte = (k0 * 2) ^ ((row & 7) << 4);
        *(ushort8*)((char*)xs + row * 1024 + byte) = v;
    }
    __syncthreads();
    int w = t >> 6, lane = t & 63;
    int arow = lane & 15, kg = lane >> 4;
    f32x4 acc[4];
#pragma unroll
    for (int j = 0; j < 4; j++) acc[j] = (f32x4){0.f, 0.f, 0.f, 0.f};
    const unsigned short* wb = Wbf + ((size_t)(w * 4) * 64 + lane) * 8;
    int abase = arow * 1024;
    int aswz = (arow & 7) << 4;
    for (int ks = 0; ks < 16; ks++) {
        short8 afrag = *(const short8*)((const char*)xs + abase + ((ks * 64 + kg * 16) ^ aswz));
#pragma unroll
        for (int j = 0; j < 4; j++) {
            short8 bfrag = *(const short8*)(wb + j * 512);
            acc[j] = __builtin_amdgcn_mfma_f32_16x16x32_bf16(afrag, bfrag, acc[j], 0, 0, 0);
        }
        wb += 8192;   // next ks: 16 tiles * 64 lanes * 8
    }
    // epilogue: D col=lane&15 (feature within tile), row=(lane>>4)*4+reg (node)
    int g4 = lane >> 4, cf = lane & 15;
    float p1[4] = {0.f, 0.f, 0.f, 0.f}, p2[4] = {0.f, 0.f, 0.f, 0.f};
#pragma unroll
    for (int j = 0; j < 4; j++) {
        int d = j * 16 + cf;
        float bias = b1[w * 64 + d];
        float c1 = a1[w * 2 * NHID + d];
        float c2 = a1[w * 2 * NHID + NHID + d];
#pragma unroll
        for (int r = 0; r < 4; r++) {
            int n = n0 + g4 * 4 + r;
            float v = acc[j][r] + bias;
            h1[((size_t)w * NN + n) * NHID + d] = v;
            p1[r] += v * c1;
            p2[r] += v * c2;
        }
    }
#pragma unroll
    for (int r = 0; r < 4; r++) {
        float s1 = p1[r], s2 = p2[r];
#pragma unroll
        for (int o = 8; o >= 1; o >>= 1) {
            s1 += __shfl_xor(s1, o);
            s2 += __shfl_xor(s2, o);
        }
        if (cf == 0) {
            int n = n0 + g4 * 4 + r;
            as1[w * NN + n] = s1;
            at1[w * NN + n] = s2;
        }
    }
}

__global__ void count_deg(const int* __restrict__ src, int* __restrict__ deg) {
    int k = blockIdx.x * blockDim.x + threadIdx.x;
    if (k < NEDGE) atomicAdd(&deg[src[k]], 1);
}

__global__ void scan8192(const int* __restrict__ deg, int* __restrict__ rowptr,
                         int* __restrict__ cursor) {
    __shared__ int part[256];
    __shared__ int base[256];
    int t = threadIdx.x;
    int s = 0;
#pragma unroll
    for (int i = 0; i < 32; i++) s += deg[t * 32 + i];
    part[t] = s;
    __syncthreads();
    if (t == 0) {
        int r = 0;
        for (int j = 0; j < 256; j++) { base[j] = r; r += part[j]; }
        rowptr[NN] = r;
    }
    __syncthreads();
    int r = base[t];
    for (int i = 0; i < 32; i++) {
        rowptr[t * 32 + i] = r;
        cursor[t * 32 + i] = r;
        r += deg[t * 32 + i];
    }
}

__global__ void fill_csr(const int* __restrict__ src, const int* __restrict__ tgt,
                         int* __restrict__ cursor, int* __restrict__ csr) {
    int k = blockIdx.x * blockDim.x + threadIdx.x;
    if (k < NEDGE) {
        int s = src[k];
        int p = atomicAdd(&cursor[s], 1);
        csr[p] = tgt[k];
    }
}

// one 256-thread block per row: 4 waves = 4 heads. Shared CSR + dup-combine,
// per-wave softmax + gather-aggregate + ELU. hcat[n][h*64+lane].
__global__ void agg1(const float* __restrict__ h1, const float* __restrict__ as1,
                     const float* __restrict__ at1, const int* __restrict__ rowptr,
                     const int* __restrict__ csr, float* __restrict__ hcat) {
    __shared__ int ts[MAXDEG];
    __shared__ float ss[NHEADS][MAXDEG];
    __shared__ float ps[NHEADS][MAXDEG];
    int n = blockIdx.x;
    int tid = threadIdx.x;
    int w = tid >> 6;        // wave = head
    int lane = tid & 63;
    int r0 = rowptr[n];
    int deg = rowptr[n + 1] - r0;
    if (deg > MAXDEG) deg = MAXDEG;  // statistically impossible
    if (deg == 0) {                  // statistically impossible; avoid NaN
        hcat[(size_t)n * (NHID * NHEADS) + tid] = 0.f;
        return;
    }
    float asv0 = as1[0 * NN + n], asv1 = as1[1 * NN + n];
    float asv2 = as1[2 * NN + n], asv3 = as1[3 * NN + n];
    for (int j = tid; j < deg; j += 256) {
        int tj = csr[r0 + j];
        ts[j] = tj;
        float e0 = asv0 + at1[0 * NN + tj];
        float e1 = asv1 + at1[1 * NN + tj];
        float e2 = asv2 + at1[2 * NN + tj];
        float e3 = asv3 + at1[3 * NN + tj];
        ss[0][j] = e0 > 0.f ? e0 : LRELU_ALPHA * e0;
        ss[1][j] = e1 > 0.f ? e1 : LRELU_ALPHA * e1;
        ss[2][j] = e2 > 0.f ? e2 : LRELU_ALPHA * e2;
        ss[3][j] = e3 > 0.f ? e3 : LRELU_ALPHA * e3;
    }
    __syncthreads();
    // duplicate combine (structure shared by heads): first occurrence sums dups
    for (int j = tid; j < deg; j += 256) {
        int tj = ts[j];
        float s0 = ss[0][j], s1 = ss[1][j], s2 = ss[2][j], s3 = ss[3][j];
        bool skip = false;
        for (int j2 = 0; j2 < deg; j2++) {
            if (j2 == j) continue;
            if (ts[j2] == tj) {
                if (j2 < j) { skip = true; break; }
                s0 += ss[0][j2]; s1 += ss[1][j2]; s2 += ss[2][j2]; s3 += ss[3][j2];
            }
        }
        ps[0][j] = skip ? -INFINITY : s0;
        ps[1][j] = skip ? -INFINITY : s1;
        ps[2][j] = skip ? -INFINITY : s2;
        ps[3][j] = skip ? -INFINITY : s3;
    }
    __syncthreads();
    // per-wave (per-head) softmax over its own row (wave-synchronous LDS)
    float m = -INFINITY;
    for (int j = lane; j < deg; j += 64) m = fmaxf(m, ps[w][j]);
#pragma unroll
    for (int o = 32; o >= 1; o >>= 1) m = fmaxf(m, __shfl_xor(m, o));
    float lsum = 0.f;
    for (int j = lane; j < deg; j += 64) {
        float p = expf(ps[w][j] - m);  // exp(-inf) = 0 for dup slots
        ps[w][j] = p;
        lsum += p;
    }
#pragma unroll
    for (int o = 32; o >= 1; o >>= 1) lsum += __shfl_xor(lsum, o);
    // gather-aggregate: lane = feature d, unrolled x2 for load ILP
    const float* hb = h1 + (size_t)w * NN * NHID;
    float acc0 = 0.f, acc1 = 0.f;
    int j = 0;
    for (; j + 2 <= deg; j += 2) {
        float p0 = ps[w][j], p1 = ps[w][j + 1];
        int t0 = ts[j], t1 = ts[j + 1];
        acc0 += p0 * hb[(size_t)t0 * NHID + lane];
        acc1 += p1 * hb[(size_t)t1 * NHID + lane];
    }
    if (j < deg) acc0 += ps[w][j] * hb[(size_t)ts[j] * NHID + lane];
    float v = (acc0 + acc1) / lsum;
    v = v > 0.f ? v : (expf(v) - 1.f);  // ELU
    hcat[(size_t)n * (NHID * NHEADS) + w * NHID + lane] = v;
}

// h2[n][c] = b2[c] + sum_k hcat[n][k] * W2[c][k]; fused as2/at2 scores.
__global__ void gemm2(const float* __restrict__ hcat, const float* __restrict__ W2,
                      const float* __restrict__ b2, float* __restrict__ h2,
                      const float* __restrict__ a2, float* __restrict__ as2,
                      float* __restrict__ at2) {
    __shared__ float hs[16][260];
    __shared__ float ws[16][260];
    int t = threadIdx.x;
    int n0 = blockIdx.x * 16;
#pragma unroll
    for (int i = 0; i < 16; i++) {
        hs[i][t] = hcat[(size_t)(n0 + i) * 256 + t];
        ws[i][t] = W2[i * 256 + t];
    }
    __syncthreads();
    int nl = t >> 4, c = t & 15;
    const float4* hr = (const float4*)&hs[nl][0];
    const float4* wr = (const float4*)&ws[c][0];
    float dot = 0.f;
#pragma unroll 4
    for (int k4 = 0; k4 < 64; k4++) {
        float4 a = hr[k4], b = wr[k4];
        dot += a.x * b.x + a.y * b.y + a.z * b.z + a.w * b.w;
    }
    float v = dot + b2[c];
    h2[(size_t)(n0 + nl) * NCLASS + c] = v;
    float s1 = v * a2[c], s2 = v * a2[NCLASS + c];
#pragma unroll
    for (int o = 8; o >= 1; o >>= 1) {
        s1 += __shfl_xor(s1, o);
        s2 += __shfl_xor(s2, o);
    }
    if (c == 0) { as2[n0 + nl] = s1; at2[n0 + nl] = s2; }
}

// second GAT conv (16 classes) fused with log_softmax -> d_out
__global__ void agg2(const float* __restrict__ h2, const float* __restrict__ as2,
                     const float* __restrict__ at2, const int* __restrict__ rowptr,
                     const int* __restrict__ csr, float* __restrict__ out) {
    __shared__ int ts[MAXDEG];
    __shared__ float ss[MAXDEG];
    __shared__ float ps[MAXDEG];
    __shared__ float red[8];
    __shared__ float partial[4][NCLASS];
    int n = blockIdx.x;
    int tid = threadIdx.x;
    int w = tid >> 6;
    int lane = tid & 63;
    int r0 = rowptr[n];
    int deg = rowptr[n + 1] - r0;
    if (deg > MAXDEG) deg = MAXDEG;
    if (deg == 0) {
        if (tid < NCLASS) out[(size_t)n * NCLASS + tid] = -logf((float)NCLASS);
        return;
    }
    float asv = as2[n];
    for (int j = tid; j < deg; j += 256) {
        int tj = csr[r0 + j];
        ts[j] = tj;
        float e = asv + at2[tj];
        ss[j] = e > 0.f ? e : LRELU_ALPHA * e;
    }
    __syncthreads();
    for (int j = tid; j < deg; j += 256) {
        int tj = ts[j];
        float s = ss[j];
        bool skip = false;
        for (int j2 = 0; j2 < deg; j2++) {
            if (j2 == j) continue;
            if (ts[j2] == tj) {
                if (j2 < j) { skip = true; break; }
                s += ss[j2];
            }
        }
        ps[j] = skip ? -INFINITY : s;
    }
    __syncthreads();
    float m = -INFINITY;
    for (int j = tid; j < deg; j += 256) m = fmaxf(m, ps[j]);
#pragma unroll
    for (int o = 32; o >= 1; o >>= 1) m = fmaxf(m, __shfl_xor(m, o));
    if (lane == 0) red[w] = m;
    __syncthreads();
    m = fmaxf(fmaxf(red[0], red[1]), fmaxf(red[2], red[3]));
    float s = 0.f;
    for (int j = tid; j < deg; j += 256) {
        float p = expf(ps[j] - m);
        ps[j] = p;
        s += p;
    }
#pragma unroll
    for (int o = 32; o >= 1; o >>= 1) s += __shfl_xor(s, o);
    if (lane == 0) red[4 + w] = s;
    __syncthreads();
    float lsum = red[4] + red[5] + red[6] + red[7];
    int jg = lane >> 4, c = lane & 15;
    float acc = 0.f;
    for (int j = w * 4 + jg; j < deg; j += 16)
        acc += ps[j] * h2[(size_t)ts[j] * NCLASS + c];
    acc += __shfl_xor(acc, 16);
    acc += __shfl_xor(acc, 32);
    if (lane < NCLASS) partial[w][lane] = acc;
    __syncthreads();
    if (tid < NCLASS) {
        float v = (partial[0][tid] + partial[1][tid] + partial[2][tid] + partial[3][tid]) / lsum;
        float mm = v;
#pragma unroll
        for (int o = 8; o >= 1; o >>= 1) mm = fmaxf(mm, __shfl_xor(mm, o));
        float se = expf(v - mm);
#pragma unroll
        for (int o = 8; o >= 1; o >>= 1) se += __shfl_xor(se, o);
        out[(size_t)n * NCLASS + tid] = v - mm - logf(se);
    }
}

extern "C" void kernel_launch(void* const* d_in, const int* in_sizes, int n_in,
                              void* d_out, int out_size, void* d_ws, size_t ws_size,
                              hipStream_t stream) {
    const float* x  = (const float*)d_in[0];
    const int* el   = (const int*)d_in[1];
    const float* W1 = (const float*)d_in[2];
    const float* b1 = (const float*)d_in[3];
    const float* a1 = (const float*)d_in[4];
    const float* W2 = (const float*)d_in[5];
    const float* b2 = (const float*)d_in[6];
    const float* a2 = (const float*)d_in[7];
    float* out = (float*)d_out;

    float* h1   = (float*)d_ws;               // 4*8192*64 = 2097152
    float* hcat = h1 + 2097152;               // 8192*256  = 2097152
    float* h2   = hcat + 2097152;             // 8192*16   = 131072
    float* as1  = h2 + 131072;                // 4*8192
    float* at1  = as1 + 32768;                // 4*8192
    float* as2  = at1 + 32768;                // 8192
    float* at2  = as2 + 8192;                 // 8192
    int* deg    = (int*)(at2 + 8192);         // 8192
    int* rowptr = deg + 8192;                 // 8193 (+pad)
    int* cursor = rowptr + 8200;              // 8192
    int* csr    = cursor + 8192;              // 262144
    unsigned short* Wbf = (unsigned short*)(csr + 262144);  // 512*256 bf16 = 256KB (16B-aligned)

    const int* src = el;
    const int* tgt = el + NEDGE;

    hipMemsetAsync(deg, 0, NN * sizeof(int), stream);
    buildWbf<<<64, 256, 0, stream>>>(W1, Wbf);
    gemm1<<<NN / 16, 256, 0, stream>>>(x, Wbf, b1, h1, a1, as1, at1);
    count_deg<<<NEDGE / 256, 256, 0, stream>>>(src, deg);
    scan8192<<<1, 256, 0, stream>>>(deg, rowptr, cursor);
    fill_csr<<<NEDGE / 256, 256, 0, stream>>>(src, tgt, cursor, csr);
    agg1<<<NN, 256, 0, stream>>>(h1, as1, at1, rowptr, csr, hcat);
    gemm2<<<NN / 16, 256, 0, stream>>>(hcat, W2, b2, h2, a2, as2, at2);
    agg2<<<NN, 256, 0, stream>>>(h2, as2, at2, rowptr, csr, out);
}

// Round 5
// 135.225 us; speedup vs baseline: 1.9318x; 1.1296x over previous
//
#include <hip/hip_runtime.h>
#include <math.h>

#define NN 8192
#define NFEAT 512
#define NHID 64
#define NHEADS 4
#define NCLASS 16
#define NEDGE 262144
#define LRELU_ALPHA 0.2f
#define MAXDEG 192

typedef __attribute__((ext_vector_type(8))) short short8;
typedef __attribute__((ext_vector_type(8))) unsigned short ushort8;
typedef __attribute__((ext_vector_type(4))) float f32x4;

__device__ __forceinline__ unsigned short bfr(float f) {
    unsigned int u = __float_as_uint(f);
    u += 0x7fffu + ((u >> 16) & 1u);   // round-to-nearest-even
    return (unsigned short)(u >> 16);
}
__device__ __forceinline__ float bf2f(unsigned short u) {
    return __uint_as_float(((unsigned int)u) << 16);
}

// Wbf[((ks*16 + nt)*64 + lane)*8 + i] = bf16(W1[nt*16 + (lane&15)][ks*32 + (lane>>4)*8 + i])
__global__ void buildWbf(const float* __restrict__ W1, unsigned short* __restrict__ Wbf) {
    int idx = blockIdx.x * 256 + threadIdx.x;   // 16384 total
    int lane = idx & 63, nt = (idx >> 6) & 15, ks = idx >> 10;
    int tfeat = nt * 16 + (lane & 15);
    int k0 = ks * 32 + (lane >> 4) * 8;
    const float* src = W1 + (size_t)tfeat * NFEAT + k0;
    float4 lo = *(const float4*)src;
    float4 hi = *(const float4*)(src + 4);
    ushort8 v;
    v[0] = bfr(lo.x); v[1] = bfr(lo.y); v[2] = bfr(lo.z); v[3] = bfr(lo.w);
    v[4] = bfr(hi.x); v[5] = bfr(hi.y); v[6] = bfr(hi.z); v[7] = bfr(hi.w);
    *(ushort8*)(Wbf + (size_t)idx * 8) = v;
}

// MFMA gemm1: h1b[h][n][d] (bf16) = b1 + x@W1^T, fused as1/at1 scores.
__global__ void gemm1(const float* __restrict__ x, const unsigned short* __restrict__ Wbf,
                      const float* __restrict__ b1, unsigned short* __restrict__ h1b,
                      const float* __restrict__ a1, float* __restrict__ as1,
                      float* __restrict__ at1) {
    __shared__ __align__(16) unsigned short xs[16 * 512];   // 16 KB, XOR-swizzled rows
    int t = threadIdx.x;
    int n0 = blockIdx.x * 16;
    const float4* xv = (const float4*)(x + (size_t)n0 * NFEAT);
#pragma unroll
    for (int i = 0; i < 4; i++) {
        int g = i * 256 + t;          // 1024 groups of 8 bf16 (16 B)
        int row = g >> 6;
        int k0 = (g & 63) * 8;
        float4 lo = xv[g * 2];
        float4 hi = xv[g * 2 + 1];
        ushort8 v;
        v[0] = bfr(lo.x); v[1] = bfr(lo.y); v[2] = bfr(lo.z); v[3] = bfr(lo.w);
        v[4] = bfr(hi.x); v[5] = bfr(hi.y); v[6] = bfr(hi.z); v[7] = bfr(hi.w);
        int byte = (k0 * 2) ^ ((row & 7) << 4);
        *(ushort8*)((char*)xs + row * 1024 + byte) = v;
    }
    __syncthreads();
    int w = t >> 6, lane = t & 63;
    int arow = lane & 15, kg = lane >> 4;
    f32x4 acc[4];
#pragma unroll
    for (int j = 0; j < 4; j++) acc[j] = (f32x4){0.f, 0.f, 0.f, 0.f};
    const unsigned short* wb = Wbf + ((size_t)(w * 4) * 64 + lane) * 8;
    int abase = arow * 1024;
    int aswz = (arow & 7) << 4;
    for (int ks = 0; ks < 16; ks++) {
        short8 afrag = *(const short8*)((const char*)xs + abase + ((ks * 64 + kg * 16) ^ aswz));
#pragma unroll
        for (int j = 0; j < 4; j++) {
            short8 bfrag = *(const short8*)(wb + j * 512);
            acc[j] = __builtin_amdgcn_mfma_f32_16x16x32_bf16(afrag, bfrag, acc[j], 0, 0, 0);
        }
        wb += 8192;
    }
    // epilogue: D col=lane&15 (feature within tile), row=(lane>>4)*4+reg (node)
    int g4 = lane >> 4, cf = lane & 15;
    float p1[4] = {0.f, 0.f, 0.f, 0.f}, p2[4] = {0.f, 0.f, 0.f, 0.f};
#pragma unroll
    for (int j = 0; j < 4; j++) {
        int d = j * 16 + cf;
        float bias = b1[w * 64 + d];
        float c1 = a1[w * 2 * NHID + d];
        float c2 = a1[w * 2 * NHID + NHID + d];
#pragma unroll
        for (int r = 0; r < 4; r++) {
            int n = n0 + g4 * 4 + r;
            float v = acc[j][r] + bias;
            h1b[((size_t)w * NN + n) * NHID + d] = bfr(v);
            p1[r] += v * c1;
            p2[r] += v * c2;
        }
    }
#pragma unroll
    for (int r = 0; r < 4; r++) {
        float s1 = p1[r], s2 = p2[r];
#pragma unroll
        for (int o = 8; o >= 1; o >>= 1) {
            s1 += __shfl_xor(s1, o);
            s2 += __shfl_xor(s2, o);
        }
        if (cf == 0) {
            int n = n0 + g4 * 4 + r;
            as1[w * NN + n] = s1;
            at1[w * NN + n] = s2;
        }
    }
}

__global__ void count_deg(const int* __restrict__ src, int* __restrict__ deg) {
    int k = blockIdx.x * blockDim.x + threadIdx.x;
    if (k < NEDGE) atomicAdd(&deg[src[k]], 1);
}

__global__ void scan8192(const int* __restrict__ deg, int* __restrict__ rowptr,
                         int* __restrict__ cursor) {
    __shared__ int part[256];
    __shared__ int base[256];
    int t = threadIdx.x;
    int s = 0;
#pragma unroll
    for (int i = 0; i < 32; i++) s += deg[t * 32 + i];
    part[t] = s;
    __syncthreads();
    if (t == 0) {
        int r = 0;
        for (int j = 0; j < 256; j++) { base[j] = r; r += part[j]; }
        rowptr[NN] = r;
    }
    __syncthreads();
    int r = base[t];
    for (int i = 0; i < 32; i++) {
        rowptr[t * 32 + i] = r;
        cursor[t * 32 + i] = r;
        r += deg[t * 32 + i];
    }
}

__global__ void fill_csr(const int* __restrict__ src, const int* __restrict__ tgt,
                         int* __restrict__ cursor, int* __restrict__ csr) {
    int k = blockIdx.x * blockDim.x + threadIdx.x;
    if (k < NEDGE) {
        int s = src[k];
        int p = atomicAdd(&cursor[s], 1);
        csr[p] = tgt[k];
    }
}

// one 256-thread block per row: 4 waves = 4 heads. Shared CSR + dup-combine,
// per-wave softmax + 8-edge-parallel bf16 gather-aggregate + ELU.
__global__ void agg1(const unsigned short* __restrict__ h1b, const float* __restrict__ as1,
                     const float* __restrict__ at1, const int* __restrict__ rowptr,
                     const int* __restrict__ csr, float* __restrict__ hcat) {
    __shared__ int ts[MAXDEG];
    __shared__ float ss[NHEADS][MAXDEG];
    __shared__ float ps[NHEADS][MAXDEG];
    int n = blockIdx.x;
    int tid = threadIdx.x;
    int w = tid >> 6;        // wave = head
    int lane = tid & 63;
    int r0 = rowptr[n];
    int deg = rowptr[n + 1] - r0;
    if (deg > MAXDEG) deg = MAXDEG;  // statistically impossible
    if (deg == 0) {                  // statistically impossible; avoid NaN
        hcat[(size_t)n * (NHID * NHEADS) + tid] = 0.f;
        return;
    }
    float asv0 = as1[0 * NN + n], asv1 = as1[1 * NN + n];
    float asv2 = as1[2 * NN + n], asv3 = as1[3 * NN + n];
    for (int j = tid; j < deg; j += 256) {
        int tj = csr[r0 + j];
        ts[j] = tj;
        float e0 = asv0 + at1[0 * NN + tj];
        float e1 = asv1 + at1[1 * NN + tj];
        float e2 = asv2 + at1[2 * NN + tj];
        float e3 = asv3 + at1[3 * NN + tj];
        ss[0][j] = e0 > 0.f ? e0 : LRELU_ALPHA * e0;
        ss[1][j] = e1 > 0.f ? e1 : LRELU_ALPHA * e1;
        ss[2][j] = e2 > 0.f ? e2 : LRELU_ALPHA * e2;
        ss[3][j] = e3 > 0.f ? e3 : LRELU_ALPHA * e3;
    }
    __syncthreads();
    // duplicate combine (structure shared by heads): first occurrence sums dups
    for (int j = tid; j < deg; j += 256) {
        int tj = ts[j];
        float s0 = ss[0][j], s1 = ss[1][j], s2 = ss[2][j], s3 = ss[3][j];
        bool skip = false;
        for (int j2 = 0; j2 < deg; j2++) {
            if (j2 == j) continue;
            if (ts[j2] == tj) {
                if (j2 < j) { skip = true; break; }
                s0 += ss[0][j2]; s1 += ss[1][j2]; s2 += ss[2][j2]; s3 += ss[3][j2];
            }
        }
        ps[0][j] = skip ? -INFINITY : s0;
        ps[1][j] = skip ? -INFINITY : s1;
        ps[2][j] = skip ? -INFINITY : s2;
        ps[3][j] = skip ? -INFINITY : s3;
    }
    __syncthreads();
    // per-wave (per-head) softmax over its own row (wave-synchronous LDS)
    float m = -INFINITY;
    for (int j = lane; j < deg; j += 64) m = fmaxf(m, ps[w][j]);
#pragma unroll
    for (int o = 32; o >= 1; o >>= 1) m = fmaxf(m, __shfl_xor(m, o));
    float lsum = 0.f;
    for (int j = lane; j < deg; j += 64) {
        float p = expf(ps[w][j] - m);  // exp(-inf) = 0 for dup slots
        ps[w][j] = p;
        lsum += p;
    }
#pragma unroll
    for (int o = 32; o >= 1; o >>= 1) lsum += __shfl_xor(lsum, o);
    // 8-edge-parallel gather: lane = eg*8 + dg; each lane loads ushort8
    // (features dg*8..dg*8+7) of row ts[j+eg]; wave covers 8 rows x 128 B.
    int eg = lane >> 3, dg = lane & 7;
    const unsigned short* hb = h1b + (size_t)w * NN * NHID;
    float acc[8] = {0.f, 0.f, 0.f, 0.f, 0.f, 0.f, 0.f, 0.f};
    for (int j = eg; j < deg; j += 8) {
        float p = ps[w][j];
        int tj = ts[j];
        ushort8 hv = *(const ushort8*)(hb + (size_t)tj * NHID + dg * 8);
#pragma unroll
        for (int i = 0; i < 8; i++) acc[i] += p * bf2f(hv[i]);
    }
#pragma unroll
    for (int i = 0; i < 8; i++) {
        float a = acc[i];
        a += __shfl_xor(a, 8);
        a += __shfl_xor(a, 16);
        a += __shfl_xor(a, 32);
        acc[i] = a;
    }
    // lane (eg,dg) writes feature dg*8+eg using acc[eg]
    float v = acc[eg] / lsum;
    v = v > 0.f ? v : (expf(v) - 1.f);  // ELU
    hcat[(size_t)n * (NHID * NHEADS) + w * NHID + dg * 8 + eg] = v;
}

// h2[n][c] = b2[c] + sum_k hcat[n][k] * W2[c][k]; fused as2/at2 scores.
__global__ void gemm2(const float* __restrict__ hcat, const float* __restrict__ W2,
                      const float* __restrict__ b2, float* __restrict__ h2,
                      const float* __restrict__ a2, float* __restrict__ as2,
                      float* __restrict__ at2) {
    __shared__ float hs[16][260];
    __shared__ float ws[16][260];
    int t = threadIdx.x;
    int n0 = blockIdx.x * 16;
#pragma unroll
    for (int i = 0; i < 16; i++) {
        hs[i][t] = hcat[(size_t)(n0 + i) * 256 + t];
        ws[i][t] = W2[i * 256 + t];
    }
    __syncthreads();
    int nl = t >> 4, c = t & 15;
    const float4* hr = (const float4*)&hs[nl][0];
    const float4* wr = (const float4*)&ws[c][0];
    float dot = 0.f;
#pragma unroll 4
    for (int k4 = 0; k4 < 64; k4++) {
        float4 a = hr[k4], b = wr[k4];
        dot += a.x * b.x + a.y * b.y + a.z * b.z + a.w * b.w;
    }
    float v = dot + b2[c];
    h2[(size_t)(n0 + nl) * NCLASS + c] = v;
    float s1 = v * a2[c], s2 = v * a2[NCLASS + c];
#pragma unroll
    for (int o = 8; o >= 1; o >>= 1) {
        s1 += __shfl_xor(s1, o);
        s2 += __shfl_xor(s2, o);
    }
    if (c == 0) { as2[n0 + nl] = s1; at2[n0 + nl] = s2; }
}

// second GAT conv (16 classes) fused with log_softmax -> d_out
__global__ void agg2(const float* __restrict__ h2, const float* __restrict__ as2,
                     const float* __restrict__ at2, const int* __restrict__ rowptr,
                     const int* __restrict__ csr, float* __restrict__ out) {
    __shared__ int ts[MAXDEG];
    __shared__ float ss[MAXDEG];
    __shared__ float ps[MAXDEG];
    __shared__ float red[8];
    __shared__ float partial[4][NCLASS];
    int n = blockIdx.x;
    int tid = threadIdx.x;
    int w = tid >> 6;
    int lane = tid & 63;
    int r0 = rowptr[n];
    int deg = rowptr[n + 1] - r0;
    if (deg > MAXDEG) deg = MAXDEG;
    if (deg == 0) {
        if (tid < NCLASS) out[(size_t)n * NCLASS + tid] = -logf((float)NCLASS);
        return;
    }
    float asv = as2[n];
    for (int j = tid; j < deg; j += 256) {
        int tj = csr[r0 + j];
        ts[j] = tj;
        float e = asv + at2[tj];
        ss[j] = e > 0.f ? e : LRELU_ALPHA * e;
    }
    __syncthreads();
    for (int j = tid; j < deg; j += 256) {
        int tj = ts[j];
        float s = ss[j];
        bool skip = false;
        for (int j2 = 0; j2 < deg; j2++) {
            if (j2 == j) continue;
            if (ts[j2] == tj) {
                if (j2 < j) { skip = true; break; }
                s += ss[j2];
            }
        }
        ps[j] = skip ? -INFINITY : s;
    }
    __syncthreads();
    float m = -INFINITY;
    for (int j = tid; j < deg; j += 256) m = fmaxf(m, ps[j]);
#pragma unroll
    for (int o = 32; o >= 1; o >>= 1) m = fmaxf(m, __shfl_xor(m, o));
    if (lane == 0) red[w] = m;
    __syncthreads();
    m = fmaxf(fmaxf(red[0], red[1]), fmaxf(red[2], red[3]));
    float s = 0.f;
    for (int j = tid; j < deg; j += 256) {
        float p = expf(ps[j] - m);
        ps[j] = p;
        s += p;
    }
#pragma unroll
    for (int o = 32; o >= 1; o >>= 1) s += __shfl_xor(s, o);
    if (lane == 0) red[4 + w] = s;
    __syncthreads();
    float lsum = red[4] + red[5] + red[6] + red[7];
    int jg = lane >> 4, c = lane & 15;
    float acc = 0.f;
    for (int j = w * 4 + jg; j < deg; j += 16)
        acc += ps[j] * h2[(size_t)ts[j] * NCLASS + c];
    acc += __shfl_xor(acc, 16);
    acc += __shfl_xor(acc, 32);
    if (lane < NCLASS) partial[w][lane] = acc;
    __syncthreads();
    if (tid < NCLASS) {
        float v = (partial[0][tid] + partial[1][tid] + partial[2][tid] + partial[3][tid]) / lsum;
        float mm = v;
#pragma unroll
        for (int o = 8; o >= 1; o >>= 1) mm = fmaxf(mm, __shfl_xor(mm, o));
        float se = expf(v - mm);
#pragma unroll
        for (int o = 8; o >= 1; o >>= 1) se += __shfl_xor(se, o);
        out[(size_t)n * NCLASS + tid] = v - mm - logf(se);
    }
}

extern "C" void kernel_launch(void* const* d_in, const int* in_sizes, int n_in,
                              void* d_out, int out_size, void* d_ws, size_t ws_size,
                              hipStream_t stream) {
    const float* x  = (const float*)d_in[0];
    const int* el   = (const int*)d_in[1];
    const float* W1 = (const float*)d_in[2];
    const float* b1 = (const float*)d_in[3];
    const float* a1 = (const float*)d_in[4];
    const float* W2 = (const float*)d_in[5];
    const float* b2 = (const float*)d_in[6];
    const float* a2 = (const float*)d_in[7];
    float* out = (float*)d_out;

    unsigned short* h1b = (unsigned short*)d_ws;  // 4*8192*64 bf16 = 4 MB (16B-aligned)
    float* hcat = (float*)(h1b + 2097152);        // 8192*256  = 2097152 floats
    float* h2   = hcat + 2097152;                 // 8192*16
    float* as1  = h2 + 131072;
    float* at1  = as1 + 32768;
    float* as2  = at1 + 32768;
    float* at2  = as2 + 8192;
    int* deg    = (int*)(at2 + 8192);
    int* rowptr = deg + 8192;
    int* cursor = rowptr + 8200;
    int* csr    = cursor + 8192;
    unsigned short* Wbf = (unsigned short*)(csr + 262144);  // 256KB

    const int* src = el;
    const int* tgt = el + NEDGE;

    hipMemsetAsync(deg, 0, NN * sizeof(int), stream);
    buildWbf<<<64, 256, 0, stream>>>(W1, Wbf);
    gemm1<<<NN / 16, 256, 0, stream>>>(x, Wbf, b1, h1b, a1, as1, at1);
    count_deg<<<NEDGE / 256, 256, 0, stream>>>(src, deg);
    scan8192<<<1, 256, 0, stream>>>(deg, rowptr, cursor);
    fill_csr<<<NEDGE / 256, 256, 0, stream>>>(src, tgt, cursor, csr);
    agg1<<<NN, 256, 0, stream>>>(h1b, as1, at1, rowptr, csr, hcat);
    gemm2<<<NN / 16, 256, 0, stream>>>(hcat, W2, b2, h2, a2, as2, at2);
    agg2<<<NN, 256, 0, stream>>>(h2, as2, at2, rowptr, csr, out);
}

// Round 6
// 116.523 us; speedup vs baseline: 2.2418x; 1.1605x over previous
//
#include <hip/hip_runtime.h>
#include <math.h>

#define NN 8192
#define NFEAT 512
#define NHID 64
#define NHEADS 4
#define NCLASS 16
#define NEDGE 262144
#define LRELU_ALPHA 0.2f
#define MAXDEG 192

typedef __attribute__((ext_vector_type(8))) short short8;
typedef __attribute__((ext_vector_type(8))) unsigned short ushort8;
typedef __attribute__((ext_vector_type(4))) float f32x4;

__device__ __forceinline__ unsigned short bfr(float f) {
    unsigned int u = __float_as_uint(f);
    u += 0x7fffu + ((u >> 16) & 1u);   // round-to-nearest-even
    return (unsigned short)(u >> 16);
}
__device__ __forceinline__ float bf2f(unsigned short u) {
    return __uint_as_float(((unsigned int)u) << 16);
}

// Wbf[((ks*16 + nt)*64 + lane)*8 + i] = bf16(W1[nt*16 + (lane&15)][ks*32 + (lane>>4)*8 + i])
__global__ void buildWbf(const float* __restrict__ W1, unsigned short* __restrict__ Wbf) {
    int idx = blockIdx.x * 256 + threadIdx.x;   // 16384 total
    int lane = idx & 63, nt = (idx >> 6) & 15, ks = idx >> 10;
    int tfeat = nt * 16 + (lane & 15);
    int k0 = ks * 32 + (lane >> 4) * 8;
    const float* src = W1 + (size_t)tfeat * NFEAT + k0;
    float4 lo = *(const float4*)src;
    float4 hi = *(const float4*)(src + 4);
    ushort8 v;
    v[0] = bfr(lo.x); v[1] = bfr(lo.y); v[2] = bfr(lo.z); v[3] = bfr(lo.w);
    v[4] = bfr(hi.x); v[5] = bfr(hi.y); v[6] = bfr(hi.z); v[7] = bfr(hi.w);
    *(ushort8*)(Wbf + (size_t)idx * 8) = v;
}

// MFMA gemm1: h1b[h][n][d] (bf16) = b1 + x@W1^T, fused scores (as1/at1 laid [n][4]).
__global__ void gemm1(const float* __restrict__ x, const unsigned short* __restrict__ Wbf,
                      const float* __restrict__ b1, unsigned short* __restrict__ h1b,
                      const float* __restrict__ a1, float* __restrict__ as1,
                      float* __restrict__ at1) {
    __shared__ __align__(16) unsigned short xs[16 * 512];   // 16 KB, XOR-swizzled rows
    int t = threadIdx.x;
    int n0 = blockIdx.x * 16;
    const float4* xv = (const float4*)(x + (size_t)n0 * NFEAT);
#pragma unroll
    for (int i = 0; i < 4; i++) {
        int g = i * 256 + t;          // 1024 groups of 8 bf16 (16 B)
        int row = g >> 6;
        int k0 = (g & 63) * 8;
        float4 lo = xv[g * 2];
        float4 hi = xv[g * 2 + 1];
        ushort8 v;
        v[0] = bfr(lo.x); v[1] = bfr(lo.y); v[2] = bfr(lo.z); v[3] = bfr(lo.w);
        v[4] = bfr(hi.x); v[5] = bfr(hi.y); v[6] = bfr(hi.z); v[7] = bfr(hi.w);
        int byte = (k0 * 2) ^ ((row & 7) << 4);
        *(ushort8*)((char*)xs + row * 1024 + byte) = v;
    }
    __syncthreads();
    int w = t >> 6, lane = t & 63;
    int arow = lane & 15, kg = lane >> 4;
    f32x4 acc[4];
#pragma unroll
    for (int j = 0; j < 4; j++) acc[j] = (f32x4){0.f, 0.f, 0.f, 0.f};
    const unsigned short* wb = Wbf + ((size_t)(w * 4) * 64 + lane) * 8;
    int abase = arow * 1024;
    int aswz = (arow & 7) << 4;
    for (int ks = 0; ks < 16; ks++) {
        short8 afrag = *(const short8*)((const char*)xs + abase + ((ks * 64 + kg * 16) ^ aswz));
#pragma unroll
        for (int j = 0; j < 4; j++) {
            short8 bfrag = *(const short8*)(wb + j * 512);
            acc[j] = __builtin_amdgcn_mfma_f32_16x16x32_bf16(afrag, bfrag, acc[j], 0, 0, 0);
        }
        wb += 8192;
    }
    // epilogue: D col=lane&15 (feature within tile), row=(lane>>4)*4+reg (node)
    int g4 = lane >> 4, cf = lane & 15;
    float p1[4] = {0.f, 0.f, 0.f, 0.f}, p2[4] = {0.f, 0.f, 0.f, 0.f};
#pragma unroll
    for (int j = 0; j < 4; j++) {
        int d = j * 16 + cf;
        float bias = b1[w * 64 + d];
        float c1 = a1[w * 2 * NHID + d];
        float c2 = a1[w * 2 * NHID + NHID + d];
#pragma unroll
        for (int r = 0; r < 4; r++) {
            int n = n0 + g4 * 4 + r;
            float v = acc[j][r] + bias;
            h1b[((size_t)w * NN + n) * NHID + d] = bfr(v);
            p1[r] += v * c1;
            p2[r] += v * c2;
        }
    }
#pragma unroll
    for (int r = 0; r < 4; r++) {
        float s1 = p1[r], s2 = p2[r];
#pragma unroll
        for (int o = 8; o >= 1; o >>= 1) {
            s1 += __shfl_xor(s1, o);
            s2 += __shfl_xor(s2, o);
        }
        if (cf == 0) {
            int n = n0 + g4 * 4 + r;
            as1[n * 4 + w] = s1;
            at1[n * 4 + w] = s2;
        }
    }
}

__global__ void count_deg(const int* __restrict__ src, int* __restrict__ deg) {
    int k = blockIdx.x * blockDim.x + threadIdx.x;
    if (k < NEDGE) atomicAdd(&deg[src[k]], 1);
}

__global__ void scan8192(const int* __restrict__ deg, int* __restrict__ rowptr,
                         int* __restrict__ cursor) {
    __shared__ int part[256];
    __shared__ int base[256];
    int t = threadIdx.x;
    int s = 0;
#pragma unroll
    for (int i = 0; i < 32; i++) s += deg[t * 32 + i];
    part[t] = s;
    __syncthreads();
    if (t == 0) {
        int r = 0;
        for (int j = 0; j < 256; j++) { base[j] = r; r += part[j]; }
        rowptr[NN] = r;
    }
    __syncthreads();
    int r = base[t];
    for (int i = 0; i < 32; i++) {
        rowptr[t * 32 + i] = r;
        cursor[t * 32 + i] = r;
        r += deg[t * 32 + i];
    }
}

__global__ void fill_csr(const int* __restrict__ src, const int* __restrict__ tgt,
                         int* __restrict__ cursor, int* __restrict__ csr) {
    int k = blockIdx.x * blockDim.x + threadIdx.x;
    if (k < NEDGE) {
        int s = src[k];
        int p = atomicAdd(&cursor[s], 1);
        csr[p] = tgt[k];
    }
}

// one 256-thread block per row: 4 waves = 4 heads.
// Dup insight: duplicate (src,tgt) edges have IDENTICAL scores, so the
// scatter-add sum over dups = mult * leaky(e). The dup pass is structure-only
// and writes packed (tgt | mult<<16, or -1 for dup slots) back into csr for
// agg2 to reuse. Gather: bf16, 8-edge lanes, 4-deep load pipeline.
__global__ void agg1(const unsigned short* __restrict__ h1b, const float* __restrict__ as1,
                     const float* __restrict__ at1, const int* __restrict__ rowptr,
                     int* __restrict__ csr, float* __restrict__ hcat) {
    __shared__ int ts[MAXDEG];
    __shared__ float ps[NHEADS][MAXDEG];
    int n = blockIdx.x;
    int tid = threadIdx.x;
    int w = tid >> 6;        // wave = head
    int lane = tid & 63;
    int r0 = rowptr[n];
    int deg = rowptr[n + 1] - r0;
    if (deg > MAXDEG) deg = MAXDEG;  // statistically impossible
    if (deg == 0) {                  // statistically impossible; avoid NaN
        hcat[(size_t)n * (NHID * NHEADS) + tid] = 0.f;
        return;
    }
    float4 asv = *(const float4*)(as1 + n * 4);
    for (int j = tid; j < deg; j += 256) {
        int tj = csr[r0 + j];
        ts[j] = tj;
        float4 atv = *(const float4*)(at1 + tj * 4);
        float e0 = asv.x + atv.x, e1 = asv.y + atv.y;
        float e2 = asv.z + atv.z, e3 = asv.w + atv.w;
        ps[0][j] = e0 > 0.f ? e0 : LRELU_ALPHA * e0;
        ps[1][j] = e1 > 0.f ? e1 : LRELU_ALPHA * e1;
        ps[2][j] = e2 > 0.f ? e2 : LRELU_ALPHA * e2;
        ps[3][j] = e3 > 0.f ? e3 : LRELU_ALPHA * e3;
    }
    __syncthreads();
    // structure-only dup pass: count multiplicity, mark non-first as -inf;
    // write packed csr for agg2.
    for (int j = tid; j < deg; j += 256) {
        int tj = ts[j];
        int m = 1;
        bool skip = false;
        for (int j2 = 0; j2 < deg; j2++) {
            if (j2 == j) continue;
            if (ts[j2] == tj) {
                if (j2 < j) { skip = true; break; }
                m++;
            }
        }
        if (skip) {
            ps[0][j] = -INFINITY; ps[1][j] = -INFINITY;
            ps[2][j] = -INFINITY; ps[3][j] = -INFINITY;
            csr[r0 + j] = -1;
        } else {
            float mf = (float)m;
            ps[0][j] *= mf; ps[1][j] *= mf; ps[2][j] *= mf; ps[3][j] *= mf;
            csr[r0 + j] = tj | (m << 16);
        }
    }
    __syncthreads();
    // per-wave (per-head) softmax (wave-synchronous LDS)
    float m = -INFINITY;
    for (int j = lane; j < deg; j += 64) m = fmaxf(m, ps[w][j]);
#pragma unroll
    for (int o = 32; o >= 1; o >>= 1) m = fmaxf(m, __shfl_xor(m, o));
    float lsum = 0.f;
    for (int j = lane; j < deg; j += 64) {
        float p = expf(ps[w][j] - m);  // exp(-inf) = 0 for dup slots
        ps[w][j] = p;
        lsum += p;
    }
#pragma unroll
    for (int o = 32; o >= 1; o >>= 1) lsum += __shfl_xor(lsum, o);
    // gather: lane = eg*8 + dg; 4-deep load pipeline (32 edges in flight/wave)
    int eg = lane >> 3, dg = lane & 7;
    const unsigned short* hb = h1b + (size_t)w * NN * NHID;
    float acc[8] = {0.f, 0.f, 0.f, 0.f, 0.f, 0.f, 0.f, 0.f};
    for (int j0 = 0; j0 < deg; j0 += 32) {
        int ja = j0 + eg, jb = j0 + 8 + eg, jc = j0 + 16 + eg, jd = j0 + 24 + eg;
        float pa = 0.f, pb = 0.f, pc = 0.f, pd = 0.f;
        int ta = 0, tb = 0, tc = 0, td = 0;
        if (ja < deg) { pa = ps[w][ja]; ta = ts[ja]; }
        if (jb < deg) { pb = ps[w][jb]; tb = ts[jb]; }
        if (jc < deg) { pc = ps[w][jc]; tc = ts[jc]; }
        if (jd < deg) { pd = ps[w][jd]; td = ts[jd]; }
        ushort8 ha = *(const ushort8*)(hb + (size_t)ta * NHID + dg * 8);
        ushort8 hbv = *(const ushort8*)(hb + (size_t)tb * NHID + dg * 8);
        ushort8 hc = *(const ushort8*)(hb + (size_t)tc * NHID + dg * 8);
        ushort8 hd = *(const ushort8*)(hb + (size_t)td * NHID + dg * 8);
#pragma unroll
        for (int i = 0; i < 8; i++)
            acc[i] += pa * bf2f(ha[i]) + pb * bf2f(hbv[i])
                    + pc * bf2f(hc[i]) + pd * bf2f(hd[i]);
    }
#pragma unroll
    for (int i = 0; i < 8; i++) {
        float a = acc[i];
        a += __shfl_xor(a, 8);
        a += __shfl_xor(a, 16);
        a += __shfl_xor(a, 32);
        acc[i] = a;
    }
    float v = acc[eg] / lsum;
    v = v > 0.f ? v : (expf(v) - 1.f);  // ELU
    hcat[(size_t)n * (NHID * NHEADS) + w * NHID + dg * 8 + eg] = v;
}

// h2[n][c] = b2[c] + sum_k hcat[n][k] * W2[c][k]; fused as2/at2 scores.
__global__ void gemm2(const float* __restrict__ hcat, const float* __restrict__ W2,
                      const float* __restrict__ b2, float* __restrict__ h2,
                      const float* __restrict__ a2, float* __restrict__ as2,
                      float* __restrict__ at2) {
    __shared__ float hs[16][260];
    __shared__ float ws[16][260];
    int t = threadIdx.x;
    int n0 = blockIdx.x * 16;
#pragma unroll
    for (int i = 0; i < 16; i++) {
        hs[i][t] = hcat[(size_t)(n0 + i) * 256 + t];
        ws[i][t] = W2[i * 256 + t];
    }
    __syncthreads();
    int nl = t >> 4, c = t & 15;
    const float4* hr = (const float4*)&hs[nl][0];
    const float4* wr = (const float4*)&ws[c][0];
    float dot = 0.f;
#pragma unroll 4
    for (int k4 = 0; k4 < 64; k4++) {
        float4 a = hr[k4], b = wr[k4];
        dot += a.x * b.x + a.y * b.y + a.z * b.z + a.w * b.w;
    }
    float v = dot + b2[c];
    h2[(size_t)(n0 + nl) * NCLASS + c] = v;
    float s1 = v * a2[c], s2 = v * a2[NCLASS + c];
#pragma unroll
    for (int o = 8; o >= 1; o >>= 1) {
        s1 += __shfl_xor(s1, o);
        s2 += __shfl_xor(s2, o);
    }
    if (c == 0) { as2[n0 + nl] = s1; at2[n0 + nl] = s2; }
}

// second GAT conv (16 classes) + log_softmax. Reads PACKED csr from agg1
// (no O(deg^2) pass). Gather: float4 classes, 16 edges in flight per wave.
__global__ void agg2(const float* __restrict__ h2, const float* __restrict__ as2,
                     const float* __restrict__ at2, const int* __restrict__ rowptr,
                     const int* __restrict__ csrp, float* __restrict__ out) {
    __shared__ int ts[MAXDEG];
    __shared__ float ps[MAXDEG];
    __shared__ float red[8];
    __shared__ float partial[4][NCLASS];
    int n = blockIdx.x;
    int tid = threadIdx.x;
    int w = tid >> 6;
    int lane = tid & 63;
    int r0 = rowptr[n];
    int deg = rowptr[n + 1] - r0;
    if (deg > MAXDEG) deg = MAXDEG;
    if (deg == 0) {
        if (tid < NCLASS) out[(size_t)n * NCLASS + tid] = -logf((float)NCLASS);
        return;
    }
    float asv = as2[n];
    for (int j = tid; j < deg; j += 256) {
        int pk = csrp[r0 + j];
        int tj = pk < 0 ? 0 : (pk & 0xFFFF);
        ts[j] = tj;
        if (pk < 0) {
            ps[j] = -INFINITY;
        } else {
            float e = asv + at2[tj];
            e = e > 0.f ? e : LRELU_ALPHA * e;
            ps[j] = (float)(pk >> 16) * e;
        }
    }
    __syncthreads();
    float m = -INFINITY;
    for (int j = tid; j < deg; j += 256) m = fmaxf(m, ps[j]);
#pragma unroll
    for (int o = 32; o >= 1; o >>= 1) m = fmaxf(m, __shfl_xor(m, o));
    if (lane == 0) red[w] = m;
    __syncthreads();
    m = fmaxf(fmaxf(red[0], red[1]), fmaxf(red[2], red[3]));
    float s = 0.f;
    for (int j = tid; j < deg; j += 256) {
        float p = expf(ps[j] - m);
        ps[j] = p;
        s += p;
    }
#pragma unroll
    for (int o = 32; o >= 1; o >>= 1) s += __shfl_xor(s, o);
    if (lane == 0) red[4 + w] = s;
    __syncthreads();   // also publishes ps[] writes
    float lsum = red[4] + red[5] + red[6] + red[7];
    // gather: lane = jg*4 + cq; each lane loads float4 (classes cq*4..cq*4+3)
    int jg = lane >> 2, cq = lane & 3;
    float4 a4 = {0.f, 0.f, 0.f, 0.f};
    for (int j = w * 16 + jg; j < deg; j += 64) {
        float p = ps[j];
        float4 hv = *(const float4*)(h2 + (size_t)ts[j] * NCLASS + cq * 4);
        a4.x += p * hv.x; a4.y += p * hv.y; a4.z += p * hv.z; a4.w += p * hv.w;
    }
#pragma unroll
    for (int o = 4; o <= 32; o <<= 1) {
        a4.x += __shfl_xor(a4.x, o);
        a4.y += __shfl_xor(a4.y, o);
        a4.z += __shfl_xor(a4.z, o);
        a4.w += __shfl_xor(a4.w, o);
    }
    if (jg == 0) {
        partial[w][cq * 4 + 0] = a4.x;
        partial[w][cq * 4 + 1] = a4.y;
        partial[w][cq * 4 + 2] = a4.z;
        partial[w][cq * 4 + 3] = a4.w;
    }
    __syncthreads();
    if (tid < NCLASS) {
        float v = (partial[0][tid] + partial[1][tid] + partial[2][tid] + partial[3][tid]) / lsum;
        float mm = v;
#pragma unroll
        for (int o = 8; o >= 1; o >>= 1) mm = fmaxf(mm, __shfl_xor(mm, o));
        float se = expf(v - mm);
#pragma unroll
        for (int o = 8; o >= 1; o >>= 1) se += __shfl_xor(se, o);
        out[(size_t)n * NCLASS + tid] = v - mm - logf(se);
    }
}

extern "C" void kernel_launch(void* const* d_in, const int* in_sizes, int n_in,
                              void* d_out, int out_size, void* d_ws, size_t ws_size,
                              hipStream_t stream) {
    const float* x  = (const float*)d_in[0];
    const int* el   = (const int*)d_in[1];
    const float* W1 = (const float*)d_in[2];
    const float* b1 = (const float*)d_in[3];
    const float* a1 = (const float*)d_in[4];
    const float* W2 = (const float*)d_in[5];
    const float* b2 = (const float*)d_in[6];
    const float* a2 = (const float*)d_in[7];
    float* out = (float*)d_out;

    unsigned short* h1b = (unsigned short*)d_ws;  // 4*8192*64 bf16 = 4 MB
    float* hcat = (float*)(h1b + 2097152);        // 8192*256 floats
    float* h2   = hcat + 2097152;                 // 8192*16
    float* as1  = h2 + 131072;                    // [n][4] = 32768
    float* at1  = as1 + 32768;                    // [n][4] = 32768
    float* as2  = at1 + 32768;
    float* at2  = as2 + 8192;
    int* deg    = (int*)(at2 + 8192);
    int* rowptr = deg + 8192;
    int* cursor = rowptr + 8200;
    int* csr    = cursor + 8192;
    unsigned short* Wbf = (unsigned short*)(csr + 262144);  // 256KB

    const int* src = el;
    const int* tgt = el + NEDGE;

    hipMemsetAsync(deg, 0, NN * sizeof(int), stream);
    buildWbf<<<64, 256, 0, stream>>>(W1, Wbf);
    gemm1<<<NN / 16, 256, 0, stream>>>(x, Wbf, b1, h1b, a1, as1, at1);
    count_deg<<<NEDGE / 256, 256, 0, stream>>>(src, deg);
    scan8192<<<1, 256, 0, stream>>>(deg, rowptr, cursor);
    fill_csr<<<NEDGE / 256, 256, 0, stream>>>(src, tgt, cursor, csr);
    agg1<<<NN, 256, 0, stream>>>(h1b, as1, at1, rowptr, csr, hcat);
    gemm2<<<NN / 16, 256, 0, stream>>>(hcat, W2, b2, h2, a2, as2, at2);
    agg2<<<NN, 256, 0, stream>>>(h2, as2, at2, rowptr, csr, out);
}

// Round 7
// 88.451 us; speedup vs baseline: 2.9533x; 1.3174x over previous
//
#include <hip/hip_runtime.h>
#include <math.h>

#define NN 8192
#define NFEAT 512
#define NHID 64
#define NHEADS 4
#define NCLASS 16
#define NEDGE 262144
#define LRELU_ALPHA 0.2f
#define MAXDEG 192

typedef __attribute__((ext_vector_type(8))) short short8;
typedef __attribute__((ext_vector_type(8))) unsigned short ushort8;
typedef __attribute__((ext_vector_type(4))) float f32x4;

__device__ __forceinline__ unsigned short bfr(float f) {
    unsigned int u = __float_as_uint(f);
    u += 0x7fffu + ((u >> 16) & 1u);   // round-to-nearest-even
    return (unsigned short)(u >> 16);
}
__device__ __forceinline__ float bf2f(unsigned short u) {
    return __uint_as_float(((unsigned int)u) << 16);
}

// Wbf[((ks*16 + nt)*64 + lane)*8 + i] = bf16(W1[nt*16 + (lane&15)][ks*32 + (lane>>4)*8 + i])
__global__ void buildWbf(const float* __restrict__ W1, unsigned short* __restrict__ Wbf) {
    int idx = blockIdx.x * 256 + threadIdx.x;   // 16384 total
    int lane = idx & 63, nt = (idx >> 6) & 15, ks = idx >> 10;
    int tfeat = nt * 16 + (lane & 15);
    int k0 = ks * 32 + (lane >> 4) * 8;
    const float* src = W1 + (size_t)tfeat * NFEAT + k0;
    float4 lo = *(const float4*)src;
    float4 hi = *(const float4*)(src + 4);
    ushort8 v;
    v[0] = bfr(lo.x); v[1] = bfr(lo.y); v[2] = bfr(lo.z); v[3] = bfr(lo.w);
    v[4] = bfr(hi.x); v[5] = bfr(hi.y); v[6] = bfr(hi.z); v[7] = bfr(hi.w);
    *(ushort8*)(Wbf + (size_t)idx * 8) = v;
}

// MFMA gemm1: h1b[h][n][d] (bf16) = b1 + x@W1^T, fused scores (as1/at1 laid [n][4]).
__global__ void gemm1(const float* __restrict__ x, const unsigned short* __restrict__ Wbf,
                      const float* __restrict__ b1, unsigned short* __restrict__ h1b,
                      const float* __restrict__ a1, float* __restrict__ as1,
                      float* __restrict__ at1) {
    __shared__ __align__(16) unsigned short xs[16 * 512];   // 16 KB, XOR-swizzled rows
    int t = threadIdx.x;
    int n0 = blockIdx.x * 16;
    const float4* xv = (const float4*)(x + (size_t)n0 * NFEAT);
#pragma unroll
    for (int i = 0; i < 4; i++) {
        int g = i * 256 + t;          // 1024 groups of 8 bf16 (16 B)
        int row = g >> 6;
        int k0 = (g & 63) * 8;
        float4 lo = xv[g * 2];
        float4 hi = xv[g * 2 + 1];
        ushort8 v;
        v[0] = bfr(lo.x); v[1] = bfr(lo.y); v[2] = bfr(lo.z); v[3] = bfr(lo.w);
        v[4] = bfr(hi.x); v[5] = bfr(hi.y); v[6] = bfr(hi.z); v[7] = bfr(hi.w);
        int byte = (k0 * 2) ^ ((row & 7) << 4);
        *(ushort8*)((char*)xs + row * 1024 + byte) = v;
    }
    __syncthreads();
    int w = t >> 6, lane = t & 63;
    int arow = lane & 15, kg = lane >> 4;
    f32x4 acc[4];
#pragma unroll
    for (int j = 0; j < 4; j++) acc[j] = (f32x4){0.f, 0.f, 0.f, 0.f};
    const unsigned short* wb = Wbf + ((size_t)(w * 4) * 64 + lane) * 8;
    int abase = arow * 1024;
    int aswz = (arow & 7) << 4;
    for (int ks = 0; ks < 16; ks++) {
        short8 afrag = *(const short8*)((const char*)xs + abase + ((ks * 64 + kg * 16) ^ aswz));
#pragma unroll
        for (int j = 0; j < 4; j++) {
            short8 bfrag = *(const short8*)(wb + j * 512);
            acc[j] = __builtin_amdgcn_mfma_f32_16x16x32_bf16(afrag, bfrag, acc[j], 0, 0, 0);
        }
        wb += 8192;
    }
    // epilogue: D col=lane&15 (feature within tile), row=(lane>>4)*4+reg (node)
    int g4 = lane >> 4, cf = lane & 15;
    float p1[4] = {0.f, 0.f, 0.f, 0.f}, p2[4] = {0.f, 0.f, 0.f, 0.f};
#pragma unroll
    for (int j = 0; j < 4; j++) {
        int d = j * 16 + cf;
        float bias = b1[w * 64 + d];
        float c1 = a1[w * 2 * NHID + d];
        float c2 = a1[w * 2 * NHID + NHID + d];
#pragma unroll
        for (int r = 0; r < 4; r++) {
            int n = n0 + g4 * 4 + r;
            float v = acc[j][r] + bias;
            h1b[((size_t)w * NN + n) * NHID + d] = bfr(v);
            p1[r] += v * c1;
            p2[r] += v * c2;
        }
    }
#pragma unroll
    for (int r = 0; r < 4; r++) {
        float s1 = p1[r], s2 = p2[r];
#pragma unroll
        for (int o = 8; o >= 1; o >>= 1) {
            s1 += __shfl_xor(s1, o);
            s2 += __shfl_xor(s2, o);
        }
        if (cf == 0) {
            int n = n0 + g4 * 4 + r;
            as1[n * 4 + w] = s1;
            at1[n * 4 + w] = s2;
        }
    }
}

__global__ void count_deg(const int* __restrict__ src, int* __restrict__ deg) {
    int k = blockIdx.x * blockDim.x + threadIdx.x;
    if (k < NEDGE) atomicAdd(&deg[src[k]], 1);
}

__global__ void scan8192(const int* __restrict__ deg, int* __restrict__ rowptr,
                         int* __restrict__ cursor) {
    __shared__ int part[256];
    __shared__ int base[256];
    int t = threadIdx.x;
    int s = 0;
#pragma unroll
    for (int i = 0; i < 32; i++) s += deg[t * 32 + i];
    part[t] = s;
    __syncthreads();
    if (t == 0) {
        int r = 0;
        for (int j = 0; j < 256; j++) { base[j] = r; r += part[j]; }
        rowptr[NN] = r;
    }
    __syncthreads();
    int r = base[t];
    for (int i = 0; i < 32; i++) {
        rowptr[t * 32 + i] = r;
        cursor[t * 32 + i] = r;
        r += deg[t * 32 + i];
    }
}

__global__ void fill_csr(const int* __restrict__ src, const int* __restrict__ tgt,
                         int* __restrict__ cursor, int* __restrict__ csr) {
    int k = blockIdx.x * blockDim.x + threadIdx.x;
    if (k < NEDGE) {
        int s = src[k];
        int p = atomicAdd(&cursor[s], 1);
        csr[p] = tgt[k];
    }
}

// agg1: one WAVE per row (4 rows/block, no __syncthreads anywhere).
// Fast path (deg<=64): edge j in lane j registers; dup-combine via 63-step
// register rotation; per-head shuffle softmax; 8x8 bf16 gather with shuffle
// broadcast + 7-shuffle reduce-scatter. Writes packed csr (tgt|mult<<16, -1
// for dup slots) for agg2. Rare deg>64: wave-local LDS fallback.
__global__ void agg1(const unsigned short* __restrict__ h1b, const float* __restrict__ as1,
                     const float* __restrict__ at1, const int* __restrict__ rowptr,
                     int* __restrict__ csr, float* __restrict__ hcat) {
    __shared__ int tsf[4][MAXDEG];
    __shared__ float psf[4][NHEADS][MAXDEG];
    int wv = threadIdx.x >> 6, lane = threadIdx.x & 63;
    int n = blockIdx.x * 4 + wv;
    int r0 = rowptr[n];
    int deg = rowptr[n + 1] - r0;
    if (deg > MAXDEG) deg = MAXDEG;
    if (deg == 0) {
#pragma unroll
        for (int h = 0; h < 4; h++) hcat[(size_t)n * 256 + h * 64 + lane] = 0.f;
        return;
    }
    float4 asv = *(const float4*)(as1 + n * 4);
    int eg = lane >> 3, dg = lane & 7;
    if (deg <= 64) {
        int t = -1 - lane;               // unique negatives for invalid lanes
        float ea[4] = {0.f, 0.f, 0.f, 0.f};
        if (lane < deg) {
            t = csr[r0 + lane];
            float4 atv = *(const float4*)(at1 + t * 4);
            float e0 = asv.x + atv.x, e1 = asv.y + atv.y;
            float e2 = asv.z + atv.z, e3 = asv.w + atv.w;
            ea[0] = e0 > 0.f ? e0 : LRELU_ALPHA * e0;
            ea[1] = e1 > 0.f ? e1 : LRELU_ALPHA * e1;
            ea[2] = e2 > 0.f ? e2 : LRELU_ALPHA * e2;
            ea[3] = e3 > 0.f ? e3 : LRELU_ALPHA * e3;
        }
        // dup-combine: all-pairs via rotation
        int mult = 1;
        bool skip = false;
        for (int k = 1; k < 64; k++) {
            int idx = (lane + k) & 63;
            int to = __shfl(t, idx);
            if (to == t) { mult++; if (idx < lane) skip = true; }
        }
        if (lane < deg) csr[r0 + lane] = skip ? -1 : (t | (mult << 16));
        bool valid = (lane < deg) && !skip;
        float mf = (float)mult;
        // edge target list for gather (shared across heads)
        int tj[8];
#pragma unroll
        for (int i = 0; i < 8; i++) {
            int tv = __shfl(t, i * 8 + eg);
            tj[i] = tv < 0 ? 0 : tv;
        }
        bool b2 = (eg & 4) != 0, b1 = (eg & 2) != 0, b0 = (eg & 1) != 0;
        float outv[4];
#pragma unroll
        for (int h = 0; h < 4; h++) {
            float p = valid ? mf * ea[h] : -INFINITY;
            float m = p;
#pragma unroll
            for (int o = 32; o >= 1; o >>= 1) m = fmaxf(m, __shfl_xor(m, o));
            float pe = expf(p - m);
            float s = pe;
#pragma unroll
            for (int o = 32; o >= 1; o >>= 1) s += __shfl_xor(s, o);
            const unsigned short* hb = h1b + (size_t)h * NN * NHID;
            float acc[8] = {0.f, 0.f, 0.f, 0.f, 0.f, 0.f, 0.f, 0.f};
#pragma unroll
            for (int i = 0; i < 8; i++) {
                float pj = __shfl(pe, i * 8 + eg);
                ushort8 hv = *(const ushort8*)(hb + (size_t)tj[i] * NHID + dg * 8);
#pragma unroll
                for (int q = 0; q < 8; q++) acc[q] += pj * bf2f(hv[q]);
            }
            // reduce-scatter butterfly over eg: each lane ends with sum for idx=eg
            float k4[4], k2[2], r;
#pragma unroll
            for (int q = 0; q < 4; q++) {
                float keep = b2 ? acc[4 + q] : acc[q];
                float send = b2 ? acc[q] : acc[4 + q];
                k4[q] = keep + __shfl_xor(send, 32);
            }
#pragma unroll
            for (int q = 0; q < 2; q++) {
                float keep = b1 ? k4[2 + q] : k4[q];
                float send = b1 ? k4[q] : k4[2 + q];
                k2[q] = keep + __shfl_xor(send, 16);
            }
            {
                float keep = b0 ? k2[1] : k2[0];
                float send = b0 ? k2[0] : k2[1];
                r = keep + __shfl_xor(send, 8);
            }
            float v = r / s;
            outv[h] = v > 0.f ? v : (expf(v) - 1.f);   // ELU
        }
#pragma unroll
        for (int h = 0; h < 4; h++)
            hcat[(size_t)n * 256 + h * 64 + dg * 8 + eg] = outv[h];
    } else {
        // ---- wave-local LDS fallback (statistically never taken) ----
        int* ts = tsf[wv];
        for (int j = lane; j < deg; j += 64) {
            int tv = csr[r0 + j];
            ts[j] = tv;
            float4 atv = *(const float4*)(at1 + tv * 4);
            float e0 = asv.x + atv.x, e1 = asv.y + atv.y;
            float e2 = asv.z + atv.z, e3 = asv.w + atv.w;
            psf[wv][0][j] = e0 > 0.f ? e0 : LRELU_ALPHA * e0;
            psf[wv][1][j] = e1 > 0.f ? e1 : LRELU_ALPHA * e1;
            psf[wv][2][j] = e2 > 0.f ? e2 : LRELU_ALPHA * e2;
            psf[wv][3][j] = e3 > 0.f ? e3 : LRELU_ALPHA * e3;
        }
        for (int j = lane; j < deg; j += 64) {
            int tjv = ts[j];
            int m = 1;
            bool skip = false;
            for (int j2 = 0; j2 < deg; j2++) {
                if (j2 == j) continue;
                if (ts[j2] == tjv) {
                    if (j2 < j) { skip = true; break; }
                    m++;
                }
            }
            if (skip) {
                psf[wv][0][j] = -INFINITY; psf[wv][1][j] = -INFINITY;
                psf[wv][2][j] = -INFINITY; psf[wv][3][j] = -INFINITY;
                csr[r0 + j] = -1;
            } else {
                float mf = (float)m;
                psf[wv][0][j] *= mf; psf[wv][1][j] *= mf;
                psf[wv][2][j] *= mf; psf[wv][3][j] *= mf;
                csr[r0 + j] = tjv | (m << 16);
            }
        }
        for (int h = 0; h < 4; h++) {
            float m = -INFINITY;
            for (int j = lane; j < deg; j += 64) m = fmaxf(m, psf[wv][h][j]);
#pragma unroll
            for (int o = 32; o >= 1; o >>= 1) m = fmaxf(m, __shfl_xor(m, o));
            float s = 0.f;
            for (int j = lane; j < deg; j += 64) {
                float pe = expf(psf[wv][h][j] - m);
                psf[wv][h][j] = pe;
                s += pe;
            }
#pragma unroll
            for (int o = 32; o >= 1; o >>= 1) s += __shfl_xor(s, o);
            const unsigned short* hb = h1b + (size_t)h * NN * NHID;
            float acc[8] = {0.f, 0.f, 0.f, 0.f, 0.f, 0.f, 0.f, 0.f};
            for (int j = eg; j < deg; j += 8) {
                float pj = psf[wv][h][j];
                int tjv = ts[j];
                ushort8 hv = *(const ushort8*)(hb + (size_t)tjv * NHID + dg * 8);
#pragma unroll
                for (int q = 0; q < 8; q++) acc[q] += pj * bf2f(hv[q]);
            }
            bool b2 = (eg & 4) != 0, b1 = (eg & 2) != 0, b0 = (eg & 1) != 0;
            float k4[4], k2[2], r;
#pragma unroll
            for (int q = 0; q < 4; q++) {
                float keep = b2 ? acc[4 + q] : acc[q];
                float send = b2 ? acc[q] : acc[4 + q];
                k4[q] = keep + __shfl_xor(send, 32);
            }
#pragma unroll
            for (int q = 0; q < 2; q++) {
                float keep = b1 ? k4[2 + q] : k4[q];
                float send = b1 ? k4[q] : k4[2 + q];
                k2[q] = keep + __shfl_xor(send, 16);
            }
            {
                float keep = b0 ? k2[1] : k2[0];
                float send = b0 ? k2[0] : k2[1];
                r = keep + __shfl_xor(send, 8);
            }
            float v = r / s;
            v = v > 0.f ? v : (expf(v) - 1.f);
            hcat[(size_t)n * 256 + h * 64 + dg * 8 + eg] = v;
        }
    }
}

// h2[n][c] = b2[c] + sum_k hcat[n][k] * W2[c][k]; fused as2/at2 scores.
__global__ void gemm2(const float* __restrict__ hcat, const float* __restrict__ W2,
                      const float* __restrict__ b2, float* __restrict__ h2,
                      const float* __restrict__ a2, float* __restrict__ as2,
                      float* __restrict__ at2) {
    __shared__ float hs[16][260];
    __shared__ float ws[16][260];
    int t = threadIdx.x;
    int n0 = blockIdx.x * 16;
#pragma unroll
    for (int i = 0; i < 16; i++) {
        hs[i][t] = hcat[(size_t)(n0 + i) * 256 + t];
        ws[i][t] = W2[i * 256 + t];
    }
    __syncthreads();
    int nl = t >> 4, c = t & 15;
    const float4* hr = (const float4*)&hs[nl][0];
    const float4* wr = (const float4*)&ws[c][0];
    float dot = 0.f;
#pragma unroll 4
    for (int k4 = 0; k4 < 64; k4++) {
        float4 a = hr[k4], b = wr[k4];
        dot += a.x * b.x + a.y * b.y + a.z * b.z + a.w * b.w;
    }
    float v = dot + b2[c];
    h2[(size_t)(n0 + nl) * NCLASS + c] = v;
    float s1 = v * a2[c], s2 = v * a2[NCLASS + c];
#pragma unroll
    for (int o = 8; o >= 1; o >>= 1) {
        s1 += __shfl_xor(s1, o);
        s2 += __shfl_xor(s2, o);
    }
    if (c == 0) { as2[n0 + nl] = s1; at2[n0 + nl] = s2; }
}

// agg2: one WAVE per row, packed csr (no dup pass), fused log_softmax.
__global__ void agg2(const float* __restrict__ h2, const float* __restrict__ as2,
                     const float* __restrict__ at2, const int* __restrict__ rowptr,
                     const int* __restrict__ csrp, float* __restrict__ out) {
    __shared__ int tf[4][MAXDEG];
    __shared__ float pf[4][MAXDEG];
    int wv = threadIdx.x >> 6, lane = threadIdx.x & 63;
    int n = blockIdx.x * 4 + wv;
    int r0 = rowptr[n];
    int deg = rowptr[n + 1] - r0;
    if (deg > MAXDEG) deg = MAXDEG;
    if (deg == 0) {
        if (lane < NCLASS) out[(size_t)n * NCLASS + lane] = -logf((float)NCLASS);
        return;
    }
    float asvn = as2[n];
    int jg = lane >> 2, cq = lane & 3;
    if (deg <= 64) {
        int pk = (lane < deg) ? csrp[r0 + lane] : -1;
        int t = 0;
        float p = -INFINITY;
        if (pk >= 0) {
            t = pk & 0xFFFF;
            float e = asvn + at2[t];
            e = e > 0.f ? e : LRELU_ALPHA * e;
            p = (float)(pk >> 16) * e;
        }
        float m = p;
#pragma unroll
        for (int o = 32; o >= 1; o >>= 1) m = fmaxf(m, __shfl_xor(m, o));
        float pe = expf(p - m);
        float s = pe;
#pragma unroll
        for (int o = 32; o >= 1; o >>= 1) s += __shfl_xor(s, o);
        float4 a4 = {0.f, 0.f, 0.f, 0.f};
#pragma unroll
        for (int i = 0; i < 4; i++) {
            int j = i * 16 + jg;
            float pj = __shfl(pe, j);
            int tjv = __shfl(t, j);
            float4 hv = *(const float4*)(h2 + (size_t)tjv * NCLASS + cq * 4);
            a4.x += pj * hv.x; a4.y += pj * hv.y;
            a4.z += pj * hv.z; a4.w += pj * hv.w;
        }
#pragma unroll
        for (int o = 4; o <= 32; o <<= 1) {
            a4.x += __shfl_xor(a4.x, o);
            a4.y += __shfl_xor(a4.y, o);
            a4.z += __shfl_xor(a4.z, o);
            a4.w += __shfl_xor(a4.w, o);
        }
        float inv = 1.f / s;
        float4 v4 = {a4.x * inv, a4.y * inv, a4.z * inv, a4.w * inv};
        float mm = fmaxf(fmaxf(v4.x, v4.y), fmaxf(v4.z, v4.w));
        mm = fmaxf(mm, __shfl_xor(mm, 1));
        mm = fmaxf(mm, __shfl_xor(mm, 2));
        float se = expf(v4.x - mm) + expf(v4.y - mm) + expf(v4.z - mm) + expf(v4.w - mm);
        se += __shfl_xor(se, 1);
        se += __shfl_xor(se, 2);
        float lse = mm + logf(se);
        if (jg == 0) {
            float4 o4 = {v4.x - lse, v4.y - lse, v4.z - lse, v4.w - lse};
            *(float4*)(out + (size_t)n * NCLASS + cq * 4) = o4;
        }
    } else {
        // ---- wave-local LDS fallback ----
        for (int j = lane; j < deg; j += 64) {
            int pk = csrp[r0 + j];
            if (pk < 0) {
                tf[wv][j] = 0;
                pf[wv][j] = -INFINITY;
            } else {
                int t = pk & 0xFFFF;
                tf[wv][j] = t;
                float e = asvn + at2[t];
                e = e > 0.f ? e : LRELU_ALPHA * e;
                pf[wv][j] = (float)(pk >> 16) * e;
            }
        }
        float m = -INFINITY;
        for (int j = lane; j < deg; j += 64) m = fmaxf(m, pf[wv][j]);
#pragma unroll
        for (int o = 32; o >= 1; o >>= 1) m = fmaxf(m, __shfl_xor(m, o));
        float s = 0.f;
        for (int j = lane; j < deg; j += 64) {
            float pe = expf(pf[wv][j] - m);
            pf[wv][j] = pe;
            s += pe;
        }
#pragma unroll
        for (int o = 32; o >= 1; o >>= 1) s += __shfl_xor(s, o);
        float4 a4 = {0.f, 0.f, 0.f, 0.f};
        for (int j = jg; j < deg; j += 16) {
            float pj = pf[wv][j];
            float4 hv = *(const float4*)(h2 + (size_t)tf[wv][j] * NCLASS + cq * 4);
            a4.x += pj * hv.x; a4.y += pj * hv.y;
            a4.z += pj * hv.z; a4.w += pj * hv.w;
        }
#pragma unroll
        for (int o = 4; o <= 32; o <<= 1) {
            a4.x += __shfl_xor(a4.x, o);
            a4.y += __shfl_xor(a4.y, o);
            a4.z += __shfl_xor(a4.z, o);
            a4.w += __shfl_xor(a4.w, o);
        }
        float inv = 1.f / s;
        float4 v4 = {a4.x * inv, a4.y * inv, a4.z * inv, a4.w * inv};
        float mm = fmaxf(fmaxf(v4.x, v4.y), fmaxf(v4.z, v4.w));
        mm = fmaxf(mm, __shfl_xor(mm, 1));
        mm = fmaxf(mm, __shfl_xor(mm, 2));
        float se = expf(v4.x - mm) + expf(v4.y - mm) + expf(v4.z - mm) + expf(v4.w - mm);
        se += __shfl_xor(se, 1);
        se += __shfl_xor(se, 2);
        float lse = mm + logf(se);
        if (jg == 0) {
            float4 o4 = {v4.x - lse, v4.y - lse, v4.z - lse, v4.w - lse};
            *(float4*)(out + (size_t)n * NCLASS + cq * 4) = o4;
        }
    }
}

extern "C" void kernel_launch(void* const* d_in, const int* in_sizes, int n_in,
                              void* d_out, int out_size, void* d_ws, size_t ws_size,
                              hipStream_t stream) {
    const float* x  = (const float*)d_in[0];
    const int* el   = (const int*)d_in[1];
    const float* W1 = (const float*)d_in[2];
    const float* b1 = (const float*)d_in[3];
    const float* a1 = (const float*)d_in[4];
    const float* W2 = (const float*)d_in[5];
    const float* b2 = (const float*)d_in[6];
    const float* a2 = (const float*)d_in[7];
    float* out = (float*)d_out;

    unsigned short* h1b = (unsigned short*)d_ws;  // 4*8192*64 bf16 = 4 MB
    float* hcat = (float*)(h1b + 2097152);        // 8192*256 floats
    float* h2   = hcat + 2097152;                 // 8192*16
    float* as1  = h2 + 131072;                    // [n][4] = 32768
    float* at1  = as1 + 32768;                    // [n][4] = 32768
    float* as2  = at1 + 32768;
    float* at2  = as2 + 8192;
    int* deg    = (int*)(at2 + 8192);
    int* rowptr = deg + 8192;
    int* cursor = rowptr + 8200;
    int* csr    = cursor + 8192;
    unsigned short* Wbf = (unsigned short*)(csr + 262144);  // 256KB

    const int* src = el;
    const int* tgt = el + NEDGE;

    hipMemsetAsync(deg, 0, NN * sizeof(int), stream);
    buildWbf<<<64, 256, 0, stream>>>(W1, Wbf);
    gemm1<<<NN / 16, 256, 0, stream>>>(x, Wbf, b1, h1b, a1, as1, at1);
    count_deg<<<NEDGE / 256, 256, 0, stream>>>(src, deg);
    scan8192<<<1, 256, 0, stream>>>(deg, rowptr, cursor);
    fill_csr<<<NEDGE / 256, 256, 0, stream>>>(src, tgt, cursor, csr);
    agg1<<<NN / 4, 256, 0, stream>>>(h1b, as1, at1, rowptr, csr, hcat);
    gemm2<<<NN / 16, 256, 0, stream>>>(hcat, W2, b2, h2, a2, as2, at2);
    agg2<<<NN / 4, 256, 0, stream>>>(h2, as2, at2, rowptr, csr, out);
}

// Round 8
// 87.009 us; speedup vs baseline: 3.0023x; 1.0166x over previous
//
#include <hip/hip_runtime.h>
#include <math.h>

#define NN 8192
#define NFEAT 512
#define NHID 64
#define NHEADS 4
#define NCLASS 16
#define NEDGE 262144
#define LRELU_ALPHA 0.2f
#define MAXDEG 192

typedef __attribute__((ext_vector_type(8))) short short8;
typedef __attribute__((ext_vector_type(8))) unsigned short ushort8;
typedef __attribute__((ext_vector_type(4))) float f32x4;

__device__ __forceinline__ unsigned short bfr(float f) {
    unsigned int u = __float_as_uint(f);
    u += 0x7fffu + ((u >> 16) & 1u);   // round-to-nearest-even
    return (unsigned short)(u >> 16);
}
__device__ __forceinline__ float bf2f(unsigned short u) {
    return __uint_as_float(((unsigned int)u) << 16);
}

// Wbf[((ks*16 + nt)*64 + lane)*8 + i] = bf16(W1[nt*16 + (lane&15)][ks*32 + (lane>>4)*8 + i])
__global__ void buildWbf(const float* __restrict__ W1, unsigned short* __restrict__ Wbf) {
    int idx = blockIdx.x * 256 + threadIdx.x;   // 16384 total
    int lane = idx & 63, nt = (idx >> 6) & 15, ks = idx >> 10;
    int tfeat = nt * 16 + (lane & 15);
    int k0 = ks * 32 + (lane >> 4) * 8;
    const float* src = W1 + (size_t)tfeat * NFEAT + k0;
    float4 lo = *(const float4*)src;
    float4 hi = *(const float4*)(src + 4);
    ushort8 v;
    v[0] = bfr(lo.x); v[1] = bfr(lo.y); v[2] = bfr(lo.z); v[3] = bfr(lo.w);
    v[4] = bfr(hi.x); v[5] = bfr(hi.y); v[6] = bfr(hi.z); v[7] = bfr(hi.w);
    *(ushort8*)(Wbf + (size_t)idx * 8) = v;
}

__global__ void zero_deg(int* __restrict__ deg) {
    deg[blockIdx.x * 256 + threadIdx.x] = 0;
}

// MFMA gemm1: h1b[h][n][d] (bf16) = b1 + x@W1^T, fused scores (as1/at1 laid [n][4]).
__global__ void gemm1(const float* __restrict__ x, const unsigned short* __restrict__ Wbf,
                      const float* __restrict__ b1, unsigned short* __restrict__ h1b,
                      const float* __restrict__ a1, float* __restrict__ as1,
                      float* __restrict__ at1) {
    __shared__ __align__(16) unsigned short xs[16 * 512];   // 16 KB, XOR-swizzled rows
    int t = threadIdx.x;
    int n0 = blockIdx.x * 16;
    const float4* xv = (const float4*)(x + (size_t)n0 * NFEAT);
#pragma unroll
    for (int i = 0; i < 4; i++) {
        int g = i * 256 + t;          // 1024 groups of 8 bf16 (16 B)
        int row = g >> 6;
        int k0 = (g & 63) * 8;
        float4 lo = xv[g * 2];
        float4 hi = xv[g * 2 + 1];
        ushort8 v;
        v[0] = bfr(lo.x); v[1] = bfr(lo.y); v[2] = bfr(lo.z); v[3] = bfr(lo.w);
        v[4] = bfr(hi.x); v[5] = bfr(hi.y); v[6] = bfr(hi.z); v[7] = bfr(hi.w);
        int byte = (k0 * 2) ^ ((row & 7) << 4);
        *(ushort8*)((char*)xs + row * 1024 + byte) = v;
    }
    __syncthreads();
    int w = t >> 6, lane = t & 63;
    int arow = lane & 15, kg = lane >> 4;
    f32x4 acc[4];
#pragma unroll
    for (int j = 0; j < 4; j++) acc[j] = (f32x4){0.f, 0.f, 0.f, 0.f};
    const unsigned short* wb = Wbf + ((size_t)(w * 4) * 64 + lane) * 8;
    int abase = arow * 1024;
    int aswz = (arow & 7) << 4;
    for (int ks = 0; ks < 16; ks++) {
        short8 afrag = *(const short8*)((const char*)xs + abase + ((ks * 64 + kg * 16) ^ aswz));
#pragma unroll
        for (int j = 0; j < 4; j++) {
            short8 bfrag = *(const short8*)(wb + j * 512);
            acc[j] = __builtin_amdgcn_mfma_f32_16x16x32_bf16(afrag, bfrag, acc[j], 0, 0, 0);
        }
        wb += 8192;
    }
    // epilogue: D col=lane&15 (feature within tile), row=(lane>>4)*4+reg (node)
    int g4 = lane >> 4, cf = lane & 15;
    float p1[4] = {0.f, 0.f, 0.f, 0.f}, p2[4] = {0.f, 0.f, 0.f, 0.f};
#pragma unroll
    for (int j = 0; j < 4; j++) {
        int d = j * 16 + cf;
        float bias = b1[w * 64 + d];
        float c1 = a1[w * 2 * NHID + d];
        float c2 = a1[w * 2 * NHID + NHID + d];
#pragma unroll
        for (int r = 0; r < 4; r++) {
            int n = n0 + g4 * 4 + r;
            float v = acc[j][r] + bias;
            h1b[((size_t)w * NN + n) * NHID + d] = bfr(v);
            p1[r] += v * c1;
            p2[r] += v * c2;
        }
    }
#pragma unroll
    for (int r = 0; r < 4; r++) {
        float s1 = p1[r], s2 = p2[r];
#pragma unroll
        for (int o = 8; o >= 1; o >>= 1) {
            s1 += __shfl_xor(s1, o);
            s2 += __shfl_xor(s2, o);
        }
        if (cf == 0) {
            int n = n0 + g4 * 4 + r;
            as1[n * 4 + w] = s1;
            at1[n * 4 + w] = s2;
        }
    }
}

__global__ void count_deg(const int* __restrict__ src, int* __restrict__ deg) {
    int k = blockIdx.x * blockDim.x + threadIdx.x;
    if (k < NEDGE) atomicAdd(&deg[src[k]], 1);
}

// parallel two-level scan: 256 threads, each owns 32 elements.
__global__ void scan8192(const int* __restrict__ deg, int* __restrict__ rowptr,
                         int* __restrict__ cursor) {
    __shared__ int wsum[4];
    int t = threadIdx.x;
    int lane = t & 63, w = t >> 6;
    int s = 0;
#pragma unroll
    for (int i = 0; i < 32; i++) s += deg[t * 32 + i];
    // inclusive wave scan of s
    int sc = s;
#pragma unroll
    for (int o = 1; o < 64; o <<= 1) {
        int v = __shfl_up(sc, o);
        if (lane >= o) sc += v;
    }
    if (lane == 63) wsum[w] = sc;
    __syncthreads();
    int woff = 0;
#pragma unroll
    for (int i = 0; i < 4; i++) woff += (i < w) ? wsum[i] : 0;
    int r = woff + sc - s;   // exclusive prefix for this thread's chunk
    for (int i = 0; i < 32; i++) {
        rowptr[t * 32 + i] = r;
        cursor[t * 32 + i] = r;
        r += deg[t * 32 + i];
    }
    if (t == 255) rowptr[NN] = r;
}

__global__ void fill_csr(const int* __restrict__ src, const int* __restrict__ tgt,
                         int* __restrict__ cursor, int* __restrict__ csr) {
    int k = blockIdx.x * blockDim.x + threadIdx.x;
    if (k < NEDGE) {
        int s = src[k];
        int p = atomicAdd(&cursor[s], 1);
        csr[p] = tgt[k];
    }
}

// agg1: one WAVE per row (4 rows/block, no __syncthreads on fast path).
__global__ void agg1(const unsigned short* __restrict__ h1b, const float* __restrict__ as1,
                     const float* __restrict__ at1, const int* __restrict__ rowptr,
                     int* __restrict__ csr, float* __restrict__ hcat) {
    __shared__ int tsf[4][MAXDEG];
    __shared__ float psf[4][NHEADS][MAXDEG];
    int wv = threadIdx.x >> 6, lane = threadIdx.x & 63;
    int n = blockIdx.x * 4 + wv;
    int r0 = rowptr[n];
    int deg = rowptr[n + 1] - r0;
    if (deg > MAXDEG) deg = MAXDEG;
    if (deg == 0) {
#pragma unroll
        for (int h = 0; h < 4; h++) hcat[(size_t)n * 256 + h * 64 + lane] = 0.f;
        return;
    }
    float4 asv = *(const float4*)(as1 + n * 4);
    int eg = lane >> 3, dg = lane & 7;
    if (deg <= 64) {
        int t = -1 - lane;               // unique negatives for invalid lanes
        float ea[4] = {0.f, 0.f, 0.f, 0.f};
        if (lane < deg) {
            t = csr[r0 + lane];
            float4 atv = *(const float4*)(at1 + t * 4);
            float e0 = asv.x + atv.x, e1 = asv.y + atv.y;
            float e2 = asv.z + atv.z, e3 = asv.w + atv.w;
            ea[0] = e0 > 0.f ? e0 : LRELU_ALPHA * e0;
            ea[1] = e1 > 0.f ? e1 : LRELU_ALPHA * e1;
            ea[2] = e2 > 0.f ? e2 : LRELU_ALPHA * e2;
            ea[3] = e3 > 0.f ? e3 : LRELU_ALPHA * e3;
        }
        // dup-combine: all-pairs via rotation
        int mult = 1;
        bool skip = false;
        for (int k = 1; k < 64; k++) {
            int idx = (lane + k) & 63;
            int to = __shfl(t, idx);
            if (to == t) { mult++; if (idx < lane) skip = true; }
        }
        if (lane < deg) csr[r0 + lane] = skip ? -1 : (t | (mult << 16));
        bool valid = (lane < deg) && !skip;
        float mf = (float)mult;
        int tj[8];
#pragma unroll
        for (int i = 0; i < 8; i++) {
            int tv = __shfl(t, i * 8 + eg);
            tj[i] = tv < 0 ? 0 : tv;
        }
        bool b2 = (eg & 4) != 0, b1 = (eg & 2) != 0, b0 = (eg & 1) != 0;
        float outv[4];
#pragma unroll
        for (int h = 0; h < 4; h++) {
            float p = valid ? mf * ea[h] : -INFINITY;
            float m = p;
#pragma unroll
            for (int o = 32; o >= 1; o >>= 1) m = fmaxf(m, __shfl_xor(m, o));
            float pe = expf(p - m);
            float s = pe;
#pragma unroll
            for (int o = 32; o >= 1; o >>= 1) s += __shfl_xor(s, o);
            const unsigned short* hb = h1b + (size_t)h * NN * NHID;
            float acc[8] = {0.f, 0.f, 0.f, 0.f, 0.f, 0.f, 0.f, 0.f};
#pragma unroll
            for (int i = 0; i < 8; i++) {
                float pj = __shfl(pe, i * 8 + eg);
                ushort8 hv = *(const ushort8*)(hb + (size_t)tj[i] * NHID + dg * 8);
#pragma unroll
                for (int q = 0; q < 8; q++) acc[q] += pj * bf2f(hv[q]);
            }
            // reduce-scatter butterfly over eg
            float k4[4], k2[2], r;
#pragma unroll
            for (int q = 0; q < 4; q++) {
                float keep = b2 ? acc[4 + q] : acc[q];
                float send = b2 ? acc[q] : acc[4 + q];
                k4[q] = keep + __shfl_xor(send, 32);
            }
#pragma unroll
            for (int q = 0; q < 2; q++) {
                float keep = b1 ? k4[2 + q] : k4[q];
                float send = b1 ? k4[q] : k4[2 + q];
                k2[q] = keep + __shfl_xor(send, 16);
            }
            {
                float keep = b0 ? k2[1] : k2[0];
                float send = b0 ? k2[0] : k2[1];
                r = keep + __shfl_xor(send, 8);
            }
            float v = r / s;
            outv[h] = v > 0.f ? v : (expf(v) - 1.f);   // ELU
        }
#pragma unroll
        for (int h = 0; h < 4; h++)
            hcat[(size_t)n * 256 + h * 64 + dg * 8 + eg] = outv[h];
    } else {
        // ---- wave-local LDS fallback (statistically never taken) ----
        int* ts = tsf[wv];
        for (int j = lane; j < deg; j += 64) {
            int tv = csr[r0 + j];
            ts[j] = tv;
            float4 atv = *(const float4*)(at1 + tv * 4);
            float e0 = asv.x + atv.x, e1 = asv.y + atv.y;
            float e2 = asv.z + atv.z, e3 = asv.w + atv.w;
            psf[wv][0][j] = e0 > 0.f ? e0 : LRELU_ALPHA * e0;
            psf[wv][1][j] = e1 > 0.f ? e1 : LRELU_ALPHA * e1;
            psf[wv][2][j] = e2 > 0.f ? e2 : LRELU_ALPHA * e2;
            psf[wv][3][j] = e3 > 0.f ? e3 : LRELU_ALPHA * e3;
        }
        for (int j = lane; j < deg; j += 64) {
            int tjv = ts[j];
            int m = 1;
            bool skip = false;
            for (int j2 = 0; j2 < deg; j2++) {
                if (j2 == j) continue;
                if (ts[j2] == tjv) {
                    if (j2 < j) { skip = true; break; }
                    m++;
                }
            }
            if (skip) {
                psf[wv][0][j] = -INFINITY; psf[wv][1][j] = -INFINITY;
                psf[wv][2][j] = -INFINITY; psf[wv][3][j] = -INFINITY;
                csr[r0 + j] = -1;
            } else {
                float mf = (float)m;
                psf[wv][0][j] *= mf; psf[wv][1][j] *= mf;
                psf[wv][2][j] *= mf; psf[wv][3][j] *= mf;
                csr[r0 + j] = tjv | (m << 16);
            }
        }
        for (int h = 0; h < 4; h++) {
            float m = -INFINITY;
            for (int j = lane; j < deg; j += 64) m = fmaxf(m, psf[wv][h][j]);
#pragma unroll
            for (int o = 32; o >= 1; o >>= 1) m = fmaxf(m, __shfl_xor(m, o));
            float s = 0.f;
            for (int j = lane; j < deg; j += 64) {
                float pe = expf(psf[wv][h][j] - m);
                psf[wv][h][j] = pe;
                s += pe;
            }
#pragma unroll
            for (int o = 32; o >= 1; o >>= 1) s += __shfl_xor(s, o);
            const unsigned short* hb = h1b + (size_t)h * NN * NHID;
            float acc[8] = {0.f, 0.f, 0.f, 0.f, 0.f, 0.f, 0.f, 0.f};
            for (int j = eg; j < deg; j += 8) {
                float pj = psf[wv][h][j];
                int tjv = ts[j];
                ushort8 hv = *(const ushort8*)(hb + (size_t)tjv * NHID + dg * 8);
#pragma unroll
                for (int q = 0; q < 8; q++) acc[q] += pj * bf2f(hv[q]);
            }
            bool b2 = (eg & 4) != 0, b1 = (eg & 2) != 0, b0 = (eg & 1) != 0;
            float k4[4], k2[2], r;
#pragma unroll
            for (int q = 0; q < 4; q++) {
                float keep = b2 ? acc[4 + q] : acc[q];
                float send = b2 ? acc[q] : acc[4 + q];
                k4[q] = keep + __shfl_xor(send, 32);
            }
#pragma unroll
            for (int q = 0; q < 2; q++) {
                float keep = b1 ? k4[2 + q] : k4[q];
                float send = b1 ? k4[q] : k4[2 + q];
                k2[q] = keep + __shfl_xor(send, 16);
            }
            {
                float keep = b0 ? k2[1] : k2[0];
                float send = b0 ? k2[0] : k2[1];
                r = keep + __shfl_xor(send, 8);
            }
            float v = r / s;
            v = v > 0.f ? v : (expf(v) - 1.f);
            hcat[(size_t)n * 256 + h * 64 + dg * 8 + eg] = v;
        }
    }
}

// h2[n][c] = b2[c] + sum_k hcat[n][k] * W2[c][k]; fused as2/at2 scores.
__global__ void gemm2(const float* __restrict__ hcat, const float* __restrict__ W2,
                      const float* __restrict__ b2, float* __restrict__ h2,
                      const float* __restrict__ a2, float* __restrict__ as2,
                      float* __restrict__ at2) {
    __shared__ float hs[16][260];
    __shared__ float ws[16][260];
    int t = threadIdx.x;
    int n0 = blockIdx.x * 16;
#pragma unroll
    for (int i = 0; i < 16; i++) {
        hs[i][t] = hcat[(size_t)(n0 + i) * 256 + t];
        ws[i][t] = W2[i * 256 + t];
    }
    __syncthreads();
    int nl = t >> 4, c = t & 15;
    const float4* hr = (const float4*)&hs[nl][0];
    const float4* wr = (const float4*)&ws[c][0];
    float dot = 0.f;
#pragma unroll 4
    for (int k4 = 0; k4 < 64; k4++) {
        float4 a = hr[k4], b = wr[k4];
        dot += a.x * b.x + a.y * b.y + a.z * b.z + a.w * b.w;
    }
    float v = dot + b2[c];
    h2[(size_t)(n0 + nl) * NCLASS + c] = v;
    float s1 = v * a2[c], s2 = v * a2[NCLASS + c];
#pragma unroll
    for (int o = 8; o >= 1; o >>= 1) {
        s1 += __shfl_xor(s1, o);
        s2 += __shfl_xor(s2, o);
    }
    if (c == 0) { as2[n0 + nl] = s1; at2[n0 + nl] = s2; }
}

// agg2: one WAVE per row, packed csr (no dup pass), fused log_softmax.
__global__ void agg2(const float* __restrict__ h2, const float* __restrict__ as2,
                     const float* __restrict__ at2, const int* __restrict__ rowptr,
                     const int* __restrict__ csrp, float* __restrict__ out) {
    __shared__ int tf[4][MAXDEG];
    __shared__ float pf[4][MAXDEG];
    int wv = threadIdx.x >> 6, lane = threadIdx.x & 63;
    int n = blockIdx.x * 4 + wv;
    int r0 = rowptr[n];
    int deg = rowptr[n + 1] - r0;
    if (deg > MAXDEG) deg = MAXDEG;
    if (deg == 0) {
        if (lane < NCLASS) out[(size_t)n * NCLASS + lane] = -logf((float)NCLASS);
        return;
    }
    float asvn = as2[n];
    int jg = lane >> 2, cq = lane & 3;
    if (deg <= 64) {
        int pk = (lane < deg) ? csrp[r0 + lane] : -1;
        int t = 0;
        float p = -INFINITY;
        if (pk >= 0) {
            t = pk & 0xFFFF;
            float e = asvn + at2[t];
            e = e > 0.f ? e : LRELU_ALPHA * e;
            p = (float)(pk >> 16) * e;
        }
        float m = p;
#pragma unroll
        for (int o = 32; o >= 1; o >>= 1) m = fmaxf(m, __shfl_xor(m, o));
        float pe = expf(p - m);
        float s = pe;
#pragma unroll
        for (int o = 32; o >= 1; o >>= 1) s += __shfl_xor(s, o);
        float4 a4 = {0.f, 0.f, 0.f, 0.f};
#pragma unroll
        for (int i = 0; i < 4; i++) {
            int j = i * 16 + jg;
            float pj = __shfl(pe, j);
            int tjv = __shfl(t, j);
            float4 hv = *(const float4*)(h2 + (size_t)tjv * NCLASS + cq * 4);
            a4.x += pj * hv.x; a4.y += pj * hv.y;
            a4.z += pj * hv.z; a4.w += pj * hv.w;
        }
#pragma unroll
        for (int o = 4; o <= 32; o <<= 1) {
            a4.x += __shfl_xor(a4.x, o);
            a4.y += __shfl_xor(a4.y, o);
            a4.z += __shfl_xor(a4.z, o);
            a4.w += __shfl_xor(a4.w, o);
        }
        float inv = 1.f / s;
        float4 v4 = {a4.x * inv, a4.y * inv, a4.z * inv, a4.w * inv};
        float mm = fmaxf(fmaxf(v4.x, v4.y), fmaxf(v4.z, v4.w));
        mm = fmaxf(mm, __shfl_xor(mm, 1));
        mm = fmaxf(mm, __shfl_xor(mm, 2));
        float se = expf(v4.x - mm) + expf(v4.y - mm) + expf(v4.z - mm) + expf(v4.w - mm);
        se += __shfl_xor(se, 1);
        se += __shfl_xor(se, 2);
        float lse = mm + logf(se);
        if (jg == 0) {
            float4 o4 = {v4.x - lse, v4.y - lse, v4.z - lse, v4.w - lse};
            *(float4*)(out + (size_t)n * NCLASS + cq * 4) = o4;
        }
    } else {
        // ---- wave-local LDS fallback ----
        for (int j = lane; j < deg; j += 64) {
            int pk = csrp[r0 + j];
            if (pk < 0) {
                tf[wv][j] = 0;
                pf[wv][j] = -INFINITY;
            } else {
                int t = pk & 0xFFFF;
                tf[wv][j] = t;
                float e = asvn + at2[t];
                e = e > 0.f ? e : LRELU_ALPHA * e;
                pf[wv][j] = (float)(pk >> 16) * e;
            }
        }
        float m = -INFINITY;
        for (int j = lane; j < deg; j += 64) m = fmaxf(m, pf[wv][j]);
#pragma unroll
        for (int o = 32; o >= 1; o >>= 1) m = fmaxf(m, __shfl_xor(m, o));
        float s = 0.f;
        for (int j = lane; j < deg; j += 64) {
            float pe = expf(pf[wv][j] - m);
            pf[wv][j] = pe;
            s += pe;
        }
#pragma unroll
        for (int o = 32; o >= 1; o >>= 1) s += __shfl_xor(s, o);
        float4 a4 = {0.f, 0.f, 0.f, 0.f};
        for (int j = jg; j < deg; j += 16) {
            float pj = pf[wv][j];
            float4 hv = *(const float4*)(h2 + (size_t)tf[wv][j] * NCLASS + cq * 4);
            a4.x += pj * hv.x; a4.y += pj * hv.y;
            a4.z += pj * hv.z; a4.w += pj * hv.w;
        }
#pragma unroll
        for (int o = 4; o <= 32; o <<= 1) {
            a4.x += __shfl_xor(a4.x, o);
            a4.y += __shfl_xor(a4.y, o);
            a4.z += __shfl_xor(a4.z, o);
            a4.w += __shfl_xor(a4.w, o);
        }
        float inv = 1.f / s;
        float4 v4 = {a4.x * inv, a4.y * inv, a4.z * inv, a4.w * inv};
        float mm = fmaxf(fmaxf(v4.x, v4.y), fmaxf(v4.z, v4.w));
        mm = fmaxf(mm, __shfl_xor(mm, 1));
        mm = fmaxf(mm, __shfl_xor(mm, 2));
        float se = expf(v4.x - mm) + expf(v4.y - mm) + expf(v4.z - mm) + expf(v4.w - mm);
        se += __shfl_xor(se, 1);
        se += __shfl_xor(se, 2);
        float lse = mm + logf(se);
        if (jg == 0) {
            float4 o4 = {v4.x - lse, v4.y - lse, v4.z - lse, v4.w - lse};
            *(float4*)(out + (size_t)n * NCLASS + cq * 4) = o4;
        }
    }
}

extern "C" void kernel_launch(void* const* d_in, const int* in_sizes, int n_in,
                              void* d_out, int out_size, void* d_ws, size_t ws_size,
                              hipStream_t stream) {
    const float* x  = (const float*)d_in[0];
    const int* el   = (const int*)d_in[1];
    const float* W1 = (const float*)d_in[2];
    const float* b1 = (const float*)d_in[3];
    const float* a1 = (const float*)d_in[4];
    const float* W2 = (const float*)d_in[5];
    const float* b2 = (const float*)d_in[6];
    const float* a2 = (const float*)d_in[7];
    float* out = (float*)d_out;

    unsigned short* h1b = (unsigned short*)d_ws;  // 4*8192*64 bf16 = 4 MB
    float* hcat = (float*)(h1b + 2097152);        // 8192*256 floats
    float* h2   = hcat + 2097152;                 // 8192*16
    float* as1  = h2 + 131072;                    // [n][4] = 32768
    float* at1  = as1 + 32768;                    // [n][4] = 32768
    float* as2  = at1 + 32768;
    float* at2  = as2 + 8192;
    int* deg    = (int*)(at2 + 8192);
    int* rowptr = deg + 8192;
    int* cursor = rowptr + 8200;
    int* csr    = cursor + 8192;
    unsigned short* Wbf = (unsigned short*)(csr + 262144);  // 256KB

    const int* src = el;
    const int* tgt = el + NEDGE;

    zero_deg<<<32, 256, 0, stream>>>(deg);
    buildWbf<<<64, 256, 0, stream>>>(W1, Wbf);
    gemm1<<<NN / 16, 256, 0, stream>>>(x, Wbf, b1, h1b, a1, as1, at1);
    count_deg<<<NEDGE / 256, 256, 0, stream>>>(src, deg);
    scan8192<<<1, 256, 0, stream>>>(deg, rowptr, cursor);
    fill_csr<<<NEDGE / 256, 256, 0, stream>>>(src, tgt, cursor, csr);
    agg1<<<NN / 4, 256, 0, stream>>>(h1b, as1, at1, rowptr, csr, hcat);
    gemm2<<<NN / 16, 256, 0, stream>>>(hcat, W2, b2, h2, a2, as2, at2);
    agg2<<<NN / 4, 256, 0, stream>>>(h2, as2, at2, rowptr, csr, out);
}

// Round 9
// 81.367 us; speedup vs baseline: 3.2104x; 1.0693x over previous
//
#include <hip/hip_runtime.h>
#include <math.h>

#define NN 8192
#define NFEAT 512
#define NHID 64
#define NHEADS 4
#define NCLASS 16
#define NEDGE 262144
#define LRELU_ALPHA 0.2f
#define MAXDEG 128

typedef __attribute__((ext_vector_type(8))) short short8;
typedef __attribute__((ext_vector_type(8))) unsigned short ushort8;
typedef __attribute__((ext_vector_type(4))) float f32x4;

__device__ __forceinline__ unsigned short bfr(float f) {
    unsigned int u = __float_as_uint(f);
    u += 0x7fffu + ((u >> 16) & 1u);   // round-to-nearest-even
    return (unsigned short)(u >> 16);
}
__device__ __forceinline__ float bf2f(unsigned short u) {
    return __uint_as_float(((unsigned int)u) << 16);
}

// prep: blocks 0..63 build Wbf (B-fragment-ordered bf16 W1);
// blocks 64..95 zero deg; block 96 transposes W2 -> bf16 [256][24].
__global__ void prep(const float* __restrict__ W1, unsigned short* __restrict__ Wbf,
                     int* __restrict__ deg, const float* __restrict__ W2,
                     unsigned short* __restrict__ W2tb) {
    int b = blockIdx.x, t = threadIdx.x;
    if (b < 64) {
        int idx = b * 256 + t;
        int lane = idx & 63, nt = (idx >> 6) & 15, ks = idx >> 10;
        int tfeat = nt * 16 + (lane & 15);
        int k0 = ks * 32 + (lane >> 4) * 8;
        const float* src = W1 + (size_t)tfeat * NFEAT + k0;
        float4 lo = *(const float4*)src;
        float4 hi = *(const float4*)(src + 4);
        ushort8 v;
        v[0] = bfr(lo.x); v[1] = bfr(lo.y); v[2] = bfr(lo.z); v[3] = bfr(lo.w);
        v[4] = bfr(hi.x); v[5] = bfr(hi.y); v[6] = bfr(hi.z); v[7] = bfr(hi.w);
        *(ushort8*)(Wbf + (size_t)idx * 8) = v;
    } else if (b < 96) {
        deg[(b - 64) * 256 + t] = 0;
    } else {
#pragma unroll
        for (int c = 0; c < NCLASS; c++)
            W2tb[t * 24 + c] = bfr(W2[c * 256 + t]);   // reads coalesced per c
    }
}

// gemm1c: blocks 0..511 = MFMA gemm1 (h1b bf16 + fused as1/at1 scores);
// blocks 512..1535 = count_deg (overlapped).
__global__ void gemm1c(const float* __restrict__ x, const unsigned short* __restrict__ Wbf,
                       const float* __restrict__ b1, unsigned short* __restrict__ h1b,
                       const float* __restrict__ a1, float* __restrict__ as1,
                       float* __restrict__ at1, const int* __restrict__ src_e,
                       int* __restrict__ deg) {
    __shared__ __align__(16) unsigned short xs[16 * 512];   // 16 KB, XOR-swizzled rows
    int t = threadIdx.x;
    if (blockIdx.x >= 512) {
        int k = (blockIdx.x - 512) * 256 + t;
        if (k < NEDGE) atomicAdd(&deg[src_e[k]], 1);
        return;
    }
    int n0 = blockIdx.x * 16;
    const float4* xv = (const float4*)(x + (size_t)n0 * NFEAT);
#pragma unroll
    for (int i = 0; i < 4; i++) {
        int g = i * 256 + t;
        int row = g >> 6;
        int k0 = (g & 63) * 8;
        float4 lo = xv[g * 2];
        float4 hi = xv[g * 2 + 1];
        ushort8 v;
        v[0] = bfr(lo.x); v[1] = bfr(lo.y); v[2] = bfr(lo.z); v[3] = bfr(lo.w);
        v[4] = bfr(hi.x); v[5] = bfr(hi.y); v[6] = bfr(hi.z); v[7] = bfr(hi.w);
        int byte = (k0 * 2) ^ ((row & 7) << 4);
        *(ushort8*)((char*)xs + row * 1024 + byte) = v;
    }
    __syncthreads();
    int w = t >> 6, lane = t & 63;
    int arow = lane & 15, kg = lane >> 4;
    f32x4 acc[4];
#pragma unroll
    for (int j = 0; j < 4; j++) acc[j] = (f32x4){0.f, 0.f, 0.f, 0.f};
    const unsigned short* wb = Wbf + ((size_t)(w * 4) * 64 + lane) * 8;
    int abase = arow * 1024;
    int aswz = (arow & 7) << 4;
    for (int ks = 0; ks < 16; ks++) {
        short8 afrag = *(const short8*)((const char*)xs + abase + ((ks * 64 + kg * 16) ^ aswz));
#pragma unroll
        for (int j = 0; j < 4; j++) {
            short8 bfrag = *(const short8*)(wb + j * 512);
            acc[j] = __builtin_amdgcn_mfma_f32_16x16x32_bf16(afrag, bfrag, acc[j], 0, 0, 0);
        }
        wb += 8192;
    }
    int g4 = lane >> 4, cf = lane & 15;
    float p1[4] = {0.f, 0.f, 0.f, 0.f}, p2[4] = {0.f, 0.f, 0.f, 0.f};
#pragma unroll
    for (int j = 0; j < 4; j++) {
        int d = j * 16 + cf;
        float bias = b1[w * 64 + d];
        float c1 = a1[w * 2 * NHID + d];
        float c2 = a1[w * 2 * NHID + NHID + d];
#pragma unroll
        for (int r = 0; r < 4; r++) {
            int n = n0 + g4 * 4 + r;
            float v = acc[j][r] + bias;
            h1b[((size_t)w * NN + n) * NHID + d] = bfr(v);
            p1[r] += v * c1;
            p2[r] += v * c2;
        }
    }
#pragma unroll
    for (int r = 0; r < 4; r++) {
        float s1 = p1[r], s2 = p2[r];
#pragma unroll
        for (int o = 8; o >= 1; o >>= 1) {
            s1 += __shfl_xor(s1, o);
            s2 += __shfl_xor(s2, o);
        }
        if (cf == 0) {
            int n = n0 + g4 * 4 + r;
            as1[n * 4 + w] = s1;
            at1[n * 4 + w] = s2;
        }
    }
}

// parallel two-level scan: 256 threads, each owns 32 elements.
__global__ void scan8192(const int* __restrict__ deg, int* __restrict__ rowptr,
                         int* __restrict__ cursor) {
    __shared__ int wsum[4];
    int t = threadIdx.x;
    int lane = t & 63, w = t >> 6;
    int s = 0;
#pragma unroll
    for (int i = 0; i < 32; i++) s += deg[t * 32 + i];
    int sc = s;
#pragma unroll
    for (int o = 1; o < 64; o <<= 1) {
        int v = __shfl_up(sc, o);
        if (lane >= o) sc += v;
    }
    if (lane == 63) wsum[w] = sc;
    __syncthreads();
    int woff = 0;
#pragma unroll
    for (int i = 0; i < 4; i++) woff += (i < w) ? wsum[i] : 0;
    int r = woff + sc - s;
    for (int i = 0; i < 32; i++) {
        rowptr[t * 32 + i] = r;
        cursor[t * 32 + i] = r;
        r += deg[t * 32 + i];
    }
    if (t == 255) rowptr[NN] = r;
}

__global__ void fill_csr(const int* __restrict__ src, const int* __restrict__ tgt,
                         int* __restrict__ cursor, int* __restrict__ csr) {
    int k = blockIdx.x * blockDim.x + threadIdx.x;
    if (k < NEDGE) {
        int s = src[k];
        int p = atomicAdd(&cursor[s], 1);
        csr[p] = tgt[k];
    }
}

// agg1f: one WAVE per row; softmax + gather (as before) PLUS fused gemm2:
// the wave holds the full 256-feature hcat row in registers (outv[4]/lane),
// so h2[n][:], as2[n], at2[n] are computed in-register via W2^T in LDS and a
// reduce-scatter butterfly. hcat is never materialized.
__global__ void agg1f(const unsigned short* __restrict__ h1b, const float* __restrict__ as1,
                      const float* __restrict__ at1, const int* __restrict__ rowptr,
                      int* __restrict__ csr, const unsigned short* __restrict__ W2tb,
                      const float* __restrict__ b2g, const float* __restrict__ a2,
                      float* __restrict__ h2, float* __restrict__ as2,
                      float* __restrict__ at2) {
    __shared__ unsigned short W2ls[256 * 24];     // 12 KB
    __shared__ int tsf[4][MAXDEG];                // fallback only
    __shared__ float psf[4][NHEADS][MAXDEG];      // fallback only
    int tid = threadIdx.x;
    {   // stage W2^T (coalesced uint copy, 12288 B)
        const unsigned int* s = (const unsigned int*)W2tb;
        unsigned int* d = (unsigned int*)W2ls;
#pragma unroll
        for (int i = 0; i < 12; i++) d[tid + 256 * i] = s[tid + 256 * i];
    }
    __syncthreads();
    int wv = tid >> 6, lane = tid & 63;
    int n = blockIdx.x * 4 + wv;
    int r0 = rowptr[n];
    int deg = rowptr[n + 1] - r0;
    if (deg > MAXDEG) deg = MAXDEG;
    int eg = lane >> 3, dg = lane & 7;
    float outv[4] = {0.f, 0.f, 0.f, 0.f};
    if (deg > 0 && deg <= 64) {
        float4 asv = *(const float4*)(as1 + n * 4);
        int t = -1 - lane;
        float ea[4] = {0.f, 0.f, 0.f, 0.f};
        if (lane < deg) {
            t = csr[r0 + lane];
            float4 atv = *(const float4*)(at1 + t * 4);
            float e0 = asv.x + atv.x, e1 = asv.y + atv.y;
            float e2 = asv.z + atv.z, e3 = asv.w + atv.w;
            ea[0] = e0 > 0.f ? e0 : LRELU_ALPHA * e0;
            ea[1] = e1 > 0.f ? e1 : LRELU_ALPHA * e1;
            ea[2] = e2 > 0.f ? e2 : LRELU_ALPHA * e2;
            ea[3] = e3 > 0.f ? e3 : LRELU_ALPHA * e3;
        }
        int mult = 1;
        bool skip = false;
        for (int k = 1; k < 64; k++) {
            int idx = (lane + k) & 63;
            int to = __shfl(t, idx);
            if (to == t) { mult++; if (idx < lane) skip = true; }
        }
        if (lane < deg) csr[r0 + lane] = skip ? -1 : (t | (mult << 16));
        bool valid = (lane < deg) && !skip;
        float mf = (float)mult;
        int tj[8];
#pragma unroll
        for (int i = 0; i < 8; i++) {
            int tv = __shfl(t, i * 8 + eg);
            tj[i] = tv < 0 ? 0 : tv;
        }
        bool b2 = (eg & 4) != 0, b1 = (eg & 2) != 0, b0 = (eg & 1) != 0;
#pragma unroll
        for (int h = 0; h < 4; h++) {
            float p = valid ? mf * ea[h] : -INFINITY;
            float m = p;
#pragma unroll
            for (int o = 32; o >= 1; o >>= 1) m = fmaxf(m, __shfl_xor(m, o));
            float pe = expf(p - m);
            float s = pe;
#pragma unroll
            for (int o = 32; o >= 1; o >>= 1) s += __shfl_xor(s, o);
            const unsigned short* hb = h1b + (size_t)h * NN * NHID;
            float acc[8] = {0.f, 0.f, 0.f, 0.f, 0.f, 0.f, 0.f, 0.f};
#pragma unroll
            for (int i = 0; i < 8; i++) {
                float pj = __shfl(pe, i * 8 + eg);
                ushort8 hv = *(const ushort8*)(hb + (size_t)tj[i] * NHID + dg * 8);
#pragma unroll
                for (int q = 0; q < 8; q++) acc[q] += pj * bf2f(hv[q]);
            }
            float k4[4], k2[2], r;
#pragma unroll
            for (int q = 0; q < 4; q++) {
                float keep = b2 ? acc[4 + q] : acc[q];
                float send = b2 ? acc[q] : acc[4 + q];
                k4[q] = keep + __shfl_xor(send, 32);
            }
#pragma unroll
            for (int q = 0; q < 2; q++) {
                float keep = b1 ? k4[2 + q] : k4[q];
                float send = b1 ? k4[q] : k4[2 + q];
                k2[q] = keep + __shfl_xor(send, 16);
            }
            {
                float keep = b0 ? k2[1] : k2[0];
                float send = b0 ? k2[0] : k2[1];
                r = keep + __shfl_xor(send, 8);
            }
            float v = r / s;
            outv[h] = v > 0.f ? v : (expf(v) - 1.f);   // ELU
        }
    } else if (deg > 64) {
        // ---- wave-local LDS fallback (statistically never taken) ----
        float4 asv = *(const float4*)(as1 + n * 4);
        int* ts = tsf[wv];
        for (int j = lane; j < deg; j += 64) {
            int tv = csr[r0 + j];
            ts[j] = tv;
            float4 atv = *(const float4*)(at1 + tv * 4);
            float e0 = asv.x + atv.x, e1 = asv.y + atv.y;
            float e2 = asv.z + atv.z, e3 = asv.w + atv.w;
            psf[wv][0][j] = e0 > 0.f ? e0 : LRELU_ALPHA * e0;
            psf[wv][1][j] = e1 > 0.f ? e1 : LRELU_ALPHA * e1;
            psf[wv][2][j] = e2 > 0.f ? e2 : LRELU_ALPHA * e2;
            psf[wv][3][j] = e3 > 0.f ? e3 : LRELU_ALPHA * e3;
        }
        for (int j = lane; j < deg; j += 64) {
            int tjv = ts[j];
            int m = 1;
            bool skip = false;
            for (int j2 = 0; j2 < deg; j2++) {
                if (j2 == j) continue;
                if (ts[j2] == tjv) {
                    if (j2 < j) { skip = true; break; }
                    m++;
                }
            }
            if (skip) {
                psf[wv][0][j] = -INFINITY; psf[wv][1][j] = -INFINITY;
                psf[wv][2][j] = -INFINITY; psf[wv][3][j] = -INFINITY;
                csr[r0 + j] = -1;
            } else {
                float mf = (float)m;
                psf[wv][0][j] *= mf; psf[wv][1][j] *= mf;
                psf[wv][2][j] *= mf; psf[wv][3][j] *= mf;
                csr[r0 + j] = tjv | (m << 16);
            }
        }
        for (int h = 0; h < 4; h++) {
            float m = -INFINITY;
            for (int j = lane; j < deg; j += 64) m = fmaxf(m, psf[wv][h][j]);
#pragma unroll
            for (int o = 32; o >= 1; o >>= 1) m = fmaxf(m, __shfl_xor(m, o));
            float s = 0.f;
            for (int j = lane; j < deg; j += 64) {
                float pe = expf(psf[wv][h][j] - m);
                psf[wv][h][j] = pe;
                s += pe;
            }
#pragma unroll
            for (int o = 32; o >= 1; o >>= 1) s += __shfl_xor(s, o);
            const unsigned short* hb = h1b + (size_t)h * NN * NHID;
            float acc[8] = {0.f, 0.f, 0.f, 0.f, 0.f, 0.f, 0.f, 0.f};
            for (int j = eg; j < deg; j += 8) {
                float pj = psf[wv][h][j];
                int tjv = ts[j];
                ushort8 hv = *(const ushort8*)(hb + (size_t)tjv * NHID + dg * 8);
#pragma unroll
                for (int q = 0; q < 8; q++) acc[q] += pj * bf2f(hv[q]);
            }
            bool b2 = (eg & 4) != 0, b1 = (eg & 2) != 0, b0 = (eg & 1) != 0;
            float k4[4], k2[2], r;
#pragma unroll
            for (int q = 0; q < 4; q++) {
                float keep = b2 ? acc[4 + q] : acc[q];
                float send = b2 ? acc[q] : acc[4 + q];
                k4[q] = keep + __shfl_xor(send, 32);
            }
#pragma unroll
            for (int q = 0; q < 2; q++) {
                float keep = b1 ? k4[2 + q] : k4[q];
                float send = b1 ? k4[q] : k4[2 + q];
                k2[q] = keep + __shfl_xor(send, 16);
            }
            {
                float keep = b0 ? k2[1] : k2[0];
                float send = b0 ? k2[0] : k2[1];
                r = keep + __shfl_xor(send, 8);
            }
            float v = r / s;
            outv[h] = v > 0.f ? v : (expf(v) - 1.f);
        }
    }
    // ---- fused gemm2 epilogue: h2[n][:], as2[n], at2[n] ----
    float cp[16];
#pragma unroll
    for (int c = 0; c < 16; c++) cp[c] = 0.f;
#pragma unroll
    for (int h = 0; h < 4; h++) {
        const unsigned short* wrow = &W2ls[(h * 64 + dg * 8 + eg) * 24];
        float ov = outv[h];
#pragma unroll
        for (int c = 0; c < 16; c++) cp[c] = fmaf(ov, bf2f(wrow[c]), cp[c]);
    }
    bool t0 = (lane & 1) != 0, t1 = (lane & 2) != 0, t2 = (lane & 4) != 0, t3 = (lane & 8) != 0;
    float p8[8];
#pragma unroll
    for (int q = 0; q < 8; q++) {
        float keep = t0 ? cp[8 + q] : cp[q];
        float send = t0 ? cp[q] : cp[8 + q];
        p8[q] = keep + __shfl_xor(send, 1);
    }
    float p4[4];
#pragma unroll
    for (int q = 0; q < 4; q++) {
        float keep = t1 ? p8[4 + q] : p8[q];
        float send = t1 ? p8[q] : p8[4 + q];
        p4[q] = keep + __shfl_xor(send, 2);
    }
    float p2[2];
#pragma unroll
    for (int q = 0; q < 2; q++) {
        float keep = t2 ? p4[2 + q] : p4[q];
        float send = t2 ? p4[q] : p4[2 + q];
        p2[q] = keep + __shfl_xor(send, 4);
    }
    float r = (t3 ? p2[1] : p2[0]) + __shfl_xor(t3 ? p2[0] : p2[1], 8);
    r += __shfl_xor(r, 16);
    r += __shfl_xor(r, 32);
    int c = ((lane & 1) << 3) | ((lane & 2) << 1) | ((lane & 4) >> 1) | ((lane & 8) >> 3);
    float rr = r + b2g[c];
    if (lane < 16) h2[(size_t)n * NCLASS + c] = rr;
    float q1 = rr * a2[c], q2 = rr * a2[NCLASS + c];
#pragma unroll
    for (int o = 1; o < 64; o <<= 1) {
        q1 += __shfl_xor(q1, o);
        q2 += __shfl_xor(q2, o);
    }
    if (lane == 0) { as2[n] = q1 * 0.25f; at2[n] = q2 * 0.25f; }
}

// agg2: one WAVE per row, packed csr (no dup pass), fused log_softmax.
__global__ void agg2(const float* __restrict__ h2, const float* __restrict__ as2,
                     const float* __restrict__ at2, const int* __restrict__ rowptr,
                     const int* __restrict__ csrp, float* __restrict__ out) {
    __shared__ int tf[4][MAXDEG];
    __shared__ float pf[4][MAXDEG];
    int wv = threadIdx.x >> 6, lane = threadIdx.x & 63;
    int n = blockIdx.x * 4 + wv;
    int r0 = rowptr[n];
    int deg = rowptr[n + 1] - r0;
    if (deg > MAXDEG) deg = MAXDEG;
    if (deg == 0) {
        if (lane < NCLASS) out[(size_t)n * NCLASS + lane] = -logf((float)NCLASS);
        return;
    }
    float asvn = as2[n];
    int jg = lane >> 2, cq = lane & 3;
    if (deg <= 64) {
        int pk = (lane < deg) ? csrp[r0 + lane] : -1;
        int t = 0;
        float p = -INFINITY;
        if (pk >= 0) {
            t = pk & 0xFFFF;
            float e = asvn + at2[t];
            e = e > 0.f ? e : LRELU_ALPHA * e;
            p = (float)(pk >> 16) * e;
        }
        float m = p;
#pragma unroll
        for (int o = 32; o >= 1; o >>= 1) m = fmaxf(m, __shfl_xor(m, o));
        float pe = expf(p - m);
        float s = pe;
#pragma unroll
        for (int o = 32; o >= 1; o >>= 1) s += __shfl_xor(s, o);
        float4 a4 = {0.f, 0.f, 0.f, 0.f};
#pragma unroll
        for (int i = 0; i < 4; i++) {
            int j = i * 16 + jg;
            float pj = __shfl(pe, j);
            int tjv = __shfl(t, j);
            float4 hv = *(const float4*)(h2 + (size_t)tjv * NCLASS + cq * 4);
            a4.x += pj * hv.x; a4.y += pj * hv.y;
            a4.z += pj * hv.z; a4.w += pj * hv.w;
        }
#pragma unroll
        for (int o = 4; o <= 32; o <<= 1) {
            a4.x += __shfl_xor(a4.x, o);
            a4.y += __shfl_xor(a4.y, o);
            a4.z += __shfl_xor(a4.z, o);
            a4.w += __shfl_xor(a4.w, o);
        }
        float inv = 1.f / s;
        float4 v4 = {a4.x * inv, a4.y * inv, a4.z * inv, a4.w * inv};
        float mm = fmaxf(fmaxf(v4.x, v4.y), fmaxf(v4.z, v4.w));
        mm = fmaxf(mm, __shfl_xor(mm, 1));
        mm = fmaxf(mm, __shfl_xor(mm, 2));
        float se = expf(v4.x - mm) + expf(v4.y - mm) + expf(v4.z - mm) + expf(v4.w - mm);
        se += __shfl_xor(se, 1);
        se += __shfl_xor(se, 2);
        float lse = mm + logf(se);
        if (jg == 0) {
            float4 o4 = {v4.x - lse, v4.y - lse, v4.z - lse, v4.w - lse};
            *(float4*)(out + (size_t)n * NCLASS + cq * 4) = o4;
        }
    } else {
        for (int j = lane; j < deg; j += 64) {
            int pk = csrp[r0 + j];
            if (pk < 0) {
                tf[wv][j] = 0;
                pf[wv][j] = -INFINITY;
            } else {
                int t = pk & 0xFFFF;
                tf[wv][j] = t;
                float e = asvn + at2[t];
                e = e > 0.f ? e : LRELU_ALPHA * e;
                pf[wv][j] = (float)(pk >> 16) * e;
            }
        }
        float m = -INFINITY;
        for (int j = lane; j < deg; j += 64) m = fmaxf(m, pf[wv][j]);
#pragma unroll
        for (int o = 32; o >= 1; o >>= 1) m = fmaxf(m, __shfl_xor(m, o));
        float s = 0.f;
        for (int j = lane; j < deg; j += 64) {
            float pe = expf(pf[wv][j] - m);
            pf[wv][j] = pe;
            s += pe;
        }
#pragma unroll
        for (int o = 32; o >= 1; o >>= 1) s += __shfl_xor(s, o);
        float4 a4 = {0.f, 0.f, 0.f, 0.f};
        for (int j = jg; j < deg; j += 16) {
            float pj = pf[wv][j];
            float4 hv = *(const float4*)(h2 + (size_t)tf[wv][j] * NCLASS + cq * 4);
            a4.x += pj * hv.x; a4.y += pj * hv.y;
            a4.z += pj * hv.z; a4.w += pj * hv.w;
        }
#pragma unroll
        for (int o = 4; o <= 32; o <<= 1) {
            a4.x += __shfl_xor(a4.x, o);
            a4.y += __shfl_xor(a4.y, o);
            a4.z += __shfl_xor(a4.z, o);
            a4.w += __shfl_xor(a4.w, o);
        }
        float inv = 1.f / s;
        float4 v4 = {a4.x * inv, a4.y * inv, a4.z * inv, a4.w * inv};
        float mm = fmaxf(fmaxf(v4.x, v4.y), fmaxf(v4.z, v4.w));
        mm = fmaxf(mm, __shfl_xor(mm, 1));
        mm = fmaxf(mm, __shfl_xor(mm, 2));
        float se = expf(v4.x - mm) + expf(v4.y - mm) + expf(v4.z - mm) + expf(v4.w - mm);
        se += __shfl_xor(se, 1);
        se += __shfl_xor(se, 2);
        float lse = mm + logf(se);
        if (jg == 0) {
            float4 o4 = {v4.x - lse, v4.y - lse, v4.z - lse, v4.w - lse};
            *(float4*)(out + (size_t)n * NCLASS + cq * 4) = o4;
        }
    }
}

extern "C" void kernel_launch(void* const* d_in, const int* in_sizes, int n_in,
                              void* d_out, int out_size, void* d_ws, size_t ws_size,
                              hipStream_t stream) {
    const float* x  = (const float*)d_in[0];
    const int* el   = (const int*)d_in[1];
    const float* W1 = (const float*)d_in[2];
    const float* b1 = (const float*)d_in[3];
    const float* a1 = (const float*)d_in[4];
    const float* W2 = (const float*)d_in[5];
    const float* b2 = (const float*)d_in[6];
    const float* a2 = (const float*)d_in[7];
    float* out = (float*)d_out;

    unsigned short* h1b = (unsigned short*)d_ws;  // 4*8192*64 bf16 = 4 MB
    float* h2   = (float*)(h1b + 2097152);        // 8192*16 fp32
    float* as1  = h2 + 131072;                    // [n][4]
    float* at1  = as1 + 32768;                    // [n][4]
    float* as2  = at1 + 32768;
    float* at2  = as2 + 8192;
    int* deg    = (int*)(at2 + 8192);
    int* rowptr = deg + 8192;                     // 8200 (pad)
    int* cursor = rowptr + 8200;
    int* csr    = cursor + 8192;                  // 262144
    unsigned short* Wbf  = (unsigned short*)(csr + 262144);  // 256 KB
    unsigned short* W2tb = Wbf + 131072;          // 256*24 bf16

    const int* src = el;
    const int* tgt = el + NEDGE;

    prep<<<97, 256, 0, stream>>>(W1, Wbf, deg, W2, W2tb);
    gemm1c<<<1536, 256, 0, stream>>>(x, Wbf, b1, h1b, a1, as1, at1, src, deg);
    scan8192<<<1, 256, 0, stream>>>(deg, rowptr, cursor);
    fill_csr<<<1024, 256, 0, stream>>>(src, tgt, cursor, csr);
    agg1f<<<NN / 4, 256, 0, stream>>>(h1b, as1, at1, rowptr, csr, W2tb, b2, a2, h2, as2, at2);
    agg2<<<NN / 4, 256, 0, stream>>>(h2, as2, at2, rowptr, csr, out);
}

// Round 10
// 65.038 us; speedup vs baseline: 4.0164x; 1.2511x over previous
//
#include <hip/hip_runtime.h>
#include <math.h>

#define NN 8192
#define NFEAT 512
#define NHID 64
#define NHEADS 4
#define NCLASS 16
#define NEDGE 262144
#define LRELU_ALPHA 0.2f
#define MAXDEG 128

typedef __attribute__((ext_vector_type(8))) short short8;
typedef __attribute__((ext_vector_type(8))) unsigned short ushort8;
typedef __attribute__((ext_vector_type(4))) float f32x4;

__device__ __forceinline__ unsigned short bfr(float f) {
    unsigned int u = __float_as_uint(f);
    u += 0x7fffu + ((u >> 16) & 1u);   // round-to-nearest-even
    return (unsigned short)(u >> 16);
}
__device__ __forceinline__ float bf2f(unsigned short u) {
    return __uint_as_float(((unsigned int)u) << 16);
}

// prep: blocks 0..63 build Wbf (B-fragment-ordered bf16 W1);
// blocks 64..95 zero deg; block 96 packs W2^T -> bf16 [256][16].
__global__ void prep(const float* __restrict__ W1, unsigned short* __restrict__ Wbf,
                     int* __restrict__ deg, const float* __restrict__ W2,
                     unsigned short* __restrict__ W2tb) {
    int b = blockIdx.x, t = threadIdx.x;
    if (b < 64) {
        int idx = b * 256 + t;
        int lane = idx & 63, nt = (idx >> 6) & 15, ks = idx >> 10;
        int tfeat = nt * 16 + (lane & 15);
        int k0 = ks * 32 + (lane >> 4) * 8;
        const float* src = W1 + (size_t)tfeat * NFEAT + k0;
        float4 lo = *(const float4*)src;
        float4 hi = *(const float4*)(src + 4);
        ushort8 v;
        v[0] = bfr(lo.x); v[1] = bfr(lo.y); v[2] = bfr(lo.z); v[3] = bfr(lo.w);
        v[4] = bfr(hi.x); v[5] = bfr(hi.y); v[6] = bfr(hi.z); v[7] = bfr(hi.w);
        *(ushort8*)(Wbf + (size_t)idx * 8) = v;
    } else if (b < 96) {
        deg[(b - 64) * 256 + t] = 0;
    } else {
#pragma unroll
        for (int c = 0; c < NCLASS; c++)
            W2tb[t * 16 + c] = bfr(W2[c * 256 + t]);   // reads coalesced per c
    }
}

// gemm1c: blocks 0..511 = MFMA gemm1 (h1b bf16 + fused as1/at1 scores);
// blocks 512..1535 = dense-bucket CSR build (replaces count+scan+fill).
__global__ void gemm1c(const float* __restrict__ x, const unsigned short* __restrict__ Wbf,
                       const float* __restrict__ b1, unsigned short* __restrict__ h1b,
                       const float* __restrict__ a1, float* __restrict__ as1,
                       float* __restrict__ at1, const int* __restrict__ src_e,
                       const int* __restrict__ tgt_e, int* __restrict__ deg,
                       int* __restrict__ dense) {
    __shared__ __align__(16) unsigned short xs[16 * 512];   // 16 KB, XOR-swizzled rows
    int t = threadIdx.x;
    if (blockIdx.x >= 512) {
        int k = (blockIdx.x - 512) * 256 + t;   // 1024*256 == NEDGE exactly
        int s = src_e[k];
        int slot = atomicAdd(&deg[s], 1);
        if (slot < MAXDEG) dense[(size_t)s * MAXDEG + slot] = tgt_e[k];
        return;
    }
    int n0 = blockIdx.x * 16;
    const float4* xv = (const float4*)(x + (size_t)n0 * NFEAT);
#pragma unroll
    for (int i = 0; i < 4; i++) {
        int g = i * 256 + t;
        int row = g >> 6;
        int k0 = (g & 63) * 8;
        float4 lo = xv[g * 2];
        float4 hi = xv[g * 2 + 1];
        ushort8 v;
        v[0] = bfr(lo.x); v[1] = bfr(lo.y); v[2] = bfr(lo.z); v[3] = bfr(lo.w);
        v[4] = bfr(hi.x); v[5] = bfr(hi.y); v[6] = bfr(hi.z); v[7] = bfr(hi.w);
        int byte = (k0 * 2) ^ ((row & 7) << 4);
        *(ushort8*)((char*)xs + row * 1024 + byte) = v;
    }
    __syncthreads();
    int w = t >> 6, lane = t & 63;
    int arow = lane & 15, kg = lane >> 4;
    f32x4 acc[4];
#pragma unroll
    for (int j = 0; j < 4; j++) acc[j] = (f32x4){0.f, 0.f, 0.f, 0.f};
    const unsigned short* wb = Wbf + ((size_t)(w * 4) * 64 + lane) * 8;
    int abase = arow * 1024;
    int aswz = (arow & 7) << 4;
    for (int ks = 0; ks < 16; ks++) {
        short8 afrag = *(const short8*)((const char*)xs + abase + ((ks * 64 + kg * 16) ^ aswz));
#pragma unroll
        for (int j = 0; j < 4; j++) {
            short8 bfrag = *(const short8*)(wb + j * 512);
            acc[j] = __builtin_amdgcn_mfma_f32_16x16x32_bf16(afrag, bfrag, acc[j], 0, 0, 0);
        }
        wb += 8192;
    }
    int g4 = lane >> 4, cf = lane & 15;
    float p1[4] = {0.f, 0.f, 0.f, 0.f}, p2[4] = {0.f, 0.f, 0.f, 0.f};
#pragma unroll
    for (int j = 0; j < 4; j++) {
        int d = j * 16 + cf;
        float bias = b1[w * 64 + d];
        float c1 = a1[w * 2 * NHID + d];
        float c2 = a1[w * 2 * NHID + NHID + d];
#pragma unroll
        for (int r = 0; r < 4; r++) {
            int n = n0 + g4 * 4 + r;
            float v = acc[j][r] + bias;
            h1b[((size_t)w * NN + n) * NHID + d] = bfr(v);
            p1[r] += v * c1;
            p2[r] += v * c2;
        }
    }
#pragma unroll
    for (int r = 0; r < 4; r++) {
        float s1 = p1[r], s2 = p2[r];
#pragma unroll
        for (int o = 8; o >= 1; o >>= 1) {
            s1 += __shfl_xor(s1, o);
            s2 += __shfl_xor(s2, o);
        }
        if (cf == 0) {
            int n = n0 + g4 * 4 + r;
            as1[n * 4 + w] = s1;
            at1[n * 4 + w] = s2;
        }
    }
}

// agg1f: one WAVE per row, no LDS/syncthreads on fast path. Softmax + gather
// + fused gemm2 epilogue (W2^T bf16 frags loaded from L2 into registers).
// Writes packed (tgt | mult<<16, -1 dup) back into dense for agg2.
__global__ void agg1f(const unsigned short* __restrict__ h1b, const float* __restrict__ as1,
                      const float* __restrict__ at1, const int* __restrict__ degv,
                      int* __restrict__ dense, const unsigned short* __restrict__ W2tb,
                      const float* __restrict__ b2g, const float* __restrict__ a2,
                      float* __restrict__ h2, float* __restrict__ as2,
                      float* __restrict__ at2) {
    __shared__ int tsf[4][MAXDEG];            // fallback only
    __shared__ float psf[4][NHEADS][MAXDEG];  // fallback only
    int tid = threadIdx.x;
    int wv = tid >> 6, lane = tid & 63;
    int n = blockIdx.x * 4 + wv;
    int deg = degv[n];
    if (deg > MAXDEG) deg = MAXDEG;
    int eg = lane >> 3, dg = lane & 7;
    int* drow = dense + (size_t)n * MAXDEG;
    float outv[4] = {0.f, 0.f, 0.f, 0.f};
    if (deg > 0 && deg <= 64) {
        float4 asv = *(const float4*)(as1 + n * 4);
        int t = -1 - lane;
        float ea[4] = {0.f, 0.f, 0.f, 0.f};
        if (lane < deg) {
            t = drow[lane];
            float4 atv = *(const float4*)(at1 + t * 4);
            float e0 = asv.x + atv.x, e1 = asv.y + atv.y;
            float e2 = asv.z + atv.z, e3 = asv.w + atv.w;
            ea[0] = e0 > 0.f ? e0 : LRELU_ALPHA * e0;
            ea[1] = e1 > 0.f ? e1 : LRELU_ALPHA * e1;
            ea[2] = e2 > 0.f ? e2 : LRELU_ALPHA * e2;
            ea[3] = e3 > 0.f ? e3 : LRELU_ALPHA * e3;
        }
        int mult = 1;
        bool skip = false;
        for (int k = 1; k < 64; k++) {
            int idx = (lane + k) & 63;
            int to = __shfl(t, idx);
            if (to == t) { mult++; if (idx < lane) skip = true; }
        }
        if (lane < deg) drow[lane] = skip ? -1 : (t | (mult << 16));
        bool valid = (lane < deg) && !skip;
        float mf = (float)mult;
        int tj[8];
#pragma unroll
        for (int i = 0; i < 8; i++) {
            int tv = __shfl(t, i * 8 + eg);
            tj[i] = tv < 0 ? 0 : tv;
        }
        bool b2 = (eg & 4) != 0, b1 = (eg & 2) != 0, b0 = (eg & 1) != 0;
#pragma unroll
        for (int h = 0; h < 4; h++) {
            float p = valid ? mf * ea[h] : -INFINITY;
            float m = p;
#pragma unroll
            for (int o = 32; o >= 1; o >>= 1) m = fmaxf(m, __shfl_xor(m, o));
            float pe = expf(p - m);
            float s = pe;
#pragma unroll
            for (int o = 32; o >= 1; o >>= 1) s += __shfl_xor(s, o);
            const unsigned short* hb = h1b + (size_t)h * NN * NHID;
            float acc[8] = {0.f, 0.f, 0.f, 0.f, 0.f, 0.f, 0.f, 0.f};
#pragma unroll
            for (int i = 0; i < 8; i++) {
                float pj = __shfl(pe, i * 8 + eg);
                ushort8 hv = *(const ushort8*)(hb + (size_t)tj[i] * NHID + dg * 8);
#pragma unroll
                for (int q = 0; q < 8; q++) acc[q] += pj * bf2f(hv[q]);
            }
            float k4[4], k2[2], r;
#pragma unroll
            for (int q = 0; q < 4; q++) {
                float keep = b2 ? acc[4 + q] : acc[q];
                float send = b2 ? acc[q] : acc[4 + q];
                k4[q] = keep + __shfl_xor(send, 32);
            }
#pragma unroll
            for (int q = 0; q < 2; q++) {
                float keep = b1 ? k4[2 + q] : k4[q];
                float send = b1 ? k4[q] : k4[2 + q];
                k2[q] = keep + __shfl_xor(send, 16);
            }
            {
                float keep = b0 ? k2[1] : k2[0];
                float send = b0 ? k2[0] : k2[1];
                r = keep + __shfl_xor(send, 8);
            }
            float v = r / s;
            outv[h] = v > 0.f ? v : (expf(v) - 1.f);   // ELU
        }
    } else if (deg > 64) {
        // ---- wave-local LDS fallback (statistically never taken) ----
        float4 asv = *(const float4*)(as1 + n * 4);
        int* ts = tsf[wv];
        for (int j = lane; j < deg; j += 64) {
            int tv = drow[j];
            ts[j] = tv;
            float4 atv = *(const float4*)(at1 + tv * 4);
            float e0 = asv.x + atv.x, e1 = asv.y + atv.y;
            float e2 = asv.z + atv.z, e3 = asv.w + atv.w;
            psf[wv][0][j] = e0 > 0.f ? e0 : LRELU_ALPHA * e0;
            psf[wv][1][j] = e1 > 0.f ? e1 : LRELU_ALPHA * e1;
            psf[wv][2][j] = e2 > 0.f ? e2 : LRELU_ALPHA * e2;
            psf[wv][3][j] = e3 > 0.f ? e3 : LRELU_ALPHA * e3;
        }
        for (int j = lane; j < deg; j += 64) {
            int tjv = ts[j];
            int m = 1;
            bool skip = false;
            for (int j2 = 0; j2 < deg; j2++) {
                if (j2 == j) continue;
                if (ts[j2] == tjv) {
                    if (j2 < j) { skip = true; break; }
                    m++;
                }
            }
            if (skip) {
                psf[wv][0][j] = -INFINITY; psf[wv][1][j] = -INFINITY;
                psf[wv][2][j] = -INFINITY; psf[wv][3][j] = -INFINITY;
                drow[j] = -1;
            } else {
                float mf = (float)m;
                psf[wv][0][j] *= mf; psf[wv][1][j] *= mf;
                psf[wv][2][j] *= mf; psf[wv][3][j] *= mf;
                drow[j] = tjv | (m << 16);
            }
        }
        for (int h = 0; h < 4; h++) {
            float m = -INFINITY;
            for (int j = lane; j < deg; j += 64) m = fmaxf(m, psf[wv][h][j]);
#pragma unroll
            for (int o = 32; o >= 1; o >>= 1) m = fmaxf(m, __shfl_xor(m, o));
            float s = 0.f;
            for (int j = lane; j < deg; j += 64) {
                float pe = expf(psf[wv][h][j] - m);
                psf[wv][h][j] = pe;
                s += pe;
            }
#pragma unroll
            for (int o = 32; o >= 1; o >>= 1) s += __shfl_xor(s, o);
            const unsigned short* hb = h1b + (size_t)h * NN * NHID;
            float acc[8] = {0.f, 0.f, 0.f, 0.f, 0.f, 0.f, 0.f, 0.f};
            for (int j = eg; j < deg; j += 8) {
                float pj = psf[wv][h][j];
                int tjv = ts[j];
                ushort8 hv = *(const ushort8*)(hb + (size_t)tjv * NHID + dg * 8);
#pragma unroll
                for (int q = 0; q < 8; q++) acc[q] += pj * bf2f(hv[q]);
            }
            bool b2 = (eg & 4) != 0, b1 = (eg & 2) != 0, b0 = (eg & 1) != 0;
            float k4[4], k2[2], r;
#pragma unroll
            for (int q = 0; q < 4; q++) {
                float keep = b2 ? acc[4 + q] : acc[q];
                float send = b2 ? acc[q] : acc[4 + q];
                k4[q] = keep + __shfl_xor(send, 32);
            }
#pragma unroll
            for (int q = 0; q < 2; q++) {
                float keep = b1 ? k4[2 + q] : k4[q];
                float send = b1 ? k4[q] : k4[2 + q];
                k2[q] = keep + __shfl_xor(send, 16);
            }
            {
                float keep = b0 ? k2[1] : k2[0];
                float send = b0 ? k2[0] : k2[1];
                r = keep + __shfl_xor(send, 8);
            }
            float v = r / s;
            outv[h] = v > 0.f ? v : (expf(v) - 1.f);
        }
    }
    // ---- fused gemm2 epilogue: W2^T frags from L2, butterfly reduce ----
    float cp[16];
#pragma unroll
    for (int c = 0; c < 16; c++) cp[c] = 0.f;
#pragma unroll
    for (int h = 0; h < 4; h++) {
        const unsigned short* wrow = W2tb + (h * 64 + dg * 8 + eg) * 16;
        ushort8 wlo = *(const ushort8*)wrow;
        ushort8 whi = *(const ushort8*)(wrow + 8);
        float ov = outv[h];
#pragma unroll
        for (int c = 0; c < 8; c++) {
            cp[c] = fmaf(ov, bf2f(wlo[c]), cp[c]);
            cp[8 + c] = fmaf(ov, bf2f(whi[c]), cp[8 + c]);
        }
    }
    bool t0 = (lane & 1) != 0, t1 = (lane & 2) != 0, t2 = (lane & 4) != 0, t3 = (lane & 8) != 0;
    float p8[8];
#pragma unroll
    for (int q = 0; q < 8; q++) {
        float keep = t0 ? cp[8 + q] : cp[q];
        float send = t0 ? cp[q] : cp[8 + q];
        p8[q] = keep + __shfl_xor(send, 1);
    }
    float p4[4];
#pragma unroll
    for (int q = 0; q < 4; q++) {
        float keep = t1 ? p8[4 + q] : p8[q];
        float send = t1 ? p8[q] : p8[4 + q];
        p4[q] = keep + __shfl_xor(send, 2);
    }
    float p2[2];
#pragma unroll
    for (int q = 0; q < 2; q++) {
        float keep = t2 ? p4[2 + q] : p4[q];
        float send = t2 ? p4[q] : p4[2 + q];
        p2[q] = keep + __shfl_xor(send, 4);
    }
    float r = (t3 ? p2[1] : p2[0]) + __shfl_xor(t3 ? p2[0] : p2[1], 8);
    r += __shfl_xor(r, 16);
    r += __shfl_xor(r, 32);
    int c = ((lane & 1) << 3) | ((lane & 2) << 1) | ((lane & 4) >> 1) | ((lane & 8) >> 3);
    float rr = r + b2g[c];
    if (lane < 16) h2[(size_t)n * NCLASS + c] = rr;
    float q1 = rr * a2[c], q2 = rr * a2[NCLASS + c];
#pragma unroll
    for (int o = 1; o < 64; o <<= 1) {
        q1 += __shfl_xor(q1, o);
        q2 += __shfl_xor(q2, o);
    }
    if (lane == 0) { as2[n] = q1 * 0.25f; at2[n] = q2 * 0.25f; }
}

// agg2: one WAVE per row, packed dense (no dup pass), fused log_softmax.
__global__ void agg2(const float* __restrict__ h2, const float* __restrict__ as2,
                     const float* __restrict__ at2, const int* __restrict__ degv,
                     const int* __restrict__ dense, float* __restrict__ out) {
    __shared__ int tf[4][MAXDEG];
    __shared__ float pf[4][MAXDEG];
    int wv = threadIdx.x >> 6, lane = threadIdx.x & 63;
    int n = blockIdx.x * 4 + wv;
    int deg = degv[n];
    if (deg > MAXDEG) deg = MAXDEG;
    if (deg == 0) {
        if (lane < NCLASS) out[(size_t)n * NCLASS + lane] = -logf((float)NCLASS);
        return;
    }
    const int* drow = dense + (size_t)n * MAXDEG;
    float asvn = as2[n];
    int jg = lane >> 2, cq = lane & 3;
    if (deg <= 64) {
        int pk = (lane < deg) ? drow[lane] : -1;
        int t = 0;
        float p = -INFINITY;
        if (pk >= 0) {
            t = pk & 0xFFFF;
            float e = asvn + at2[t];
            e = e > 0.f ? e : LRELU_ALPHA * e;
            p = (float)(pk >> 16) * e;
        }
        float m = p;
#pragma unroll
        for (int o = 32; o >= 1; o >>= 1) m = fmaxf(m, __shfl_xor(m, o));
        float pe = expf(p - m);
        float s = pe;
#pragma unroll
        for (int o = 32; o >= 1; o >>= 1) s += __shfl_xor(s, o);
        float4 a4 = {0.f, 0.f, 0.f, 0.f};
#pragma unroll
        for (int i = 0; i < 4; i++) {
            int j = i * 16 + jg;
            float pj = __shfl(pe, j);
            int tjv = __shfl(t, j);
            float4 hv = *(const float4*)(h2 + (size_t)tjv * NCLASS + cq * 4);
            a4.x += pj * hv.x; a4.y += pj * hv.y;
            a4.z += pj * hv.z; a4.w += pj * hv.w;
        }
#pragma unroll
        for (int o = 4; o <= 32; o <<= 1) {
            a4.x += __shfl_xor(a4.x, o);
            a4.y += __shfl_xor(a4.y, o);
            a4.z += __shfl_xor(a4.z, o);
            a4.w += __shfl_xor(a4.w, o);
        }
        float inv = 1.f / s;
        float4 v4 = {a4.x * inv, a4.y * inv, a4.z * inv, a4.w * inv};
        float mm = fmaxf(fmaxf(v4.x, v4.y), fmaxf(v4.z, v4.w));
        mm = fmaxf(mm, __shfl_xor(mm, 1));
        mm = fmaxf(mm, __shfl_xor(mm, 2));
        float se = expf(v4.x - mm) + expf(v4.y - mm) + expf(v4.z - mm) + expf(v4.w - mm);
        se += __shfl_xor(se, 1);
        se += __shfl_xor(se, 2);
        float lse = mm + logf(se);
        if (jg == 0) {
            float4 o4 = {v4.x - lse, v4.y - lse, v4.z - lse, v4.w - lse};
            *(float4*)(out + (size_t)n * NCLASS + cq * 4) = o4;
        }
    } else {
        for (int j = lane; j < deg; j += 64) {
            int pk = drow[j];
            if (pk < 0) {
                tf[wv][j] = 0;
                pf[wv][j] = -INFINITY;
            } else {
                int t = pk & 0xFFFF;
                tf[wv][j] = t;
                float e = asvn + at2[t];
                e = e > 0.f ? e : LRELU_ALPHA * e;
                pf[wv][j] = (float)(pk >> 16) * e;
            }
        }
        float m = -INFINITY;
        for (int j = lane; j < deg; j += 64) m = fmaxf(m, pf[wv][j]);
#pragma unroll
        for (int o = 32; o >= 1; o >>= 1) m = fmaxf(m, __shfl_xor(m, o));
        float s = 0.f;
        for (int j = lane; j < deg; j += 64) {
            float pe = expf(pf[wv][j] - m);
            pf[wv][j] = pe;
            s += pe;
        }
#pragma unroll
        for (int o = 32; o >= 1; o >>= 1) s += __shfl_xor(s, o);
        float4 a4 = {0.f, 0.f, 0.f, 0.f};
        for (int j = jg; j < deg; j += 16) {
            float pj = pf[wv][j];
            float4 hv = *(const float4*)(h2 + (size_t)tf[wv][j] * NCLASS + cq * 4);
            a4.x += pj * hv.x; a4.y += pj * hv.y;
            a4.z += pj * hv.z; a4.w += pj * hv.w;
        }
#pragma unroll
        for (int o = 4; o <= 32; o <<= 1) {
            a4.x += __shfl_xor(a4.x, o);
            a4.y += __shfl_xor(a4.y, o);
            a4.z += __shfl_xor(a4.z, o);
            a4.w += __shfl_xor(a4.w, o);
        }
        float inv = 1.f / s;
        float4 v4 = {a4.x * inv, a4.y * inv, a4.z * inv, a4.w * inv};
        float mm = fmaxf(fmaxf(v4.x, v4.y), fmaxf(v4.z, v4.w));
        mm = fmaxf(mm, __shfl_xor(mm, 1));
        mm = fmaxf(mm, __shfl_xor(mm, 2));
        float se = expf(v4.x - mm) + expf(v4.y - mm) + expf(v4.z - mm) + expf(v4.w - mm);
        se += __shfl_xor(se, 1);
        se += __shfl_xor(se, 2);
        float lse = mm + logf(se);
        if (jg == 0) {
            float4 o4 = {v4.x - lse, v4.y - lse, v4.z - lse, v4.w - lse};
            *(float4*)(out + (size_t)n * NCLASS + cq * 4) = o4;
        }
    }
}

extern "C" void kernel_launch(void* const* d_in, const int* in_sizes, int n_in,
                              void* d_out, int out_size, void* d_ws, size_t ws_size,
                              hipStream_t stream) {
    const float* x  = (const float*)d_in[0];
    const int* el   = (const int*)d_in[1];
    const float* W1 = (const float*)d_in[2];
    const float* b1 = (const float*)d_in[3];
    const float* a1 = (const float*)d_in[4];
    const float* W2 = (const float*)d_in[5];
    const float* b2 = (const float*)d_in[6];
    const float* a2 = (const float*)d_in[7];
    float* out = (float*)d_out;

    unsigned short* h1b = (unsigned short*)d_ws;  // 4*8192*64 bf16 = 4 MB
    float* h2   = (float*)(h1b + 2097152);        // 8192*16 fp32
    float* as1  = h2 + 131072;                    // [n][4]
    float* at1  = as1 + 32768;                    // [n][4]
    float* as2  = at1 + 32768;
    float* at2  = as2 + 8192;
    int* deg    = (int*)(at2 + 8192);             // 8192
    int* dense  = deg + 8192;                     // 8192*128 = 4 MB
    unsigned short* Wbf  = (unsigned short*)(dense + 8192 * MAXDEG);  // 256 KB
    unsigned short* W2tb = Wbf + 131072;          // 256*16 bf16 = 8 KB

    const int* src = el;
    const int* tgt = el + NEDGE;

    prep<<<97, 256, 0, stream>>>(W1, Wbf, deg, W2, W2tb);
    gemm1c<<<1536, 256, 0, stream>>>(x, Wbf, b1, h1b, a1, as1, at1, src, tgt, deg, dense);
    agg1f<<<NN / 4, 256, 0, stream>>>(h1b, as1, at1, deg, dense, W2tb, b2, a2, h2, as2, at2);
    agg2<<<NN / 4, 256, 0, stream>>>(h2, as2, at2, deg, dense, out);
}